// Round 2
// baseline (403.194 us; speedup 1.0000x reference)
//
#include <hip/hip_runtime.h>

typedef short bf16x8 __attribute__((ext_vector_type(8)));
typedef float f32x4 __attribute__((ext_vector_type(4)));
typedef unsigned short ushort_t;
typedef unsigned int uint_t;

#define DIM 2048
#define NH 16
#define HD 128

__device__ __forceinline__ ushort_t f2b(float f) {
    union { float f; uint_t u; } a; a.f = f;
    uint_t u = a.u;
    return (ushort_t)((u + 0x7fffu + ((u >> 16) & 1u)) >> 16);
}

__device__ __forceinline__ uint_t cvt_pk_bf16(float lo, float hi) {
    uint_t r;
    asm("v_cvt_pk_bf16_f32 %0, %1, %2" : "=v"(r) : "v"(lo), "v"(hi));
    return r;
}

__device__ __forceinline__ void gload_lds16(const void* g, void* l) {
    void* gg = const_cast<void*>(g);
    __builtin_amdgcn_global_load_lds(
        (__attribute__((address_space(1))) uint_t*)gg,
        (__attribute__((address_space(3))) uint_t*)l, 16, 0, 0);
}

// ---------------- fp32 -> bf16 convert (generic) ----------------
__global__ __launch_bounds__(256) void k_cvt(const float* __restrict__ in,
                                             ushort_t* __restrict__ out, int n) {
    int idx = (blockIdx.x * 256 + threadIdx.x) * 8;
    if (idx >= n) return;
    float4 a = *(const float4*)(in + idx);
    float4 b = *(const float4*)(in + idx + 4);
    uint4 o;
    o.x = (uint_t)f2b(a.x) | ((uint_t)f2b(a.y) << 16);
    o.y = (uint_t)f2b(a.z) | ((uint_t)f2b(a.w) << 16);
    o.z = (uint_t)f2b(b.x) | ((uint_t)f2b(b.y) << 16);
    o.w = (uint_t)f2b(b.z) | ((uint_t)f2b(b.w) << 16);
    *(uint4*)(out + idx) = o;
}

// ---------------- batched weight convert: 6 x (2048*2048) into contiguous dst ----------------
struct CvtWArgs { const float* s[6]; };
__global__ __launch_bounds__(256) void k_cvtw(CvtWArgs a, ushort_t* __restrict__ dst) {
    int y = blockIdx.y;
    const float* in = a.s[y];
    ushort_t* out = dst + (size_t)y * 4194304;
    int idx = (blockIdx.x * 256 + threadIdx.x) * 8;
    float4 p = *(const float4*)(in + idx);
    float4 q = *(const float4*)(in + idx + 4);
    uint4 o;
    o.x = (uint_t)f2b(p.x) | ((uint_t)f2b(p.y) << 16);
    o.y = (uint_t)f2b(p.z) | ((uint_t)f2b(p.w) << 16);
    o.z = (uint_t)f2b(q.x) | ((uint_t)f2b(q.y) << 16);
    o.w = (uint_t)f2b(q.z) | ((uint_t)f2b(q.w) << 16);
    *(uint4*)(out + idx) = o;
}

// ---------------- bf16 NT GEMM: out = A(MxK) * B(NxK)^T + bias ----------------
struct GemmArgs {
    const ushort_t* A;
    const ushort_t* B;
    const float* bias;
    void* out;
};

__global__ __launch_bounds__(256) void k_gemm_bt(GemmArgs a0, GemmArgs a1,
                                                 int M, int N, int K, int out_bf16) {
    __shared__ ushort_t lA[128 * 32];
    __shared__ ushort_t lB[128 * 32];
    GemmArgs ar = blockIdx.z ? a1 : a0;
    int tid = threadIdx.x;
    int lane = tid & 63, wid = tid >> 6;
    int wr = wid >> 1, wc = wid & 1;
    int bm = blockIdx.x, bn = blockIdx.y;

    f32x4 acc[4][4];
#pragma unroll
    for (int m = 0; m < 4; m++)
#pragma unroll
        for (int n = 0; n < 4; n++) acc[m][n] = (f32x4){0.f, 0.f, 0.f, 0.f};

    const ushort_t* ga = ar.A + (size_t)(bm * 128 + wid * 32 + (lane >> 2)) * K + (lane & 3) * 8;
    const ushort_t* gb = ar.B + (size_t)(bn * 128 + wid * 32 + (lane >> 2)) * K + (lane & 3) * 8;
    ushort_t* la0 = lA + wid * 32 * 32;
    ushort_t* lb0 = lB + wid * 32 * 32;
    int r = lane & 15, kq = (lane >> 4) * 8;
    int Kt = K >> 5;

    for (int kt = 0; kt < Kt; ++kt) {
        __syncthreads();
        gload_lds16(ga, la0);
        gload_lds16(ga + 16 * (size_t)K, la0 + 16 * 32);
        gload_lds16(gb, lb0);
        gload_lds16(gb + 16 * (size_t)K, lb0 + 16 * 32);
        ga += 32; gb += 32;
        __syncthreads();
        bf16x8 af[4], bfr[4];
#pragma unroll
        for (int m = 0; m < 4; m++)
            af[m] = *(const bf16x8*)(lA + (wr * 64 + m * 16 + r) * 32 + kq);
#pragma unroll
        for (int n = 0; n < 4; n++)
            bfr[n] = *(const bf16x8*)(lB + (wc * 64 + n * 16 + r) * 32 + kq);
#pragma unroll
        for (int m = 0; m < 4; m++)
#pragma unroll
            for (int n = 0; n < 4; n++)
                acc[m][n] = __builtin_amdgcn_mfma_f32_16x16x32_bf16(af[m], bfr[n], acc[m][n], 0, 0, 0);
    }

#pragma unroll
    for (int n = 0; n < 4; n++) {
        int col = bn * 128 + wc * 64 + n * 16 + (lane & 15);
        float bv = ar.bias[col];
#pragma unroll
        for (int m = 0; m < 4; m++) {
            int row0 = bm * 128 + wr * 64 + m * 16 + (lane >> 4) * 4;
#pragma unroll
            for (int q = 0; q < 4; q++) {
                float v = acc[m][n][q] + bv;
                size_t o = (size_t)(row0 + q) * N + col;
                if (out_bf16) ((ushort_t*)ar.out)[o] = f2b(v);
                else ((float*)ar.out)[o] = v;
            }
        }
    }
}

// ---------------- fused RMSNorm + RoPE, fp32 in, bf16 out ----------------
__global__ __launch_bounds__(256) void k_rms_rope(const float* __restrict__ in,
                                                  const float* __restrict__ gain,
                                                  const float* __restrict__ freqs,
                                                  ushort_t* __restrict__ out,
                                                  int S, float oscale) {
    int row = blockIdx.x;
    int s = row % S;
    int tid = threadIdx.x;
    const float* p = in + (size_t)row * DIM + tid * 8;
    float4 a = *(const float4*)p;
    float4 b = *(const float4*)(p + 4);
    float y[8] = {a.x, a.y, a.z, a.w, b.x, b.y, b.z, b.w};
    float ss = 0.f;
#pragma unroll
    for (int j = 0; j < 8; j++) ss += y[j] * y[j];
#pragma unroll
    for (int off = 32; off > 0; off >>= 1) ss += __shfl_xor(ss, off, 64);
    __shared__ float red[4];
    int lane = tid & 63, wid = tid >> 6;
    if (lane == 0) red[wid] = ss;
    __syncthreads();
    float tot = red[0] + red[1] + red[2] + red[3];
    float inv = rsqrtf(tot * (1.0f / DIM) + 1e-6f);
    const float* g = gain + tid * 8;
    float4 g0 = *(const float4*)g;
    float4 g1 = *(const float4*)(g + 4);
    float gg[8] = {g0.x, g0.y, g0.z, g0.w, g1.x, g1.y, g1.z, g1.w};
    int p0 = (tid * 8 & 127) >> 1;
    const float* fq = freqs + ((size_t)s * 64 + p0) * 2;
    uint_t ow[4];
#pragma unroll
    for (int j = 0; j < 4; j++) {
        float fr = fq[j * 2 + 0], fi = fq[j * 2 + 1];
        float xr = y[2 * j] * inv * gg[2 * j];
        float xi = y[2 * j + 1] * inv * gg[2 * j + 1];
        float o0 = (xr * fr - xi * fi) * oscale;
        float o1 = (xr * fi + xi * fr) * oscale;
        ow[j] = (uint_t)f2b(o0) | ((uint_t)f2b(o1) << 16);
    }
    *(uint4*)(out + (size_t)row * DIM + tid * 8) = make_uint4(ow[0], ow[1], ow[2], ow[3]);
}

// ---------------- V transpose: vcam/vren (rows, DIM) -> vt[b,h,d=128,kv=1024] ----------------
__global__ __launch_bounds__(256) void k_vt(const ushort_t* __restrict__ vcam,
                                            const ushort_t* __restrict__ vren,
                                            ushort_t* __restrict__ vt) {
    __shared__ ushort_t t[64 * 136];
    int kt = blockIdx.x, h = blockIdx.y, b = blockIdx.z;
    int kv0 = kt * 64;
    const ushort_t* src = (kv0 < 512)
        ? vcam + ((size_t)(b * 512 + kv0)) * DIM + h * HD
        : vren + ((size_t)(b * 512 + kv0 - 512)) * DIM + h * HD;
    int tid = threadIdx.x;
#pragma unroll
    for (int i = 0; i < 4; i++) {
        int idx = i * 256 + tid;
        int kv = idx >> 4, c8 = idx & 15;
        uint4 v = *(const uint4*)(src + (size_t)kv * DIM + c8 * 8);
        *(uint4*)(t + kv * 136 + c8 * 8) = v;
    }
    __syncthreads();
    ushort_t* dst = vt + ((size_t)((b * NH + h) * HD)) * 1024 + kv0;
#pragma unroll
    for (int i = 0; i < 4; i++) {
        int idx = i * 256 + tid;
        int d = idx >> 3, c8 = idx & 7;
        ushort_t tmp[8];
#pragma unroll
        for (int j = 0; j < 8; j++) tmp[j] = t[(c8 * 8 + j) * 136 + d];
        uint4 o;
        o.x = (uint_t)tmp[0] | ((uint_t)tmp[1] << 16);
        o.y = (uint_t)tmp[2] | ((uint_t)tmp[3] << 16);
        o.z = (uint_t)tmp[4] | ((uint_t)tmp[5] << 16);
        o.w = (uint_t)tmp[6] | ((uint_t)tmp[7] << 16);
        *(uint4*)(dst + (size_t)d * 1024 + c8 * 8) = o;
    }
}

// ---------------- flash attention, swapped-QK^T (S^T = K x Q^T), in-register P ----------------
// Q comes pre-scaled by (1/sqrt(HD))*log2(e); softmax uses exp2.
__global__ __launch_bounds__(256, 4) void k_attn(const ushort_t* __restrict__ Q,
                                                 const ushort_t* __restrict__ Kc,
                                                 const ushort_t* __restrict__ Kr,
                                                 const ushort_t* __restrict__ Vt,
                                                 ushort_t* __restrict__ O) {
    __shared__ ushort_t lK[64 * 128];      // [kv=64][d=128], rows XOR-swizzled
    __shared__ ushort_t lV[128 * 64];      // [d=128][kv=64], rows XOR-swizzled
    int tid = threadIdx.x, lane = tid & 63, wid = tid >> 6;
    int c = lane & 15, g = lane >> 4;
    int qt = blockIdx.x, h = blockIdx.y, b = blockIdx.z;
    int q0 = qt * 64 + wid * 16;

    // Q fragment (B-operand of S^T mfma): lane holds Q[q=c][d = ks*32 + g*8 + j]
    const ushort_t* qg = Q + ((size_t)(b * 2048 + q0 + c)) * DIM + h * HD + g * 8;
    bf16x8 aQ[4];
#pragma unroll
    for (int ks = 0; ks < 4; ks++) aQ[ks] = *(const bf16x8*)(qg + ks * 32);

    float mr = -1e30f, lr = 0.f;
    f32x4 o[8];
#pragma unroll
    for (int d = 0; d < 8; d++) o[d] = (f32x4){0, 0, 0, 0};

    for (int kvt = 0; kvt < 16; ++kvt) {
        __syncthreads();
        int kv0 = kvt * 64;
        const ushort_t* kg = (kv0 < 512)
            ? Kc + ((size_t)(b * 512 + kv0)) * DIM + h * HD
            : Kr + ((size_t)(b * 512 + kv0 - 512)) * DIM + h * HD;
#pragma unroll
        for (int cc = 0; cc < 4; cc++) {  // K: 4 rows per call (256B rows)
            int lrow = wid * 16 + cc * 4 + (lane >> 4);
            int srcoff = ((lane & 15) * 16) ^ ((lrow & 7) << 4);
            gload_lds16((const char*)kg + (size_t)lrow * DIM * 2 + srcoff,
                        lK + (wid * 16 + cc * 4) * 128);
        }
        const ushort_t* vg = Vt + ((size_t)((b * NH + h) * HD)) * 1024 + kv0;
#pragma unroll
        for (int cc = 0; cc < 4; cc++) {  // Vt: 8 rows per call (128B rows)
            int vrow = wid * 32 + cc * 8 + (lane >> 3);
            int srcoff = ((lane & 7) * 16) ^ ((vrow & 7) << 4);
            gload_lds16((const char*)vg + (size_t)vrow * 1024 * 2 + srcoff,
                        lV + (wid * 32 + cc * 8) * 64);
        }
        __syncthreads();

        // S^T = K Q^T with permuted kv-row map:
        //   MFMA n, A-row a -> kv = (n>>1)*32 + (a>>2)*8 + (n&1)*4 + (a&3)
        // so lane (g,c) ends holding P at kv = (n>>1)*32 + g*8 + (n&1)*4 + r.
        f32x4 sT[4];
#pragma unroll
        for (int n = 0; n < 4; n++) sT[n] = (f32x4){0, 0, 0, 0};
#pragma unroll
        for (int n = 0; n < 4; n++) {
            int row = ((n >> 1) << 5) + ((c >> 2) << 3) + ((n & 1) << 2) + (c & 3);
            int rsw = (row & 7) << 4;
#pragma unroll
            for (int ks = 0; ks < 4; ks++) {
                int byt = (row * 256 + (ks * 32 + g * 8) * 2) ^ rsw;
                bf16x8 aK = *(const bf16x8*)((const char*)lK + byt);
                sT[n] = __builtin_amdgcn_mfma_f32_16x16x32_bf16(aK, aQ[ks], sT[n], 0, 0, 0);
            }
        }

        // online softmax over kv for q = c (per-lane 16 values + 2 shuffles)
        float mloc = sT[0][0];
#pragma unroll
        for (int n = 0; n < 4; n++)
#pragma unroll
            for (int r = 0; r < 4; r++) mloc = fmaxf(mloc, sT[n][r]);
        mloc = fmaxf(mloc, __shfl_xor(mloc, 16, 64));
        mloc = fmaxf(mloc, __shfl_xor(mloc, 32, 64));
        float mn = fmaxf(mr, mloc);
        float alpha = exp2f(mr - mn);
        mr = mn;
        float p[4][4];
        float ps = 0.f;
#pragma unroll
        for (int n = 0; n < 4; n++)
#pragma unroll
            for (int r = 0; r < 4; r++) {
                p[n][r] = exp2f(sT[n][r] - mn);
                ps += p[n][r];
            }
        ps += __shfl_xor(ps, 16, 64);
        ps += __shfl_xor(ps, 32, 64);
        lr = lr * alpha + ps;
#pragma unroll
        for (int d = 0; d < 8; d++) o[d] *= alpha;

        // O^T += Vt * P  (P packed fully in-lane: B-frag k = g*8 + (n&1)*4 + r)
#pragma unroll
        for (int kk = 0; kk < 2; kk++) {
            union { uint_t u[4]; bf16x8 v; } bP;
            bP.u[0] = cvt_pk_bf16(p[2 * kk][0], p[2 * kk][1]);
            bP.u[1] = cvt_pk_bf16(p[2 * kk][2], p[2 * kk][3]);
            bP.u[2] = cvt_pk_bf16(p[2 * kk + 1][0], p[2 * kk + 1][1]);
            bP.u[3] = cvt_pk_bf16(p[2 * kk + 1][2], p[2 * kk + 1][3]);
#pragma unroll
            for (int dt = 0; dt < 8; dt++) {
                int vrow = dt * 16 + c;
                int byt = (vrow * 128 + (kk * 32 + g * 8) * 2) ^ ((vrow & 7) << 4);
                bf16x8 aV = *(const bf16x8*)((const char*)lV + byt);
                o[dt] = __builtin_amdgcn_mfma_f32_16x16x32_bf16(aV, bP.v, o[dt], 0, 0, 0);
            }
        }
    }

    // epilogue: lane holds O[d = dt*16 + g*4 + r][q = c]; 8B packed stores
    float inv = 1.0f / lr;
    size_t orow = (size_t)(b * 2048 + q0 + c) * DIM + h * HD;
#pragma unroll
    for (int dt = 0; dt < 8; dt++) {
        uint2 w;
        w.x = (uint_t)f2b(o[dt][0] * inv) | ((uint_t)f2b(o[dt][1] * inv) << 16);
        w.y = (uint_t)f2b(o[dt][2] * inv) | ((uint_t)f2b(o[dt][3] * inv) << 16);
        *(uint2*)(O + orow + dt * 16 + g * 4) = w;
    }
}

extern "C" void kernel_launch(void* const* d_in, const int* in_sizes, int n_in,
                              void* d_out, int out_size, void* d_ws, size_t ws_size,
                              hipStream_t stream) {
    const float* x   = (const float*)d_in[0];
    const float* cam = (const float*)d_in[1];
    const float* ren = (const float*)d_in[2];
    const float* fx  = (const float*)d_in[3];
    const float* fc  = (const float*)d_in[4];
    const float* fr  = (const float*)d_in[5];
    const float* wq  = (const float*)d_in[6];
    const float* bq  = (const float*)d_in[7];
    const float* wk  = (const float*)d_in[8];
    const float* bk  = (const float*)d_in[9];
    const float* wv  = (const float*)d_in[10];
    const float* bv  = (const float*)d_in[11];
    const float* wkr = (const float*)d_in[12];
    const float* bkr = (const float*)d_in[13];
    const float* wvr = (const float*)d_in[14];
    const float* bvr = (const float*)d_in[15];
    const float* wo  = (const float*)d_in[16];
    const float* bo  = (const float*)d_in[17];
    const float* gq  = (const float*)d_in[18];
    const float* gk  = (const float*)d_in[19];

    char* ws = (char*)d_ws;
    ushort_t* wq_b     = (ushort_t*)(ws + 0);
    ushort_t* wk_b     = (ushort_t*)(ws + 8388608);
    ushort_t* wv_b     = (ushort_t*)(ws + 16777216);
    ushort_t* wkr_b    = (ushort_t*)(ws + 25165824);
    ushort_t* wvr_b    = (ushort_t*)(ws + 33554432);
    ushort_t* wo_b     = (ushort_t*)(ws + 41943040);
    ushort_t* xb       = (ushort_t*)(ws + 50331648);   // 16.8MB; reused by attn_bf later
    ushort_t* camb     = (ushort_t*)(ws + 67108864);
    ushort_t* renb     = (ushort_t*)(ws + 71303168);
    float*    kcam_lin = (float*)(ws + 75497472);      // 8.4MB; region reused by vt later
    float*    kren_lin = (float*)(ws + 83886080);
    ushort_t* q_bf     = (ushort_t*)(ws + 92274688);
    ushort_t* kcam_bf  = (ushort_t*)(ws + 109051904);
    ushort_t* kren_bf  = (ushort_t*)(ws + 113246208);
    ushort_t* vcam_bf  = (ushort_t*)(ws + 117440512);
    ushort_t* vren_bf  = (ushort_t*)(ws + 121634816);
    ushort_t* vt       = (ushort_t*)(ws + 75497472);   // overlays dead kcam_lin/kren_lin
    ushort_t* attn_bf  = (ushort_t*)(ws + 50331648);   // overlays dead xb
    float*    q_lin    = (float*)d_out;                // d_out doubles as Q-proj scratch

    // fp32 -> bf16 converts (weights batched: dsts are contiguous from ws+0)
    CvtWArgs cw{{wq, wk, wv, wkr, wvr, wo}};
    k_cvtw<<<dim3(2048, 6), 256, 0, stream>>>(cw, wq_b);
    k_cvt<<<4096, 256, 0, stream>>>(x, xb, 8388608);
    k_cvt<<<1024, 256, 0, stream>>>(cam, camb, 2097152);
    k_cvt<<<1024, 256, 0, stream>>>(ren, renb, 2097152);

    // Q projection -> fp32 scratch (d_out), then RMSNorm+RoPE; fold (1/sqrt(HD))*log2(e)
    GemmArgs gqa{xb, wq_b, bq, (void*)q_lin};
    k_gemm_bt<<<dim3(32, 16, 1), 256, 0, stream>>>(gqa, gqa, 4096, 2048, 2048, 0);
    k_rms_rope<<<4096, 256, 0, stream>>>(q_lin, gq, fx, q_bf, 2048,
                                         0.08838834764831845f * 1.4426950408889634f);

    // K projections (cam/ren batched in z), RMSNorm+RoPE
    GemmArgs kca{camb, wk_b, bk, (void*)kcam_lin};
    GemmArgs kra{renb, wkr_b, bkr, (void*)kren_lin};
    k_gemm_bt<<<dim3(8, 16, 2), 256, 0, stream>>>(kca, kra, 1024, 2048, 2048, 0);
    k_rms_rope<<<1024, 256, 0, stream>>>(kcam_lin, gk, fc, kcam_bf, 512, 1.0f);
    k_rms_rope<<<1024, 256, 0, stream>>>(kren_lin, gk, fr, kren_bf, 512, 1.0f);

    // V projections straight to bf16, then transpose to [b,h,d,kv]
    GemmArgs vca{camb, wv_b, bv, (void*)vcam_bf};
    GemmArgs vra{renb, wvr_b, bvr, (void*)vren_bf};
    k_gemm_bt<<<dim3(8, 16, 2), 256, 0, stream>>>(vca, vra, 1024, 2048, 2048, 1);
    k_vt<<<dim3(16, 16, 2), 256, 0, stream>>>(vcam_bf, vren_bf, vt);

    // flash attention
    k_attn<<<dim3(32, 16, 2), 256, 0, stream>>>(q_bf, kcam_bf, kren_bf, vt, attn_bf);

    // output projection -> d_out (fp32)
    GemmArgs goa{attn_bf, wo_b, bo, d_out};
    k_gemm_bt<<<dim3(32, 16, 1), 256, 0, stream>>>(goa, goa, 4096, 2048, 2048, 0);
}

// Round 3
// 328.447 us; speedup vs baseline: 1.2276x; 1.2276x over previous
//
#include <hip/hip_runtime.h>

typedef short bf16x8 __attribute__((ext_vector_type(8)));
typedef float f32x4 __attribute__((ext_vector_type(4)));
typedef unsigned short ushort_t;
typedef unsigned int uint_t;

#define DIM 2048
#define NH 16
#define HD 128

__device__ __forceinline__ ushort_t f2b(float f) {
    union { float f; uint_t u; } a; a.f = f;
    uint_t u = a.u;
    return (ushort_t)((u + 0x7fffu + ((u >> 16) & 1u)) >> 16);
}

__device__ __forceinline__ uint_t cvt_pk_bf16(float lo, float hi) {
    uint_t r;
    asm("v_cvt_pk_bf16_f32 %0, %1, %2" : "=v"(r) : "v"(lo), "v"(hi));
    return r;
}

__device__ __forceinline__ void gload_lds16(const void* g, void* l) {
    void* gg = const_cast<void*>(g);
    __builtin_amdgcn_global_load_lds(
        (__attribute__((address_space(1))) uint_t*)gg,
        (__attribute__((address_space(3))) uint_t*)l, 16, 0, 0);
}

// ---------------- fp32 -> bf16 convert (generic) ----------------
__global__ __launch_bounds__(256) void k_cvt(const float* __restrict__ in,
                                             ushort_t* __restrict__ out, int n) {
    int idx = (blockIdx.x * 256 + threadIdx.x) * 8;
    if (idx >= n) return;
    float4 a = *(const float4*)(in + idx);
    float4 b = *(const float4*)(in + idx + 4);
    uint4 o;
    o.x = (uint_t)f2b(a.x) | ((uint_t)f2b(a.y) << 16);
    o.y = (uint_t)f2b(a.z) | ((uint_t)f2b(a.w) << 16);
    o.z = (uint_t)f2b(b.x) | ((uint_t)f2b(b.y) << 16);
    o.w = (uint_t)f2b(b.z) | ((uint_t)f2b(b.w) << 16);
    *(uint4*)(out + idx) = o;
}

// ---------------- batched weight convert: 6 x (2048*2048) into contiguous dst ----------------
struct CvtWArgs { const float* s[6]; };
__global__ __launch_bounds__(256) void k_cvtw(CvtWArgs a, ushort_t* __restrict__ dst) {
    int y = blockIdx.y;
    const float* in = a.s[y];
    ushort_t* out = dst + (size_t)y * 4194304;
    int idx = (blockIdx.x * 256 + threadIdx.x) * 8;
    float4 p = *(const float4*)(in + idx);
    float4 q = *(const float4*)(in + idx + 4);
    uint4 o;
    o.x = (uint_t)f2b(p.x) | ((uint_t)f2b(p.y) << 16);
    o.y = (uint_t)f2b(p.z) | ((uint_t)f2b(p.w) << 16);
    o.z = (uint_t)f2b(q.x) | ((uint_t)f2b(q.y) << 16);
    o.w = (uint_t)f2b(q.z) | ((uint_t)f2b(q.w) << 16);
    *(uint4*)(out + idx) = o;
}

// ---------------- bf16 NT GEMM: out = A(MxK) * B(NxK)^T + bias ----------------
struct GemmArgs {
    const ushort_t* A;
    const ushort_t* B;
    const float* bias;
    void* out;
};

__global__ __launch_bounds__(256) void k_gemm_bt(GemmArgs a0, GemmArgs a1,
                                                 int M, int N, int K, int out_bf16) {
    __shared__ ushort_t lA[128 * 32];
    __shared__ ushort_t lB[128 * 32];
    GemmArgs ar = blockIdx.z ? a1 : a0;
    int tid = threadIdx.x;
    int lane = tid & 63, wid = tid >> 6;
    int wr = wid >> 1, wc = wid & 1;
    int bm = blockIdx.x, bn = blockIdx.y;

    f32x4 acc[4][4];
#pragma unroll
    for (int m = 0; m < 4; m++)
#pragma unroll
        for (int n = 0; n < 4; n++) acc[m][n] = (f32x4){0.f, 0.f, 0.f, 0.f};

    const ushort_t* ga = ar.A + (size_t)(bm * 128 + wid * 32 + (lane >> 2)) * K + (lane & 3) * 8;
    const ushort_t* gb = ar.B + (size_t)(bn * 128 + wid * 32 + (lane >> 2)) * K + (lane & 3) * 8;
    ushort_t* la0 = lA + wid * 32 * 32;
    ushort_t* lb0 = lB + wid * 32 * 32;
    int r = lane & 15, kq = (lane >> 4) * 8;
    int Kt = K >> 5;

    for (int kt = 0; kt < Kt; ++kt) {
        __syncthreads();
        gload_lds16(ga, la0);
        gload_lds16(ga + 16 * (size_t)K, la0 + 16 * 32);
        gload_lds16(gb, lb0);
        gload_lds16(gb + 16 * (size_t)K, lb0 + 16 * 32);
        ga += 32; gb += 32;
        __syncthreads();
        bf16x8 af[4], bfr[4];
#pragma unroll
        for (int m = 0; m < 4; m++)
            af[m] = *(const bf16x8*)(lA + (wr * 64 + m * 16 + r) * 32 + kq);
#pragma unroll
        for (int n = 0; n < 4; n++)
            bfr[n] = *(const bf16x8*)(lB + (wc * 64 + n * 16 + r) * 32 + kq);
#pragma unroll
        for (int m = 0; m < 4; m++)
#pragma unroll
            for (int n = 0; n < 4; n++)
                acc[m][n] = __builtin_amdgcn_mfma_f32_16x16x32_bf16(af[m], bfr[n], acc[m][n], 0, 0, 0);
    }

#pragma unroll
    for (int n = 0; n < 4; n++) {
        int col = bn * 128 + wc * 64 + n * 16 + (lane & 15);
        float bv = ar.bias[col];
#pragma unroll
        for (int m = 0; m < 4; m++) {
            int row0 = bm * 128 + wr * 64 + m * 16 + (lane >> 4) * 4;
#pragma unroll
            for (int q = 0; q < 4; q++) {
                float v = acc[m][n][q] + bv;
                size_t o = (size_t)(row0 + q) * N + col;
                if (out_bf16) ((ushort_t*)ar.out)[o] = f2b(v);
                else ((float*)ar.out)[o] = v;
            }
        }
    }
}

// ---------------- fused RMSNorm + RoPE, fp32 in, bf16 out ----------------
__global__ __launch_bounds__(256) void k_rms_rope(const float* __restrict__ in,
                                                  const float* __restrict__ gain,
                                                  const float* __restrict__ freqs,
                                                  ushort_t* __restrict__ out,
                                                  int S, float oscale) {
    int row = blockIdx.x;
    int s = row % S;
    int tid = threadIdx.x;
    const float* p = in + (size_t)row * DIM + tid * 8;
    float4 a = *(const float4*)p;
    float4 b = *(const float4*)(p + 4);
    float y[8] = {a.x, a.y, a.z, a.w, b.x, b.y, b.z, b.w};
    float ss = 0.f;
#pragma unroll
    for (int j = 0; j < 8; j++) ss += y[j] * y[j];
#pragma unroll
    for (int off = 32; off > 0; off >>= 1) ss += __shfl_xor(ss, off, 64);
    __shared__ float red[4];
    int lane = tid & 63, wid = tid >> 6;
    if (lane == 0) red[wid] = ss;
    __syncthreads();
    float tot = red[0] + red[1] + red[2] + red[3];
    float inv = rsqrtf(tot * (1.0f / DIM) + 1e-6f);
    const float* g = gain + tid * 8;
    float4 g0 = *(const float4*)g;
    float4 g1 = *(const float4*)(g + 4);
    float gg[8] = {g0.x, g0.y, g0.z, g0.w, g1.x, g1.y, g1.z, g1.w};
    int p0 = (tid * 8 & 127) >> 1;
    const float* fq = freqs + ((size_t)s * 64 + p0) * 2;
    uint_t ow[4];
#pragma unroll
    for (int j = 0; j < 4; j++) {
        float fr = fq[j * 2 + 0], fi = fq[j * 2 + 1];
        float xr = y[2 * j] * inv * gg[2 * j];
        float xi = y[2 * j + 1] * inv * gg[2 * j + 1];
        float o0 = (xr * fr - xi * fi) * oscale;
        float o1 = (xr * fi + xi * fr) * oscale;
        ow[j] = (uint_t)f2b(o0) | ((uint_t)f2b(o1) << 16);
    }
    *(uint4*)(out + (size_t)row * DIM + tid * 8) = make_uint4(ow[0], ow[1], ow[2], ow[3]);
}

// ---------------- V transpose: vcam/vren (rows, DIM) -> vt[b,h,d=128,kv=1024] ----------------
__global__ __launch_bounds__(256) void k_vt(const ushort_t* __restrict__ vcam,
                                            const ushort_t* __restrict__ vren,
                                            ushort_t* __restrict__ vt) {
    __shared__ ushort_t t[64 * 136];
    int kt = blockIdx.x, h = blockIdx.y, b = blockIdx.z;
    int kv0 = kt * 64;
    const ushort_t* src = (kv0 < 512)
        ? vcam + ((size_t)(b * 512 + kv0)) * DIM + h * HD
        : vren + ((size_t)(b * 512 + kv0 - 512)) * DIM + h * HD;
    int tid = threadIdx.x;
#pragma unroll
    for (int i = 0; i < 4; i++) {
        int idx = i * 256 + tid;
        int kv = idx >> 4, c8 = idx & 15;
        uint4 v = *(const uint4*)(src + (size_t)kv * DIM + c8 * 8);
        *(uint4*)(t + kv * 136 + c8 * 8) = v;
    }
    __syncthreads();
    ushort_t* dst = vt + ((size_t)((b * NH + h) * HD)) * 1024 + kv0;
#pragma unroll
    for (int i = 0; i < 4; i++) {
        int idx = i * 256 + tid;
        int d = idx >> 3, c8 = idx & 7;
        ushort_t tmp[8];
#pragma unroll
        for (int j = 0; j < 8; j++) tmp[j] = t[(c8 * 8 + j) * 136 + d];
        uint4 o;
        o.x = (uint_t)tmp[0] | ((uint_t)tmp[1] << 16);
        o.y = (uint_t)tmp[2] | ((uint_t)tmp[3] << 16);
        o.z = (uint_t)tmp[4] | ((uint_t)tmp[5] << 16);
        o.w = (uint_t)tmp[6] | ((uint_t)tmp[7] << 16);
        *(uint4*)(dst + (size_t)d * 1024 + c8 * 8) = o;
    }
}

// ---------------- flash attention, swapped-QK^T, XCD-pinned, in-register P ----------------
// Q comes pre-scaled by (1/sqrt(HD))*log2(e); softmax uses exp2.
// Grid: flat 1024 blocks. xcd = bid&7 owns 4 (h,b) combos -> K/V stay in that XCD's L2.
__global__ __launch_bounds__(256, 4) void k_attn(const ushort_t* __restrict__ Q,
                                                 const ushort_t* __restrict__ Kc,
                                                 const ushort_t* __restrict__ Kr,
                                                 const ushort_t* __restrict__ Vt,
                                                 ushort_t* __restrict__ O) {
    __shared__ char smem[32768];
    ushort_t* lK = (ushort_t*)smem;            // [kv=64][d=128], chunk-swizzled
    ushort_t* lV = (ushort_t*)(smem + 16384);  // [d=128][kv=64], chunk-swizzled
    ushort_t* lO = (ushort_t*)smem;            // epilogue overlay [64][136]

    int tid = threadIdx.x, lane = tid & 63, wid = tid >> 6;
    int c = lane & 15, g = lane >> 4;

    // XCD-pinned decode: each XCD gets 2 heads x 2 batches, 32 qt-blocks each.
    int bid = blockIdx.x;
    int xcd = bid & 7, idx = bid >> 3;
    int combo = idx & 3, qt = idx >> 2;
    int b = combo >> 1, h = xcd * 2 + (combo & 1);
    int q0 = qt * 64 + wid * 16;

    // Q fragment (B-operand of S^T mfma): lane holds Q[q=c][d = ks*32 + g*8 + j]
    const ushort_t* qg = Q + ((size_t)(b * 2048 + q0 + c)) * DIM + h * HD + g * 8;
    bf16x8 aQ[4];
#pragma unroll
    for (int ks = 0; ks < 4; ks++) aQ[ks] = *(const bf16x8*)(qg + ks * 32);

    float mr = -1e30f, lr = 0.f;
    f32x4 o[8];
#pragma unroll
    for (int d = 0; d < 8; d++) o[d] = (f32x4){0, 0, 0, 0};

    for (int kvt = 0; kvt < 16; ++kvt) {
        __syncthreads();
        int kv0 = kvt * 64;
        const ushort_t* kg = (kv0 < 512)
            ? Kc + ((size_t)(b * 512 + kv0)) * DIM + h * HD
            : Kr + ((size_t)(b * 512 + kv0 - 512)) * DIM + h * HD;
        // K stage: swizzle on row bits {0,1,3,4}: sw = (r&3)|(((r>>3)&3)<<2)
#pragma unroll
        for (int cc = 0; cc < 4; cc++) {
            int lrow = wid * 16 + cc * 4 + (lane >> 4);
            int sw = (lrow & 3) | (((lrow >> 3) & 3) << 2);
            int srcoff = ((lane & 15) ^ sw) << 4;
            gload_lds16((const char*)kg + (size_t)lrow * (DIM * 2) + srcoff,
                        lK + (wid * 16 + cc * 4) * 128);
        }
        const ushort_t* vg = Vt + ((size_t)((b * NH + h) * HD)) * 1024 + kv0;
#pragma unroll
        for (int cc = 0; cc < 4; cc++) {
            int vrow = wid * 32 + cc * 8 + (lane >> 3);
            int srcoff = ((lane & 7) ^ (vrow & 7)) << 4;
            gload_lds16((const char*)vg + (size_t)vrow * (1024 * 2) + srcoff,
                        lV + (wid * 32 + cc * 8) * 64);
        }
        __syncthreads();

        // S^T = K Q^T with permuted kv-row map:
        //   MFMA n, A-row a -> kv = (n>>1)*32 + (a>>2)*8 + (n&1)*4 + (a&3)
        f32x4 sT[4];
#pragma unroll
        for (int n = 0; n < 4; n++) sT[n] = (f32x4){0, 0, 0, 0};
#pragma unroll
        for (int n = 0; n < 4; n++) {
            int row = ((n >> 1) << 5) + ((c >> 2) << 3) + ((n & 1) << 2) + (c & 3);
            int sw = (row & 3) | (((row >> 3) & 3) << 2);
#pragma unroll
            for (int ks = 0; ks < 4; ks++) {
                int chunk = (ks << 2) + g;
                int byt = row * 256 + ((chunk ^ sw) << 4);
                bf16x8 aK = *(const bf16x8*)((const char*)lK + byt);
                sT[n] = __builtin_amdgcn_mfma_f32_16x16x32_bf16(aK, aQ[ks], sT[n], 0, 0, 0);
            }
        }

        // online softmax over kv for q = c (per-lane 16 values + 2 shuffles)
        float mloc = sT[0][0];
#pragma unroll
        for (int n = 0; n < 4; n++)
#pragma unroll
            for (int r = 0; r < 4; r++) mloc = fmaxf(mloc, sT[n][r]);
        mloc = fmaxf(mloc, __shfl_xor(mloc, 16, 64));
        mloc = fmaxf(mloc, __shfl_xor(mloc, 32, 64));
        float mn = fmaxf(mr, mloc);
        float alpha = exp2f(mr - mn);
        mr = mn;
        float p[4][4];
        float ps = 0.f;
#pragma unroll
        for (int n = 0; n < 4; n++)
#pragma unroll
            for (int r = 0; r < 4; r++) {
                p[n][r] = exp2f(sT[n][r] - mn);
                ps += p[n][r];
            }
        ps += __shfl_xor(ps, 16, 64);
        ps += __shfl_xor(ps, 32, 64);
        lr = lr * alpha + ps;
#pragma unroll
        for (int d = 0; d < 8; d++) o[d] *= alpha;

        // O^T += Vt * P  (P packed fully in-lane: B-frag k = g*8 + (n&1)*4 + r)
#pragma unroll
        for (int kk = 0; kk < 2; kk++) {
            union { uint_t u[4]; bf16x8 v; } bP;
            bP.u[0] = cvt_pk_bf16(p[2 * kk][0], p[2 * kk][1]);
            bP.u[1] = cvt_pk_bf16(p[2 * kk][2], p[2 * kk][3]);
            bP.u[2] = cvt_pk_bf16(p[2 * kk + 1][0], p[2 * kk + 1][1]);
            bP.u[3] = cvt_pk_bf16(p[2 * kk + 1][2], p[2 * kk + 1][3]);
#pragma unroll
            for (int dt = 0; dt < 8; dt++) {
                int vrow = dt * 16 + c;
                int chunk = (kk << 2) + g;
                int byt = vrow * 128 + ((chunk ^ (vrow & 7)) << 4);
                bf16x8 aV = *(const bf16x8*)((const char*)lV + byt);
                o[dt] = __builtin_amdgcn_mfma_f32_16x16x32_bf16(aV, bP.v, o[dt], 0, 0, 0);
            }
        }
    }

    // epilogue: lane holds O[d = dt*16 + g*4 + r][q = c]. Stage in LDS, write full lines.
    __syncthreads();
    float inv = 1.0f / lr;
#pragma unroll
    for (int dt = 0; dt < 8; dt++) {
        uint2 w;
        w.x = (uint_t)f2b(o[dt][0] * inv) | ((uint_t)f2b(o[dt][1] * inv) << 16);
        w.y = (uint_t)f2b(o[dt][2] * inv) | ((uint_t)f2b(o[dt][3] * inv) << 16);
        *(uint2*)(lO + (wid * 16 + c) * 136 + dt * 16 + g * 4) = w;
    }
    __syncthreads();
    int row = tid >> 2, c8 = tid & 3;
    const ushort_t* src = lO + row * 136 + c8 * 32;
    ushort_t* dst = O + (size_t)(b * 2048 + qt * 64 + row) * DIM + h * HD + c8 * 32;
#pragma unroll
    for (int k = 0; k < 4; k++) *(uint4*)(dst + k * 8) = *(const uint4*)(src + k * 8);
}

extern "C" void kernel_launch(void* const* d_in, const int* in_sizes, int n_in,
                              void* d_out, int out_size, void* d_ws, size_t ws_size,
                              hipStream_t stream) {
    const float* x   = (const float*)d_in[0];
    const float* cam = (const float*)d_in[1];
    const float* ren = (const float*)d_in[2];
    const float* fx  = (const float*)d_in[3];
    const float* fc  = (const float*)d_in[4];
    const float* fr  = (const float*)d_in[5];
    const float* wq  = (const float*)d_in[6];
    const float* bq  = (const float*)d_in[7];
    const float* wk  = (const float*)d_in[8];
    const float* bk  = (const float*)d_in[9];
    const float* wv  = (const float*)d_in[10];
    const float* bv  = (const float*)d_in[11];
    const float* wkr = (const float*)d_in[12];
    const float* bkr = (const float*)d_in[13];
    const float* wvr = (const float*)d_in[14];
    const float* bvr = (const float*)d_in[15];
    const float* wo  = (const float*)d_in[16];
    const float* bo  = (const float*)d_in[17];
    const float* gq  = (const float*)d_in[18];
    const float* gk  = (const float*)d_in[19];

    char* ws = (char*)d_ws;
    ushort_t* wq_b     = (ushort_t*)(ws + 0);
    ushort_t* wk_b     = (ushort_t*)(ws + 8388608);
    ushort_t* wv_b     = (ushort_t*)(ws + 16777216);
    ushort_t* wkr_b    = (ushort_t*)(ws + 25165824);
    ushort_t* wvr_b    = (ushort_t*)(ws + 33554432);
    ushort_t* wo_b     = (ushort_t*)(ws + 41943040);
    ushort_t* xb       = (ushort_t*)(ws + 50331648);   // 16.8MB; reused by attn_bf later
    ushort_t* camb     = (ushort_t*)(ws + 67108864);
    ushort_t* renb     = (ushort_t*)(ws + 71303168);
    float*    kcam_lin = (float*)(ws + 75497472);      // 8.4MB; region reused by vt later
    float*    kren_lin = (float*)(ws + 83886080);
    ushort_t* q_bf     = (ushort_t*)(ws + 92274688);
    ushort_t* kcam_bf  = (ushort_t*)(ws + 109051904);
    ushort_t* kren_bf  = (ushort_t*)(ws + 113246208);
    ushort_t* vcam_bf  = (ushort_t*)(ws + 117440512);
    ushort_t* vren_bf  = (ushort_t*)(ws + 121634816);
    ushort_t* vt       = (ushort_t*)(ws + 75497472);   // overlays dead kcam_lin/kren_lin
    ushort_t* attn_bf  = (ushort_t*)(ws + 50331648);   // overlays dead xb
    float*    q_lin    = (float*)d_out;                // d_out doubles as Q-proj scratch

    // fp32 -> bf16 converts (weights batched: dsts are contiguous from ws+0)
    CvtWArgs cw{{wq, wk, wv, wkr, wvr, wo}};
    k_cvtw<<<dim3(2048, 6), 256, 0, stream>>>(cw, wq_b);
    k_cvt<<<4096, 256, 0, stream>>>(x, xb, 8388608);
    k_cvt<<<1024, 256, 0, stream>>>(cam, camb, 2097152);
    k_cvt<<<1024, 256, 0, stream>>>(ren, renb, 2097152);

    // Q projection -> fp32 scratch (d_out), then RMSNorm+RoPE; fold (1/sqrt(HD))*log2(e)
    GemmArgs gqa{xb, wq_b, bq, (void*)q_lin};
    k_gemm_bt<<<dim3(32, 16, 1), 256, 0, stream>>>(gqa, gqa, 4096, 2048, 2048, 0);
    k_rms_rope<<<4096, 256, 0, stream>>>(q_lin, gq, fx, q_bf, 2048,
                                         0.08838834764831845f * 1.4426950408889634f);

    // K projections (cam/ren batched in z), RMSNorm+RoPE
    GemmArgs kca{camb, wk_b, bk, (void*)kcam_lin};
    GemmArgs kra{renb, wkr_b, bkr, (void*)kren_lin};
    k_gemm_bt<<<dim3(8, 16, 2), 256, 0, stream>>>(kca, kra, 1024, 2048, 2048, 0);
    k_rms_rope<<<1024, 256, 0, stream>>>(kcam_lin, gk, fc, kcam_bf, 512, 1.0f);
    k_rms_rope<<<1024, 256, 0, stream>>>(kren_lin, gk, fr, kren_bf, 512, 1.0f);

    // V projections straight to bf16, then transpose to [b,h,d,kv]
    GemmArgs vca{camb, wv_b, bv, (void*)vcam_bf};
    GemmArgs vra{renb, wvr_b, bvr, (void*)vren_bf};
    k_gemm_bt<<<dim3(8, 16, 2), 256, 0, stream>>>(vca, vra, 1024, 2048, 2048, 1);
    k_vt<<<dim3(16, 16, 2), 256, 0, stream>>>(vcam_bf, vren_bf, vt);

    // flash attention (flat grid, XCD-pinned decode in-kernel)
    k_attn<<<dim3(1024, 1, 1), 256, 0, stream>>>(q_bf, kcam_bf, kren_bf, vt, attn_bf);

    // output projection -> d_out (fp32)
    GemmArgs goa{attn_bf, wo_b, bo, d_out};
    k_gemm_bt<<<dim3(32, 16, 1), 256, 0, stream>>>(goa, goa, 4096, 2048, 2048, 0);
}

// Round 4
// 270.634 us; speedup vs baseline: 1.4898x; 1.2136x over previous
//
#include <hip/hip_runtime.h>

typedef short bf16x8 __attribute__((ext_vector_type(8)));
typedef float f32x4 __attribute__((ext_vector_type(4)));
typedef unsigned short ushort_t;
typedef unsigned int uint_t;

#define DIM 2048
#define NH 16
#define HD 128

__device__ __forceinline__ ushort_t f2b(float f) {
    union { float f; uint_t u; } a; a.f = f;
    uint_t u = a.u;
    return (ushort_t)((u + 0x7fffu + ((u >> 16) & 1u)) >> 16);
}

__device__ __forceinline__ uint_t cvt_pk_bf16(float lo, float hi) {
    uint_t r;
    asm("v_cvt_pk_bf16_f32 %0, %1, %2" : "=v"(r) : "v"(lo), "v"(hi));
    return r;
}

__device__ __forceinline__ void gload_lds16(const void* g, void* l) {
    void* gg = const_cast<void*>(g);
    __builtin_amdgcn_global_load_lds(
        (__attribute__((address_space(1))) uint_t*)gg,
        (__attribute__((address_space(3))) uint_t*)l, 16, 0, 0);
}

// ---------------- fp32 -> bf16 convert (generic) ----------------
__global__ __launch_bounds__(256) void k_cvt(const float* __restrict__ in,
                                             ushort_t* __restrict__ out, int n) {
    int idx = (blockIdx.x * 256 + threadIdx.x) * 8;
    if (idx >= n) return;
    float4 a = *(const float4*)(in + idx);
    float4 b = *(const float4*)(in + idx + 4);
    uint4 o;
    o.x = (uint_t)f2b(a.x) | ((uint_t)f2b(a.y) << 16);
    o.y = (uint_t)f2b(a.z) | ((uint_t)f2b(a.w) << 16);
    o.z = (uint_t)f2b(b.x) | ((uint_t)f2b(b.y) << 16);
    o.w = (uint_t)f2b(b.z) | ((uint_t)f2b(b.w) << 16);
    *(uint4*)(out + idx) = o;
}

// ---------------- batched weight convert: 6 x (2048*2048) into contiguous dst ----------------
struct CvtWArgs { const float* s[6]; };
__global__ __launch_bounds__(256) void k_cvtw(CvtWArgs a, ushort_t* __restrict__ dst) {
    int y = blockIdx.y;
    const float* in = a.s[y];
    ushort_t* out = dst + (size_t)y * 4194304;
    int idx = (blockIdx.x * 256 + threadIdx.x) * 8;
    float4 p = *(const float4*)(in + idx);
    float4 q = *(const float4*)(in + idx + 4);
    uint4 o;
    o.x = (uint_t)f2b(p.x) | ((uint_t)f2b(p.y) << 16);
    o.y = (uint_t)f2b(p.z) | ((uint_t)f2b(p.w) << 16);
    o.z = (uint_t)f2b(q.x) | ((uint_t)f2b(q.y) << 16);
    o.w = (uint_t)f2b(q.z) | ((uint_t)f2b(q.w) << 16);
    *(uint4*)(out + idx) = o;
}

// ---------------- pipelined bf16 NT GEMM, BM=128 BN=256 BK=32, 512 thr ----------------
// out = A(Mx2048) * B(Nx2048)^T + bias.  MODE 0: fp32 out0 (ld 2048).
// MODE 2: cols<2048 -> fp32 out0 (ld 2048), cols>=2048 -> bf16 out1 (ld 2048).
struct G8 {
    const ushort_t* A;
    const ushort_t* B;
    const float* bias0;
    const float* bias1;
    void* out0;
    void* out1;
};

template<int MODE>
__global__ __launch_bounds__(512, 2) void k_gemm8(G8 a0, G8 a1) {
    // per buffer d (0/1) at d*24576: A[128][32] bf16 (8KB) then B[256][32] (16KB)
    __shared__ __align__(16) char sm[49152];
    int tid = threadIdx.x, lane = tid & 63, wid = tid >> 6;
    int c = lane & 15, g = lane >> 4;
    int wr = wid >> 2, wc = wid & 3;

    // bijective XCD remap: each XCD gets a contiguous re-range (shares B panels)
    int flat = blockIdx.x + blockIdx.y * gridDim.x;
    int qq = (gridDim.x * gridDim.y) >> 3;
    int re = (flat & 7) * qq + (flat >> 3);
    int bm = re % gridDim.x, bn = re / gridDim.x;

    G8 ar = blockIdx.z ? a1 : a0;

    // staging source addrs (chunk pre-swizzled: rule 21 — LDS dest linear)
    int chunk = ((tid & 3) ^ ((tid >> 3) & 3)) << 4;
    const char* gA  = (const char*)ar.A + (size_t)(bm * 128 + (tid >> 2)) * (DIM * 2) + chunk;
    const char* gB0 = (const char*)ar.B + (size_t)(bn * 256 + (tid >> 2)) * (DIM * 2) + chunk;
    const char* gB1 = gB0 + (size_t)128 * (DIM * 2);
    char* wA  = sm + wid * 1024;
    char* wB0 = sm + 8192 + wid * 1024;
    char* wB1 = sm + 16384 + wid * 1024;

    f32x4 acc[4][4];
#pragma unroll
    for (int m = 0; m < 4; m++)
#pragma unroll
        for (int n = 0; n < 4; n++) acc[m][n] = (f32x4){0.f, 0.f, 0.f, 0.f};

    // prologue: stage tiles 0 (buf0) and 1 (buf1)
    gload_lds16(gA, wA);
    gload_lds16(gB0, wB0);
    gload_lds16(gB1, wB1);
    gload_lds16(gA + 64, wA + 24576);
    gload_lds16(gB0 + 64, wB0 + 24576);
    gload_lds16(gB1 + 64, wB1 + 24576);
    asm volatile("s_waitcnt vmcnt(3)" ::: "memory");   // tile 0 resident; tile 1 in flight
    __builtin_amdgcn_s_barrier();

    // ds_read offsets (read-side swizzle matches staging pre-swizzle)
    int arow = wr * 64 + c;
    int aoff = arow * 64 + ((g ^ ((arow >> 1) & 3)) << 4);
    int brow = wc * 64 + c;
    int boff = 8192 + brow * 64 + ((g ^ ((brow >> 1) & 3)) << 4);

    for (int kt = 0; kt < 64; ++kt) {
        int dboff = (kt & 1) * 24576;
        bf16x8 aF[4], bF[4];
#pragma unroll
        for (int m = 0; m < 4; m++) aF[m] = *(const bf16x8*)(sm + dboff + aoff + m * 1024);
#pragma unroll
        for (int n = 0; n < 4; n++) bF[n] = *(const bf16x8*)(sm + dboff + boff + n * 1024);
        asm volatile("s_waitcnt lgkmcnt(0)" ::: "memory");
        __builtin_amdgcn_sched_barrier(0);
        __builtin_amdgcn_s_barrier();              // all waves done reading buf[cur]
        int nt = kt + 2; if (nt > 63) nt = 63;     // clamped tail restage (harmless)
        size_t koff = (size_t)nt * 64;
        __builtin_amdgcn_s_setprio(1);
#pragma unroll
        for (int m = 0; m < 4; m++)
            acc[m][0] = __builtin_amdgcn_mfma_f32_16x16x32_bf16(aF[m], bF[0], acc[m][0], 0, 0, 0);
        gload_lds16(gA + koff, wA + dboff);
#pragma unroll
        for (int m = 0; m < 4; m++)
            acc[m][1] = __builtin_amdgcn_mfma_f32_16x16x32_bf16(aF[m], bF[1], acc[m][1], 0, 0, 0);
        gload_lds16(gB0 + koff, wB0 + dboff);
#pragma unroll
        for (int m = 0; m < 4; m++)
            acc[m][2] = __builtin_amdgcn_mfma_f32_16x16x32_bf16(aF[m], bF[2], acc[m][2], 0, 0, 0);
        gload_lds16(gB1 + koff, wB1 + dboff);
#pragma unroll
        for (int m = 0; m < 4; m++)
            acc[m][3] = __builtin_amdgcn_mfma_f32_16x16x32_bf16(aF[m], bF[3], acc[m][3], 0, 0, 0);
        __builtin_amdgcn_s_setprio(0);
        asm volatile("s_waitcnt vmcnt(3)" ::: "memory");  // tile kt+1 resident; kt+2 in flight
        __builtin_amdgcn_s_barrier();
    }

    // epilogue: C[row=arow][col=brow], row=(lane>>4)*4+q, col=lane&15 within frag
    int orow = bm * 128 + wr * 64 + g * 4;
    int ocol = bn * 256 + wc * 64 + c;
    if (MODE == 0 || ocol < 2048) {
        float* o0 = (float*)ar.out0;
#pragma unroll
        for (int n = 0; n < 4; n++) {
            float bv = ar.bias0[ocol + n * 16];
#pragma unroll
            for (int m = 0; m < 4; m++)
#pragma unroll
                for (int q = 0; q < 4; q++)
                    o0[(size_t)(orow + m * 16 + q) * 2048 + ocol + n * 16] = acc[m][n][q] + bv;
        }
    } else {
        ushort_t* o1 = (ushort_t*)ar.out1;
        int col2 = ocol - 2048;
#pragma unroll
        for (int n = 0; n < 4; n++) {
            float bv = ar.bias1[col2 + n * 16];
#pragma unroll
            for (int m = 0; m < 4; m++)
#pragma unroll
                for (int q = 0; q < 4; q++)
                    o1[(size_t)(orow + m * 16 + q) * 2048 + col2 + n * 16] = f2b(acc[m][n][q] + bv);
        }
    }
}

// ---------------- fused RMSNorm + RoPE, fp32 in, bf16 out ----------------
__global__ __launch_bounds__(256) void k_rms_rope(const float* __restrict__ in,
                                                  const float* __restrict__ gain,
                                                  const float* __restrict__ freqs,
                                                  ushort_t* __restrict__ out,
                                                  int S, float oscale) {
    int row = blockIdx.x;
    int s = row % S;
    int tid = threadIdx.x;
    const float* p = in + (size_t)row * DIM + tid * 8;
    float4 a = *(const float4*)p;
    float4 b = *(const float4*)(p + 4);
    float y[8] = {a.x, a.y, a.z, a.w, b.x, b.y, b.z, b.w};
    float ss = 0.f;
#pragma unroll
    for (int j = 0; j < 8; j++) ss += y[j] * y[j];
#pragma unroll
    for (int off = 32; off > 0; off >>= 1) ss += __shfl_xor(ss, off, 64);
    __shared__ float red[4];
    int lane = tid & 63, wid = tid >> 6;
    if (lane == 0) red[wid] = ss;
    __syncthreads();
    float tot = red[0] + red[1] + red[2] + red[3];
    float inv = rsqrtf(tot * (1.0f / DIM) + 1e-6f);
    const float* g = gain + tid * 8;
    float4 g0 = *(const float4*)g;
    float4 g1 = *(const float4*)(g + 4);
    float gg[8] = {g0.x, g0.y, g0.z, g0.w, g1.x, g1.y, g1.z, g1.w};
    int p0 = (tid * 8 & 127) >> 1;
    const float* fq = freqs + ((size_t)s * 64 + p0) * 2;
    uint_t ow[4];
#pragma unroll
    for (int j = 0; j < 4; j++) {
        float fr = fq[j * 2 + 0], fi = fq[j * 2 + 1];
        float xr = y[2 * j] * inv * gg[2 * j];
        float xi = y[2 * j + 1] * inv * gg[2 * j + 1];
        float o0 = (xr * fr - xi * fi) * oscale;
        float o1 = (xr * fi + xi * fr) * oscale;
        ow[j] = (uint_t)f2b(o0) | ((uint_t)f2b(o1) << 16);
    }
    *(uint4*)(out + (size_t)row * DIM + tid * 8) = make_uint4(ow[0], ow[1], ow[2], ow[3]);
}

// ---------------- V transpose: vcam/vren (rows, DIM) -> vt[b,h,d=128,kv=1024] ----------------
__global__ __launch_bounds__(256) void k_vt(const ushort_t* __restrict__ vcam,
                                            const ushort_t* __restrict__ vren,
                                            ushort_t* __restrict__ vt) {
    __shared__ ushort_t t[64 * 136];
    int kt = blockIdx.x, h = blockIdx.y, b = blockIdx.z;
    int kv0 = kt * 64;
    const ushort_t* src = (kv0 < 512)
        ? vcam + ((size_t)(b * 512 + kv0)) * DIM + h * HD
        : vren + ((size_t)(b * 512 + kv0 - 512)) * DIM + h * HD;
    int tid = threadIdx.x;
#pragma unroll
    for (int i = 0; i < 4; i++) {
        int idx = i * 256 + tid;
        int kv = idx >> 4, c8 = idx & 15;
        uint4 v = *(const uint4*)(src + (size_t)kv * DIM + c8 * 8);
        *(uint4*)(t + kv * 136 + c8 * 8) = v;
    }
    __syncthreads();
    ushort_t* dst = vt + ((size_t)((b * NH + h) * HD)) * 1024 + kv0;
#pragma unroll
    for (int i = 0; i < 4; i++) {
        int idx = i * 256 + tid;
        int d = idx >> 3, c8 = idx & 7;
        ushort_t tmp[8];
#pragma unroll
        for (int j = 0; j < 8; j++) tmp[j] = t[(c8 * 8 + j) * 136 + d];
        uint4 o;
        o.x = (uint_t)tmp[0] | ((uint_t)tmp[1] << 16);
        o.y = (uint_t)tmp[2] | ((uint_t)tmp[3] << 16);
        o.z = (uint_t)tmp[4] | ((uint_t)tmp[5] << 16);
        o.w = (uint_t)tmp[6] | ((uint_t)tmp[7] << 16);
        *(uint4*)(dst + (size_t)d * 1024 + c8 * 8) = o;
    }
}

// ---------------- flash attention, swapped-QK^T, XCD-pinned, in-register P ----------------
__global__ __launch_bounds__(256, 4) void k_attn(const ushort_t* __restrict__ Q,
                                                 const ushort_t* __restrict__ Kc,
                                                 const ushort_t* __restrict__ Kr,
                                                 const ushort_t* __restrict__ Vt,
                                                 ushort_t* __restrict__ O) {
    __shared__ char smem[32768];
    ushort_t* lK = (ushort_t*)smem;
    ushort_t* lV = (ushort_t*)(smem + 16384);
    ushort_t* lO = (ushort_t*)smem;

    int tid = threadIdx.x, lane = tid & 63, wid = tid >> 6;
    int c = lane & 15, g = lane >> 4;

    int bid = blockIdx.x;
    int xcd = bid & 7, idx = bid >> 3;
    int combo = idx & 3, qt = idx >> 2;
    int b = combo >> 1, h = xcd * 2 + (combo & 1);
    int q0 = qt * 64 + wid * 16;

    const ushort_t* qg = Q + ((size_t)(b * 2048 + q0 + c)) * DIM + h * HD + g * 8;
    bf16x8 aQ[4];
#pragma unroll
    for (int ks = 0; ks < 4; ks++) aQ[ks] = *(const bf16x8*)(qg + ks * 32);

    float mr = -1e30f, lr = 0.f;
    f32x4 o[8];
#pragma unroll
    for (int d = 0; d < 8; d++) o[d] = (f32x4){0, 0, 0, 0};

    for (int kvt = 0; kvt < 16; ++kvt) {
        __syncthreads();
        int kv0 = kvt * 64;
        const ushort_t* kg = (kv0 < 512)
            ? Kc + ((size_t)(b * 512 + kv0)) * DIM + h * HD
            : Kr + ((size_t)(b * 512 + kv0 - 512)) * DIM + h * HD;
#pragma unroll
        for (int cc = 0; cc < 4; cc++) {
            int lrow = wid * 16 + cc * 4 + (lane >> 4);
            int sw = (lrow & 3) | (((lrow >> 3) & 3) << 2);
            int srcoff = ((lane & 15) ^ sw) << 4;
            gload_lds16((const char*)kg + (size_t)lrow * (DIM * 2) + srcoff,
                        lK + (wid * 16 + cc * 4) * 128);
        }
        const ushort_t* vg = Vt + ((size_t)((b * NH + h) * HD)) * 1024 + kv0;
#pragma unroll
        for (int cc = 0; cc < 4; cc++) {
            int vrow = wid * 32 + cc * 8 + (lane >> 3);
            int srcoff = ((lane & 7) ^ (vrow & 7)) << 4;
            gload_lds16((const char*)vg + (size_t)vrow * (1024 * 2) + srcoff,
                        lV + (wid * 32 + cc * 8) * 64);
        }
        __syncthreads();

        f32x4 sT[4];
#pragma unroll
        for (int n = 0; n < 4; n++) sT[n] = (f32x4){0, 0, 0, 0};
#pragma unroll
        for (int n = 0; n < 4; n++) {
            int row = ((n >> 1) << 5) + ((c >> 2) << 3) + ((n & 1) << 2) + (c & 3);
            int sw = (row & 3) | (((row >> 3) & 3) << 2);
#pragma unroll
            for (int ks = 0; ks < 4; ks++) {
                int chunk = (ks << 2) + g;
                int byt = row * 256 + ((chunk ^ sw) << 4);
                bf16x8 aK = *(const bf16x8*)((const char*)lK + byt);
                sT[n] = __builtin_amdgcn_mfma_f32_16x16x32_bf16(aK, aQ[ks], sT[n], 0, 0, 0);
            }
        }

        float mloc = sT[0][0];
#pragma unroll
        for (int n = 0; n < 4; n++)
#pragma unroll
            for (int r = 0; r < 4; r++) mloc = fmaxf(mloc, sT[n][r]);
        mloc = fmaxf(mloc, __shfl_xor(mloc, 16, 64));
        mloc = fmaxf(mloc, __shfl_xor(mloc, 32, 64));
        float mn = fmaxf(mr, mloc);
        float alpha = exp2f(mr - mn);
        mr = mn;
        float p[4][4];
        float ps = 0.f;
#pragma unroll
        for (int n = 0; n < 4; n++)
#pragma unroll
            for (int r = 0; r < 4; r++) {
                p[n][r] = exp2f(sT[n][r] - mn);
                ps += p[n][r];
            }
        ps += __shfl_xor(ps, 16, 64);
        ps += __shfl_xor(ps, 32, 64);
        lr = lr * alpha + ps;
#pragma unroll
        for (int d = 0; d < 8; d++) o[d] *= alpha;

#pragma unroll
        for (int kk = 0; kk < 2; kk++) {
            union { uint_t u[4]; bf16x8 v; } bP;
            bP.u[0] = cvt_pk_bf16(p[2 * kk][0], p[2 * kk][1]);
            bP.u[1] = cvt_pk_bf16(p[2 * kk][2], p[2 * kk][3]);
            bP.u[2] = cvt_pk_bf16(p[2 * kk + 1][0], p[2 * kk + 1][1]);
            bP.u[3] = cvt_pk_bf16(p[2 * kk + 1][2], p[2 * kk + 1][3]);
#pragma unroll
            for (int dt = 0; dt < 8; dt++) {
                int vrow = dt * 16 + c;
                int chunk = (kk << 2) + g;
                int byt = vrow * 128 + ((chunk ^ (vrow & 7)) << 4);
                bf16x8 aV = *(const bf16x8*)((const char*)lV + byt);
                o[dt] = __builtin_amdgcn_mfma_f32_16x16x32_bf16(aV, bP.v, o[dt], 0, 0, 0);
            }
        }
    }

    __syncthreads();
    float inv = 1.0f / lr;
#pragma unroll
    for (int dt = 0; dt < 8; dt++) {
        uint2 w;
        w.x = (uint_t)f2b(o[dt][0] * inv) | ((uint_t)f2b(o[dt][1] * inv) << 16);
        w.y = (uint_t)f2b(o[dt][2] * inv) | ((uint_t)f2b(o[dt][3] * inv) << 16);
        *(uint2*)(lO + (wid * 16 + c) * 136 + dt * 16 + g * 4) = w;
    }
    __syncthreads();
    int row = tid >> 2, c8 = tid & 3;
    const ushort_t* src = lO + row * 136 + c8 * 32;
    ushort_t* dst = O + (size_t)(b * 2048 + qt * 64 + row) * DIM + h * HD + c8 * 32;
#pragma unroll
    for (int k = 0; k < 4; k++) *(uint4*)(dst + k * 8) = *(const uint4*)(src + k * 8);
}

extern "C" void kernel_launch(void* const* d_in, const int* in_sizes, int n_in,
                              void* d_out, int out_size, void* d_ws, size_t ws_size,
                              hipStream_t stream) {
    const float* x   = (const float*)d_in[0];
    const float* cam = (const float*)d_in[1];
    const float* ren = (const float*)d_in[2];
    const float* fx  = (const float*)d_in[3];
    const float* fc  = (const float*)d_in[4];
    const float* fr  = (const float*)d_in[5];
    const float* wq  = (const float*)d_in[6];
    const float* bq  = (const float*)d_in[7];
    const float* wk  = (const float*)d_in[8];
    const float* bk  = (const float*)d_in[9];
    const float* wv  = (const float*)d_in[10];
    const float* bv  = (const float*)d_in[11];
    const float* wkr = (const float*)d_in[12];
    const float* bkr = (const float*)d_in[13];
    const float* wvr = (const float*)d_in[14];
    const float* bvr = (const float*)d_in[15];
    const float* wo  = (const float*)d_in[16];
    const float* bo  = (const float*)d_in[17];
    const float* gq  = (const float*)d_in[18];
    const float* gk  = (const float*)d_in[19];

    char* ws = (char*)d_ws;
    ushort_t* wq_b     = (ushort_t*)(ws + 0);
    ushort_t* wk_b     = (ushort_t*)(ws + 8388608);   // wk||wv contiguous (N=4096)
    ushort_t* wkr_b    = (ushort_t*)(ws + 25165824);  // wkr||wvr contiguous (N=4096)
    ushort_t* wo_b     = (ushort_t*)(ws + 41943040);
    ushort_t* xb       = (ushort_t*)(ws + 50331648);  // 16.8MB; reused by attn_bf later
    ushort_t* camb     = (ushort_t*)(ws + 67108864);
    ushort_t* renb     = (ushort_t*)(ws + 71303168);
    float*    kcam_lin = (float*)(ws + 75497472);     // 8.4MB; region reused by vt later
    float*    kren_lin = (float*)(ws + 83886080);
    ushort_t* q_bf     = (ushort_t*)(ws + 92274688);
    ushort_t* kcam_bf  = (ushort_t*)(ws + 109051904);
    ushort_t* kren_bf  = (ushort_t*)(ws + 113246208);
    ushort_t* vcam_bf  = (ushort_t*)(ws + 117440512);
    ushort_t* vren_bf  = (ushort_t*)(ws + 121634816);
    ushort_t* vt       = (ushort_t*)(ws + 75497472);  // overlays dead kcam_lin/kren_lin
    ushort_t* attn_bf  = (ushort_t*)(ws + 50331648);  // overlays dead xb
    float*    q_lin    = (float*)d_out;               // d_out doubles as Q-proj scratch

    // fp32 -> bf16 converts
    CvtWArgs cw{{wq, wk, wv, wkr, wvr, wo}};
    k_cvtw<<<dim3(2048, 6), 256, 0, stream>>>(cw, wq_b);
    k_cvt<<<4096, 256, 0, stream>>>(x, xb, 8388608);
    k_cvt<<<1024, 256, 0, stream>>>(cam, camb, 2097152);
    k_cvt<<<1024, 256, 0, stream>>>(ren, renb, 2097152);

    // Q projection -> fp32 scratch (d_out), then RMSNorm+RoPE; fold (1/sqrt(HD))*log2(e)
    G8 qa{xb, wq_b, bq, nullptr, (void*)q_lin, nullptr};
    k_gemm8<0><<<dim3(32, 8, 1), 512, 0, stream>>>(qa, qa);
    k_rms_rope<<<4096, 256, 0, stream>>>(q_lin, gq, fx, q_bf, 2048,
                                         0.08838834764831845f * 1.4426950408889634f);

    // K+V projections fused: N=4096 split output (K fp32, V bf16), cam/ren in z
    G8 kva0{camb, wk_b, bk, bv, (void*)kcam_lin, (void*)vcam_bf};
    G8 kva1{renb, wkr_b, bkr, bvr, (void*)kren_lin, (void*)vren_bf};
    k_gemm8<2><<<dim3(8, 16, 2), 512, 0, stream>>>(kva0, kva1);
    k_rms_rope<<<1024, 256, 0, stream>>>(kcam_lin, gk, fc, kcam_bf, 512, 1.0f);
    k_rms_rope<<<1024, 256, 0, stream>>>(kren_lin, gk, fr, kren_bf, 512, 1.0f);
    k_vt<<<dim3(16, 16, 2), 256, 0, stream>>>(vcam_bf, vren_bf, vt);

    // flash attention (flat grid, XCD-pinned decode in-kernel)
    k_attn<<<dim3(1024, 1, 1), 256, 0, stream>>>(q_bf, kcam_bf, kren_bf, vt, attn_bf);

    // output projection -> d_out (fp32)
    G8 oa{attn_bf, wo_b, bo, nullptr, d_out, nullptr};
    k_gemm8<0><<<dim3(32, 8, 1), 512, 0, stream>>>(oa, oa);
}

// Round 5
// 254.194 us; speedup vs baseline: 1.5862x; 1.0647x over previous
//
#include <hip/hip_runtime.h>

typedef short bf16x8 __attribute__((ext_vector_type(8)));
typedef float f32x4 __attribute__((ext_vector_type(4)));
typedef unsigned short ushort_t;
typedef unsigned int uint_t;

#define DIM 2048
#define NH 16
#define HD 128

__device__ __forceinline__ ushort_t f2b(float f) {
    union { float f; uint_t u; } a; a.f = f;
    uint_t u = a.u;
    return (ushort_t)((u + 0x7fffu + ((u >> 16) & 1u)) >> 16);
}

__device__ __forceinline__ uint_t cvt_pk_bf16(float lo, float hi) {
    uint_t r;
    asm("v_cvt_pk_bf16_f32 %0, %1, %2" : "=v"(r) : "v"(lo), "v"(hi));
    return r;
}

__device__ __forceinline__ void gload_lds16(const void* g, void* l) {
    void* gg = const_cast<void*>(g);
    __builtin_amdgcn_global_load_lds(
        (__attribute__((address_space(1))) uint_t*)gg,
        (__attribute__((address_space(3))) uint_t*)l, 16, 0, 0);
}

// ---------------- fp32 -> bf16 convert (generic) ----------------
__global__ __launch_bounds__(256) void k_cvt(const float* __restrict__ in,
                                             ushort_t* __restrict__ out, int n) {
    int idx = (blockIdx.x * 256 + threadIdx.x) * 8;
    if (idx >= n) return;
    float4 a = *(const float4*)(in + idx);
    float4 b = *(const float4*)(in + idx + 4);
    uint4 o;
    o.x = (uint_t)f2b(a.x) | ((uint_t)f2b(a.y) << 16);
    o.y = (uint_t)f2b(a.z) | ((uint_t)f2b(a.w) << 16);
    o.z = (uint_t)f2b(b.x) | ((uint_t)f2b(b.y) << 16);
    o.w = (uint_t)f2b(b.z) | ((uint_t)f2b(b.w) << 16);
    *(uint4*)(out + idx) = o;
}

// ---------------- batched weight convert: 6 x (2048*2048) into contiguous dst ----------------
struct CvtWArgs { const float* s[6]; };
__global__ __launch_bounds__(256) void k_cvtw(CvtWArgs a, ushort_t* __restrict__ dst) {
    int y = blockIdx.y;
    const float* in = a.s[y];
    ushort_t* out = dst + (size_t)y * 4194304;
    int idx = (blockIdx.x * 256 + threadIdx.x) * 8;
    float4 p = *(const float4*)(in + idx);
    float4 q = *(const float4*)(in + idx + 4);
    uint4 o;
    o.x = (uint_t)f2b(p.x) | ((uint_t)f2b(p.y) << 16);
    o.y = (uint_t)f2b(p.z) | ((uint_t)f2b(p.w) << 16);
    o.z = (uint_t)f2b(q.x) | ((uint_t)f2b(q.y) << 16);
    o.w = (uint_t)f2b(q.z) | ((uint_t)f2b(q.w) << 16);
    *(uint4*)(out + idx) = o;
}

// ---------------- pipelined bf16 NT GEMM, BM=128 BN=256 BK=32, 512 thr ----------------
struct G8 {
    const ushort_t* A;
    const ushort_t* B;
    const float* bias0;
    const float* bias1;
    void* out0;
    void* out1;
};

template<int MODE>
__global__ __launch_bounds__(512, 2) void k_gemm8(G8 a0, G8 a1) {
    __shared__ __align__(16) char sm[49152];
    int tid = threadIdx.x, lane = tid & 63, wid = tid >> 6;
    int c = lane & 15, g = lane >> 4;
    int wr = wid >> 2, wc = wid & 3;

    int flat = blockIdx.x + blockIdx.y * gridDim.x;
    int qq = (gridDim.x * gridDim.y) >> 3;
    int re = (flat & 7) * qq + (flat >> 3);
    int bm = re % gridDim.x, bn = re / gridDim.x;

    G8 ar = blockIdx.z ? a1 : a0;

    int chunk = ((tid & 3) ^ ((tid >> 3) & 3)) << 4;
    const char* gA  = (const char*)ar.A + (size_t)(bm * 128 + (tid >> 2)) * (DIM * 2) + chunk;
    const char* gB0 = (const char*)ar.B + (size_t)(bn * 256 + (tid >> 2)) * (DIM * 2) + chunk;
    const char* gB1 = gB0 + (size_t)128 * (DIM * 2);
    char* wA  = sm + wid * 1024;
    char* wB0 = sm + 8192 + wid * 1024;
    char* wB1 = sm + 16384 + wid * 1024;

    f32x4 acc[4][4];
#pragma unroll
    for (int m = 0; m < 4; m++)
#pragma unroll
        for (int n = 0; n < 4; n++) acc[m][n] = (f32x4){0.f, 0.f, 0.f, 0.f};

    gload_lds16(gA, wA);
    gload_lds16(gB0, wB0);
    gload_lds16(gB1, wB1);
    gload_lds16(gA + 64, wA + 24576);
    gload_lds16(gB0 + 64, wB0 + 24576);
    gload_lds16(gB1 + 64, wB1 + 24576);
    asm volatile("s_waitcnt vmcnt(3)" ::: "memory");
    __builtin_amdgcn_s_barrier();

    int arow = wr * 64 + c;
    int aoff = arow * 64 + ((g ^ ((arow >> 1) & 3)) << 4);
    int brow = wc * 64 + c;
    int boff = 8192 + brow * 64 + ((g ^ ((brow >> 1) & 3)) << 4);

    for (int kt = 0; kt < 64; ++kt) {
        int dboff = (kt & 1) * 24576;
        bf16x8 aF[4], bF[4];
#pragma unroll
        for (int m = 0; m < 4; m++) aF[m] = *(const bf16x8*)(sm + dboff + aoff + m * 1024);
#pragma unroll
        for (int n = 0; n < 4; n++) bF[n] = *(const bf16x8*)(sm + dboff + boff + n * 1024);
        asm volatile("s_waitcnt lgkmcnt(0)" ::: "memory");
        __builtin_amdgcn_sched_barrier(0);
        __builtin_amdgcn_s_barrier();
        int nt = kt + 2; if (nt > 63) nt = 63;
        size_t koff = (size_t)nt * 64;
        __builtin_amdgcn_s_setprio(1);
#pragma unroll
        for (int m = 0; m < 4; m++)
            acc[m][0] = __builtin_amdgcn_mfma_f32_16x16x32_bf16(aF[m], bF[0], acc[m][0], 0, 0, 0);
        gload_lds16(gA + koff, wA + dboff);
#pragma unroll
        for (int m = 0; m < 4; m++)
            acc[m][1] = __builtin_amdgcn_mfma_f32_16x16x32_bf16(aF[m], bF[1], acc[m][1], 0, 0, 0);
        gload_lds16(gB0 + koff, wB0 + dboff);
#pragma unroll
        for (int m = 0; m < 4; m++)
            acc[m][2] = __builtin_amdgcn_mfma_f32_16x16x32_bf16(aF[m], bF[2], acc[m][2], 0, 0, 0);
        gload_lds16(gB1 + koff, wB1 + dboff);
#pragma unroll
        for (int m = 0; m < 4; m++)
            acc[m][3] = __builtin_amdgcn_mfma_f32_16x16x32_bf16(aF[m], bF[3], acc[m][3], 0, 0, 0);
        __builtin_amdgcn_s_setprio(0);
        asm volatile("s_waitcnt vmcnt(3)" ::: "memory");
        __builtin_amdgcn_s_barrier();
    }

    int orow = bm * 128 + wr * 64 + g * 4;
    int ocol = bn * 256 + wc * 64 + c;
    if (MODE == 0 || ocol < 2048) {
        float* o0 = (float*)ar.out0;
#pragma unroll
        for (int n = 0; n < 4; n++) {
            float bv = ar.bias0[ocol + n * 16];
#pragma unroll
            for (int m = 0; m < 4; m++)
#pragma unroll
                for (int q = 0; q < 4; q++)
                    o0[(size_t)(orow + m * 16 + q) * 2048 + ocol + n * 16] = acc[m][n][q] + bv;
        }
    } else {
        ushort_t* o1 = (ushort_t*)ar.out1;
        int col2 = ocol - 2048;
#pragma unroll
        for (int n = 0; n < 4; n++) {
            float bv = ar.bias1[col2 + n * 16];
#pragma unroll
            for (int m = 0; m < 4; m++)
#pragma unroll
                for (int q = 0; q < 4; q++)
                    o1[(size_t)(orow + m * 16 + q) * 2048 + col2 + n * 16] = f2b(acc[m][n][q] + bv);
        }
    }
}

// ---------------- fused RMSNorm + RoPE, fp32 in, bf16 out ----------------
__global__ __launch_bounds__(256) void k_rms_rope(const float* __restrict__ in,
                                                  const float* __restrict__ gain,
                                                  const float* __restrict__ freqs,
                                                  ushort_t* __restrict__ out,
                                                  int S, float oscale) {
    int row = blockIdx.x;
    int s = row % S;
    int tid = threadIdx.x;
    const float* p = in + (size_t)row * DIM + tid * 8;
    float4 a = *(const float4*)p;
    float4 b = *(const float4*)(p + 4);
    float y[8] = {a.x, a.y, a.z, a.w, b.x, b.y, b.z, b.w};
    float ss = 0.f;
#pragma unroll
    for (int j = 0; j < 8; j++) ss += y[j] * y[j];
#pragma unroll
    for (int off = 32; off > 0; off >>= 1) ss += __shfl_xor(ss, off, 64);
    __shared__ float red[4];
    int lane = tid & 63, wid = tid >> 6;
    if (lane == 0) red[wid] = ss;
    __syncthreads();
    float tot = red[0] + red[1] + red[2] + red[3];
    float inv = rsqrtf(tot * (1.0f / DIM) + 1e-6f);
    const float* g = gain + tid * 8;
    float4 g0 = *(const float4*)g;
    float4 g1 = *(const float4*)(g + 4);
    float gg[8] = {g0.x, g0.y, g0.z, g0.w, g1.x, g1.y, g1.z, g1.w};
    int p0 = (tid * 8 & 127) >> 1;
    const float* fq = freqs + ((size_t)s * 64 + p0) * 2;
    uint_t ow[4];
#pragma unroll
    for (int j = 0; j < 4; j++) {
        float fr = fq[j * 2 + 0], fi = fq[j * 2 + 1];
        float xr = y[2 * j] * inv * gg[2 * j];
        float xi = y[2 * j + 1] * inv * gg[2 * j + 1];
        float o0 = (xr * fr - xi * fi) * oscale;
        float o1 = (xr * fi + xi * fr) * oscale;
        ow[j] = (uint_t)f2b(o0) | ((uint_t)f2b(o1) << 16);
    }
    *(uint4*)(out + (size_t)row * DIM + tid * 8) = make_uint4(ow[0], ow[1], ow[2], ow[3]);
}

// ---------------- V transpose: vcam/vren (rows, DIM) -> vt[b,h,d=128,kv=1024] ----------------
__global__ __launch_bounds__(256) void k_vt(const ushort_t* __restrict__ vcam,
                                            const ushort_t* __restrict__ vren,
                                            ushort_t* __restrict__ vt) {
    __shared__ ushort_t t[64 * 136];
    int kt = blockIdx.x, h = blockIdx.y, b = blockIdx.z;
    int kv0 = kt * 64;
    const ushort_t* src = (kv0 < 512)
        ? vcam + ((size_t)(b * 512 + kv0)) * DIM + h * HD
        : vren + ((size_t)(b * 512 + kv0 - 512)) * DIM + h * HD;
    int tid = threadIdx.x;
#pragma unroll
    for (int i = 0; i < 4; i++) {
        int idx = i * 256 + tid;
        int kv = idx >> 4, c8 = idx & 15;
        uint4 v = *(const uint4*)(src + (size_t)kv * DIM + c8 * 8);
        *(uint4*)(t + kv * 136 + c8 * 8) = v;
    }
    __syncthreads();
    ushort_t* dst = vt + ((size_t)((b * NH + h) * HD)) * 1024 + kv0;
#pragma unroll
    for (int i = 0; i < 4; i++) {
        int idx = i * 256 + tid;
        int d = idx >> 3, c8 = idx & 7;
        ushort_t tmp[8];
#pragma unroll
        for (int j = 0; j < 8; j++) tmp[j] = t[(c8 * 8 + j) * 136 + d];
        uint4 o;
        o.x = (uint_t)tmp[0] | ((uint_t)tmp[1] << 16);
        o.y = (uint_t)tmp[2] | ((uint_t)tmp[3] << 16);
        o.z = (uint_t)tmp[4] | ((uint_t)tmp[5] << 16);
        o.w = (uint_t)tmp[6] | ((uint_t)tmp[7] << 16);
        *(uint4*)(dst + (size_t)d * 1024 + c8 * 8) = o;
    }
}

// ---------------- flash attention: 8 waves, 128 q-rows/block, double-buffered K/V ----------------
// swapped-QK^T (S^T = K x Q^T), in-register P, XCD-pinned, defer-max.
// Q pre-scaled by (1/sqrt(HD))*log2(e); softmax uses exp2.
__global__ __launch_bounds__(512, 4) void k_attn(const ushort_t* __restrict__ Q,
                                                 const ushort_t* __restrict__ Kc,
                                                 const ushort_t* __restrict__ Kr,
                                                 const ushort_t* __restrict__ Vt,
                                                 ushort_t* __restrict__ O) {
    // buffer d at d*32768: K[64][128] (16KB) then V[128][64] (16KB); chunk-swizzled
    __shared__ __align__(16) char sm[65536];
    int tid = threadIdx.x, lane = tid & 63, w = tid >> 6;
    int c = lane & 15, g = lane >> 4;

    // XCD-pinned decode: xcd owns 4 (h,b) combos x 16 q-tiles (128 rows each)
    int bid = blockIdx.x;
    int xcd = bid & 7, idx = bid >> 3;
    int combo = idx & 3, qt = idx >> 2;
    int b = combo >> 1, h = xcd * 2 + (combo & 1);

    // Q fragment (B-operand of S^T mfma): lane holds Q[q=c][d = ks*32 + g*8 + j]
    const ushort_t* qg = Q + ((size_t)(b * 2048 + qt * 128 + w * 16 + c)) * DIM + h * HD + g * 8;
    bf16x8 aQ[4];
#pragma unroll
    for (int ks = 0; ks < 4; ks++) aQ[ks] = *(const bf16x8*)(qg + ks * 32);

    // loop-invariant ds_read byte offsets: addr(n,ks) = kbase[n]^(ks<<6); addr(kk,dt)=vbase[dt]^(kk<<6)
    int kbase[4], vbase[8];
#pragma unroll
    for (int n = 0; n < 4; n++) {
        int row = ((n >> 1) << 5) + ((c >> 2) << 3) + ((n & 1) << 2) + (c & 3);
        int sw = (row & 3) | (((row >> 3) & 3) << 2);
        kbase[n] = row * 256 + ((g ^ sw) << 4);
    }
#pragma unroll
    for (int dt = 0; dt < 8; dt++) {
        int vrow = dt * 16 + c;
        vbase[dt] = vrow * 128 + ((g ^ (vrow & 7)) << 4);
    }

    // loop-invariant staging lane offsets (wave w stages K rows 8w..8w+7, V rows 16w..16w+15)
    int swk = (lane >> 4) | ((w & 3) << 2);
    size_t klo = (size_t)(8 * w + (lane >> 4)) * 4096 + (size_t)(((lane & 15) ^ swk) << 4);
    size_t vlo = (size_t)(16 * w + (lane >> 3)) * 2048 + (size_t)(((lane & 7) ^ (lane >> 3)) << 4);
    int dst0 = w * 2048;

    const char* kc0 = (const char*)Kc + ((size_t)(b * 512) * DIM + h * HD) * 2;
    const char* kr0 = (const char*)Kr + ((size_t)(b * 512) * DIM + h * HD) * 2;
    const char* vtb = (const char*)Vt + ((size_t)((b * NH + h) * HD)) * 2048;

    float mr = -1e30f, lr = 0.f;
    f32x4 o[8];
#pragma unroll
    for (int d = 0; d < 8; d++) o[d] = (f32x4){0, 0, 0, 0};

    auto STAGE = [&](int DB, int t) {
        const char* kg = (t < 8) ? kc0 + (size_t)t * 262144 : kr0 + (size_t)(t - 8) * 262144;
        const char* vg = vtb + (size_t)t * 128;
        gload_lds16(kg + klo, sm + DB + dst0);
        gload_lds16(kg + klo + 16384, sm + DB + dst0 + 1024);
        gload_lds16(vg + vlo, sm + DB + 16384 + dst0);
        gload_lds16(vg + vlo + 16384, sm + DB + 16384 + dst0 + 1024);
    };

    auto TILE = [&](int DB) {
        f32x4 sT[4];
#pragma unroll
        for (int n = 0; n < 4; n++) sT[n] = (f32x4){0, 0, 0, 0};
#pragma unroll
        for (int n = 0; n < 4; n++)
#pragma unroll
            for (int ks = 0; ks < 4; ks++) {
                bf16x8 aK = *(const bf16x8*)(sm + DB + (kbase[n] ^ (ks << 6)));
                sT[n] = __builtin_amdgcn_mfma_f32_16x16x32_bf16(aK, aQ[ks], sT[n], 0, 0, 0);
            }
        float mloc = sT[0][0];
#pragma unroll
        for (int n = 0; n < 4; n++)
#pragma unroll
            for (int r = 0; r < 4; r++) mloc = fmaxf(mloc, sT[n][r]);
        mloc = fmaxf(mloc, __shfl_xor(mloc, 16, 64));
        mloc = fmaxf(mloc, __shfl_xor(mloc, 32, 64));
        if (!__all(mloc - mr <= 8.0f)) {   // defer-max: rescale only on real growth
            float mn = fmaxf(mr, mloc);
            float al = exp2f(mr - mn);
            mr = mn;
            lr *= al;
#pragma unroll
            for (int d = 0; d < 8; d++) o[d] *= al;
        }
        float p[4][4];
        float ps = 0.f;
#pragma unroll
        for (int n = 0; n < 4; n++)
#pragma unroll
            for (int r = 0; r < 4; r++) {
                p[n][r] = exp2f(sT[n][r] - mr);
                ps += p[n][r];
            }
        ps += __shfl_xor(ps, 16, 64);
        ps += __shfl_xor(ps, 32, 64);
        lr += ps;
#pragma unroll
        for (int kk = 0; kk < 2; kk++) {
            union { uint_t u[4]; bf16x8 v; } bP;
            bP.u[0] = cvt_pk_bf16(p[2 * kk][0], p[2 * kk][1]);
            bP.u[1] = cvt_pk_bf16(p[2 * kk][2], p[2 * kk][3]);
            bP.u[2] = cvt_pk_bf16(p[2 * kk + 1][0], p[2 * kk + 1][1]);
            bP.u[3] = cvt_pk_bf16(p[2 * kk + 1][2], p[2 * kk + 1][3]);
#pragma unroll
            for (int dt = 0; dt < 8; dt++) {
                bf16x8 aV = *(const bf16x8*)(sm + DB + 16384 + (vbase[dt] ^ (kk << 6)));
                o[dt] = __builtin_amdgcn_mfma_f32_16x16x32_bf16(aV, bP.v, o[dt], 0, 0, 0);
            }
        }
    };

    STAGE(0, 0);
    __syncthreads();
#pragma unroll 1
    for (int t = 0; t < 16; t += 2) {
        STAGE(32768, t + 1);      // prefetch odd tile into buf1
        TILE(0);                  // compute even tile from buf0
        __syncthreads();          // drains vmcnt (prefetch landed) + read-done
        if (t < 14) STAGE(0, t + 2);
        TILE(32768);
        __syncthreads();
    }

    // epilogue: lane holds O[d = dt*16 + g*4 + r][q = c]. Stage in LDS, write full lines.
    float inv = 1.0f / lr;
    ushort_t* lO = (ushort_t*)sm;
#pragma unroll
    for (int dt = 0; dt < 8; dt++) {
        uint2 wv;
        wv.x = (uint_t)f2b(o[dt][0] * inv) | ((uint_t)f2b(o[dt][1] * inv) << 16);
        wv.y = (uint_t)f2b(o[dt][2] * inv) | ((uint_t)f2b(o[dt][3] * inv) << 16);
        *(uint2*)(lO + (w * 16 + c) * 136 + dt * 16 + g * 4) = wv;
    }
    __syncthreads();
    int row = tid >> 2, c8 = tid & 3;
    const ushort_t* src = lO + row * 136 + c8 * 32;
    ushort_t* dst = O + (size_t)(b * 2048 + qt * 128 + row) * DIM + h * HD + c8 * 32;
#pragma unroll
    for (int k = 0; k < 4; k++) *(uint4*)(dst + k * 8) = *(const uint4*)(src + k * 8);
}

extern "C" void kernel_launch(void* const* d_in, const int* in_sizes, int n_in,
                              void* d_out, int out_size, void* d_ws, size_t ws_size,
                              hipStream_t stream) {
    const float* x   = (const float*)d_in[0];
    const float* cam = (const float*)d_in[1];
    const float* ren = (const float*)d_in[2];
    const float* fx  = (const float*)d_in[3];
    const float* fc  = (const float*)d_in[4];
    const float* fr  = (const float*)d_in[5];
    const float* wq  = (const float*)d_in[6];
    const float* bq  = (const float*)d_in[7];
    const float* wk  = (const float*)d_in[8];
    const float* bk  = (const float*)d_in[9];
    const float* wv  = (const float*)d_in[10];
    const float* bv  = (const float*)d_in[11];
    const float* wkr = (const float*)d_in[12];
    const float* bkr = (const float*)d_in[13];
    const float* wvr = (const float*)d_in[14];
    const float* bvr = (const float*)d_in[15];
    const float* wo  = (const float*)d_in[16];
    const float* bo  = (const float*)d_in[17];
    const float* gq  = (const float*)d_in[18];
    const float* gk  = (const float*)d_in[19];

    char* ws = (char*)d_ws;
    ushort_t* wq_b     = (ushort_t*)(ws + 0);
    ushort_t* wk_b     = (ushort_t*)(ws + 8388608);   // wk||wv contiguous (N=4096)
    ushort_t* wkr_b    = (ushort_t*)(ws + 25165824);  // wkr||wvr contiguous (N=4096)
    ushort_t* wo_b     = (ushort_t*)(ws + 41943040);
    ushort_t* xb       = (ushort_t*)(ws + 50331648);  // 16.8MB; reused by attn_bf later
    ushort_t* camb     = (ushort_t*)(ws + 67108864);
    ushort_t* renb     = (ushort_t*)(ws + 71303168);
    float*    kcam_lin = (float*)(ws + 75497472);     // 8.4MB; region reused by vt later
    float*    kren_lin = (float*)(ws + 83886080);
    ushort_t* q_bf     = (ushort_t*)(ws + 92274688);
    ushort_t* kcam_bf  = (ushort_t*)(ws + 109051904);
    ushort_t* kren_bf  = (ushort_t*)(ws + 113246208);
    ushort_t* vcam_bf  = (ushort_t*)(ws + 117440512);
    ushort_t* vren_bf  = (ushort_t*)(ws + 121634816);
    ushort_t* vt       = (ushort_t*)(ws + 75497472);  // overlays dead kcam_lin/kren_lin
    ushort_t* attn_bf  = (ushort_t*)(ws + 50331648);  // overlays dead xb
    float*    q_lin    = (float*)d_out;               // d_out doubles as Q-proj scratch

    // fp32 -> bf16 converts
    CvtWArgs cw{{wq, wk, wv, wkr, wvr, wo}};
    k_cvtw<<<dim3(2048, 6), 256, 0, stream>>>(cw, wq_b);
    k_cvt<<<4096, 256, 0, stream>>>(x, xb, 8388608);
    k_cvt<<<1024, 256, 0, stream>>>(cam, camb, 2097152);
    k_cvt<<<1024, 256, 0, stream>>>(ren, renb, 2097152);

    // Q projection -> fp32 scratch (d_out), then RMSNorm+RoPE; fold (1/sqrt(HD))*log2(e)
    G8 qa{xb, wq_b, bq, nullptr, (void*)q_lin, nullptr};
    k_gemm8<0><<<dim3(32, 8, 1), 512, 0, stream>>>(qa, qa);
    k_rms_rope<<<4096, 256, 0, stream>>>(q_lin, gq, fx, q_bf, 2048,
                                         0.08838834764831845f * 1.4426950408889634f);

    // K+V projections fused: N=4096 split output (K fp32, V bf16), cam/ren in z
    G8 kva0{camb, wk_b, bk, bv, (void*)kcam_lin, (void*)vcam_bf};
    G8 kva1{renb, wkr_b, bkr, bvr, (void*)kren_lin, (void*)vren_bf};
    k_gemm8<2><<<dim3(8, 16, 2), 512, 0, stream>>>(kva0, kva1);
    k_rms_rope<<<1024, 256, 0, stream>>>(kcam_lin, gk, fc, kcam_bf, 512, 1.0f);
    k_rms_rope<<<1024, 256, 0, stream>>>(kren_lin, gk, fr, kren_bf, 512, 1.0f);
    k_vt<<<dim3(16, 16, 2), 256, 0, stream>>>(vcam_bf, vren_bf, vt);

    // flash attention (flat grid 512, XCD-pinned decode in-kernel, 128 q-rows/block)
    k_attn<<<dim3(512, 1, 1), 512, 0, stream>>>(q_bf, kcam_bf, kren_bf, vt, attn_bf);

    // output projection -> d_out (fp32)
    G8 oa{attn_bf, wo_b, bo, nullptr, d_out, nullptr};
    k_gemm8<0><<<dim3(32, 8, 1), 512, 0, stream>>>(oa, oa);
}

// Round 6
// 253.378 us; speedup vs baseline: 1.5913x; 1.0032x over previous
//
#include <hip/hip_runtime.h>

typedef short bf16x8 __attribute__((ext_vector_type(8)));
typedef float f32x4 __attribute__((ext_vector_type(4)));
typedef unsigned short ushort_t;
typedef unsigned int uint_t;

#define DIM 2048
#define NH 16
#define HD 128

__device__ __forceinline__ ushort_t f2b(float f) {
    union { float f; uint_t u; } a; a.f = f;
    uint_t u = a.u;
    return (ushort_t)((u + 0x7fffu + ((u >> 16) & 1u)) >> 16);
}

__device__ __forceinline__ uint_t cvt_pk_bf16(float lo, float hi) {
    uint_t r;
    asm("v_cvt_pk_bf16_f32 %0, %1, %2" : "=v"(r) : "v"(lo), "v"(hi));
    return r;
}

__device__ __forceinline__ void gload_lds16(const void* g, void* l) {
    void* gg = const_cast<void*>(g);
    __builtin_amdgcn_global_load_lds(
        (__attribute__((address_space(1))) uint_t*)gg,
        (__attribute__((address_space(3))) uint_t*)l, 16, 0, 0);
}

// ---------------- batched weight convert: 6 x (2048*2048) into contiguous dst ----------------
struct CvtWArgs { const float* s[6]; };
__global__ __launch_bounds__(256) void k_cvtw(CvtWArgs a, ushort_t* __restrict__ dst) {
    int y = blockIdx.y;
    const float* in = a.s[y];
    ushort_t* out = dst + (size_t)y * 4194304;
    int idx = (blockIdx.x * 256 + threadIdx.x) * 8;
    float4 p = *(const float4*)(in + idx);
    float4 q = *(const float4*)(in + idx + 4);
    uint4 o;
    o.x = (uint_t)f2b(p.x) | ((uint_t)f2b(p.y) << 16);
    o.y = (uint_t)f2b(p.z) | ((uint_t)f2b(p.w) << 16);
    o.z = (uint_t)f2b(q.x) | ((uint_t)f2b(q.y) << 16);
    o.w = (uint_t)f2b(q.z) | ((uint_t)f2b(q.w) << 16);
    *(uint4*)(out + idx) = o;
}

// ---------------- activation converts: x / cam / ren in one dispatch ----------------
struct Cvt3Args { const float* s[3]; ushort_t* d[3]; int n[3]; };
__global__ __launch_bounds__(256) void k_cvt3(Cvt3Args a) {
    int y = blockIdx.y;
    int idx = (blockIdx.x * 256 + threadIdx.x) * 8;
    if (idx >= a.n[y]) return;
    const float* in = a.s[y];
    ushort_t* out = a.d[y];
    float4 p = *(const float4*)(in + idx);
    float4 q = *(const float4*)(in + idx + 4);
    uint4 o;
    o.x = (uint_t)f2b(p.x) | ((uint_t)f2b(p.y) << 16);
    o.y = (uint_t)f2b(p.z) | ((uint_t)f2b(p.w) << 16);
    o.z = (uint_t)f2b(q.x) | ((uint_t)f2b(q.y) << 16);
    o.w = (uint_t)f2b(q.z) | ((uint_t)f2b(q.w) << 16);
    *(uint4*)(out + idx) = o;
}

// ---------------- pipelined bf16 NT GEMM, BM=128 BN=128 BK=32, 512 thr, 2 blk/CU ----------------
// out = A(Mx2048) * B(Nx2048)^T + bias; ocol<2048 -> fp32 out0, else bf16 out1 (both ld 2048).
// MERGED=1: flat<512 -> problem p0 (Q, 32x16 tiles); else KV (z in {0,1}, 8x32 tiles).
struct G8 {
    const ushort_t* A;
    const ushort_t* B;
    const float* bias0;
    const float* bias1;
    void* out0;
    void* out1;
};

template<int MERGED>
__global__ __launch_bounds__(512, 2) void k_gemm4(G8 p0, G8 p1, G8 p2) {
    // buffer d at d*16384: A[128][32] bf16 (8KB) then B[128][32] (8KB)
    __shared__ __align__(16) char sm[32768];
    int tid = threadIdx.x, lane = tid & 63, w = tid >> 6;
    int c = lane & 15, g = lane >> 4;
    int wr = w >> 2, wc = w & 3;

    int flat = blockIdx.x;
    G8 ar;
    int bm, bn;
    if (!MERGED || flat < 512) {
        int re = (flat & 7) * 64 + (flat >> 3);   // XCD-contiguous remap over 512
        bm = re & 31; bn = re >> 5;
        ar = p0;
    } else {
        int wl = flat - 512;
        int z = wl >> 8; wl &= 255;
        int re = (wl & 7) * 32 + (wl >> 3);       // remap over 256
        bm = re & 7; bn = re >> 3;
        ar = z ? p2 : p1;
    }

    // staging: thread covers row r=tid>>2, chunk pre-swizzled (rule 21: LDS dest linear)
    int chunk = ((tid & 3) ^ ((tid >> 3) & 3)) << 4;
    int r = tid >> 2;
    const char* gA = (const char*)ar.A + (size_t)(bm * 128 + r) * 4096 + chunk;
    const char* gB = (const char*)ar.B + (size_t)(bn * 128 + r) * 4096 + chunk;
    char* wA = sm + w * 1024;
    char* wB = sm + 8192 + w * 1024;

    f32x4 acc[4][2];
#pragma unroll
    for (int m = 0; m < 4; m++)
#pragma unroll
        for (int n = 0; n < 2; n++) acc[m][n] = (f32x4){0.f, 0.f, 0.f, 0.f};

    // prologue: stage tile 0 (buf0), tile 1 (buf1)
    gload_lds16(gA, wA);
    gload_lds16(gB, wB);
    gload_lds16(gA + 64, wA + 16384);
    gload_lds16(gB + 64, wB + 16384);
    asm volatile("s_waitcnt vmcnt(2)" ::: "memory");
    __builtin_amdgcn_s_barrier();

    int arow = wr * 64 + c;
    int aoff = arow * 64 + ((g ^ ((arow >> 1) & 3)) << 4);
    int brow = wc * 32 + c;
    int boff = 8192 + brow * 64 + ((g ^ ((brow >> 1) & 3)) << 4);

    for (int kt = 0; kt < 64; ++kt) {
        int dboff = (kt & 1) * 16384;
        bf16x8 aF[4], bF[2];
#pragma unroll
        for (int m = 0; m < 4; m++) aF[m] = *(const bf16x8*)(sm + dboff + aoff + m * 1024);
#pragma unroll
        for (int n = 0; n < 2; n++) bF[n] = *(const bf16x8*)(sm + dboff + boff + n * 1024);
        asm volatile("s_waitcnt lgkmcnt(0)" ::: "memory");
        __builtin_amdgcn_sched_barrier(0);
        __builtin_amdgcn_s_barrier();              // all waves done reading buf[cur]
        int nt = kt + 2; if (nt > 63) nt = 63;     // clamped tail restage (harmless)
        size_t koff = (size_t)nt * 64;
        __builtin_amdgcn_s_setprio(1);
#pragma unroll
        for (int m = 0; m < 4; m++)
            acc[m][0] = __builtin_amdgcn_mfma_f32_16x16x32_bf16(aF[m], bF[0], acc[m][0], 0, 0, 0);
        gload_lds16(gA + koff, wA + dboff);
#pragma unroll
        for (int m = 0; m < 4; m++)
            acc[m][1] = __builtin_amdgcn_mfma_f32_16x16x32_bf16(aF[m], bF[1], acc[m][1], 0, 0, 0);
        gload_lds16(gB + koff, wB + dboff);
        __builtin_amdgcn_s_setprio(0);
        asm volatile("s_waitcnt vmcnt(2)" ::: "memory");  // tile kt+1 resident; kt+2 in flight
        __builtin_amdgcn_s_barrier();
    }

    // epilogue: C[row][col], row = orow + m*16 + q, col = ocolb + n*16
    int orow = bm * 128 + wr * 64 + g * 4;
    int ocolb = bn * 128 + wc * 32 + c;
#pragma unroll
    for (int n = 0; n < 2; n++) {
        int ocol = ocolb + n * 16;
        if (!MERGED || ocol < 2048) {
            float* o0 = (float*)ar.out0;
            float bv = ar.bias0[ocol];
#pragma unroll
            for (int m = 0; m < 4; m++)
#pragma unroll
                for (int q = 0; q < 4; q++)
                    o0[(size_t)(orow + m * 16 + q) * 2048 + ocol] = acc[m][n][q] + bv;
        } else {
            ushort_t* o1 = (ushort_t*)ar.out1;
            int col2 = ocol - 2048;
            float bv = ar.bias1[col2];
#pragma unroll
            for (int m = 0; m < 4; m++)
#pragma unroll
                for (int q = 0; q < 4; q++)
                    o1[(size_t)(orow + m * 16 + q) * 2048 + col2] = f2b(acc[m][n][q] + bv);
        }
    }
}

// ---------------- fused RMSNorm + RoPE, fp32 in, bf16 out ----------------
__global__ __launch_bounds__(256) void k_rms_rope(const float* __restrict__ in,
                                                  const float* __restrict__ gain,
                                                  const float* __restrict__ freqs,
                                                  ushort_t* __restrict__ out,
                                                  int S, float oscale) {
    int row = blockIdx.x;
    int s = row % S;
    int tid = threadIdx.x;
    const float* p = in + (size_t)row * DIM + tid * 8;
    float4 a = *(const float4*)p;
    float4 b = *(const float4*)(p + 4);
    float y[8] = {a.x, a.y, a.z, a.w, b.x, b.y, b.z, b.w};
    float ss = 0.f;
#pragma unroll
    for (int j = 0; j < 8; j++) ss += y[j] * y[j];
#pragma unroll
    for (int off = 32; off > 0; off >>= 1) ss += __shfl_xor(ss, off, 64);
    __shared__ float red[4];
    int lane = tid & 63, wid = tid >> 6;
    if (lane == 0) red[wid] = ss;
    __syncthreads();
    float tot = red[0] + red[1] + red[2] + red[3];
    float inv = rsqrtf(tot * (1.0f / DIM) + 1e-6f);
    const float* g = gain + tid * 8;
    float4 g0 = *(const float4*)g;
    float4 g1 = *(const float4*)(g + 4);
    float gg[8] = {g0.x, g0.y, g0.z, g0.w, g1.x, g1.y, g1.z, g1.w};
    int p0 = (tid * 8 & 127) >> 1;
    const float* fq = freqs + ((size_t)s * 64 + p0) * 2;
    uint_t ow[4];
#pragma unroll
    for (int j = 0; j < 4; j++) {
        float fr = fq[j * 2 + 0], fi = fq[j * 2 + 1];
        float xr = y[2 * j] * inv * gg[2 * j];
        float xi = y[2 * j + 1] * inv * gg[2 * j + 1];
        float o0 = (xr * fr - xi * fi) * oscale;
        float o1 = (xr * fi + xi * fr) * oscale;
        ow[j] = (uint_t)f2b(o0) | ((uint_t)f2b(o1) << 16);
    }
    *(uint4*)(out + (size_t)row * DIM + tid * 8) = make_uint4(ow[0], ow[1], ow[2], ow[3]);
}

// ---------------- V transpose: vcam/vren (rows, DIM) -> vt[b,h,d=128,kv=1024] ----------------
__global__ __launch_bounds__(256) void k_vt(const ushort_t* __restrict__ vcam,
                                            const ushort_t* __restrict__ vren,
                                            ushort_t* __restrict__ vt) {
    __shared__ ushort_t t[64 * 136];
    int kt = blockIdx.x, h = blockIdx.y, b = blockIdx.z;
    int kv0 = kt * 64;
    const ushort_t* src = (kv0 < 512)
        ? vcam + ((size_t)(b * 512 + kv0)) * DIM + h * HD
        : vren + ((size_t)(b * 512 + kv0 - 512)) * DIM + h * HD;
    int tid = threadIdx.x;
#pragma unroll
    for (int i = 0; i < 4; i++) {
        int idx = i * 256 + tid;
        int kv = idx >> 4, c8 = idx & 15;
        uint4 v = *(const uint4*)(src + (size_t)kv * DIM + c8 * 8);
        *(uint4*)(t + kv * 136 + c8 * 8) = v;
    }
    __syncthreads();
    ushort_t* dst = vt + ((size_t)((b * NH + h) * HD)) * 1024 + kv0;
#pragma unroll
    for (int i = 0; i < 4; i++) {
        int idx = i * 256 + tid;
        int d = idx >> 3, c8 = idx & 7;
        ushort_t tmp[8];
#pragma unroll
        for (int j = 0; j < 8; j++) tmp[j] = t[(c8 * 8 + j) * 136 + d];
        uint4 o;
        o.x = (uint_t)tmp[0] | ((uint_t)tmp[1] << 16);
        o.y = (uint_t)tmp[2] | ((uint_t)tmp[3] << 16);
        o.z = (uint_t)tmp[4] | ((uint_t)tmp[5] << 16);
        o.w = (uint_t)tmp[6] | ((uint_t)tmp[7] << 16);
        *(uint4*)(dst + (size_t)d * 1024 + c8 * 8) = o;
    }
}

// ---------------- flash attention: 8 waves, 128 q-rows/block, double-buffered K/V ----------------
__global__ __launch_bounds__(512, 4) void k_attn(const ushort_t* __restrict__ Q,
                                                 const ushort_t* __restrict__ Kc,
                                                 const ushort_t* __restrict__ Kr,
                                                 const ushort_t* __restrict__ Vt,
                                                 ushort_t* __restrict__ O) {
    __shared__ __align__(16) char sm[65536];
    int tid = threadIdx.x, lane = tid & 63, w = tid >> 6;
    int c = lane & 15, g = lane >> 4;

    int bid = blockIdx.x;
    int xcd = bid & 7, idx = bid >> 3;
    int combo = idx & 3, qt = idx >> 2;
    int b = combo >> 1, h = xcd * 2 + (combo & 1);

    const ushort_t* qg = Q + ((size_t)(b * 2048 + qt * 128 + w * 16 + c)) * DIM + h * HD + g * 8;
    bf16x8 aQ[4];
#pragma unroll
    for (int ks = 0; ks < 4; ks++) aQ[ks] = *(const bf16x8*)(qg + ks * 32);

    int kbase[4], vbase[8];
#pragma unroll
    for (int n = 0; n < 4; n++) {
        int row = ((n >> 1) << 5) + ((c >> 2) << 3) + ((n & 1) << 2) + (c & 3);
        int sw = (row & 3) | (((row >> 3) & 3) << 2);
        kbase[n] = row * 256 + ((g ^ sw) << 4);
    }
#pragma unroll
    for (int dt = 0; dt < 8; dt++) {
        int vrow = dt * 16 + c;
        vbase[dt] = vrow * 128 + ((g ^ (vrow & 7)) << 4);
    }

    int swk = (lane >> 4) | ((w & 3) << 2);
    size_t klo = (size_t)(8 * w + (lane >> 4)) * 4096 + (size_t)(((lane & 15) ^ swk) << 4);
    size_t vlo = (size_t)(16 * w + (lane >> 3)) * 2048 + (size_t)(((lane & 7) ^ (lane >> 3)) << 4);
    int dst0 = w * 2048;

    const char* kc0 = (const char*)Kc + ((size_t)(b * 512) * DIM + h * HD) * 2;
    const char* kr0 = (const char*)Kr + ((size_t)(b * 512) * DIM + h * HD) * 2;
    const char* vtb = (const char*)Vt + ((size_t)((b * NH + h) * HD)) * 2048;

    float mr = -1e30f, lr = 0.f;
    f32x4 o[8];
#pragma unroll
    for (int d = 0; d < 8; d++) o[d] = (f32x4){0, 0, 0, 0};

    auto STAGE = [&](int DB, int t) {
        const char* kg = (t < 8) ? kc0 + (size_t)t * 262144 : kr0 + (size_t)(t - 8) * 262144;
        const char* vg = vtb + (size_t)t * 128;
        gload_lds16(kg + klo, sm + DB + dst0);
        gload_lds16(kg + klo + 16384, sm + DB + dst0 + 1024);
        gload_lds16(vg + vlo, sm + DB + 16384 + dst0);
        gload_lds16(vg + vlo + 16384, sm + DB + 16384 + dst0 + 1024);
    };

    auto TILE = [&](int DB) {
        f32x4 sT[4];
#pragma unroll
        for (int n = 0; n < 4; n++) sT[n] = (f32x4){0, 0, 0, 0};
#pragma unroll
        for (int n = 0; n < 4; n++)
#pragma unroll
            for (int ks = 0; ks < 4; ks++) {
                bf16x8 aK = *(const bf16x8*)(sm + DB + (kbase[n] ^ (ks << 6)));
                sT[n] = __builtin_amdgcn_mfma_f32_16x16x32_bf16(aK, aQ[ks], sT[n], 0, 0, 0);
            }
        float mloc = sT[0][0];
#pragma unroll
        for (int n = 0; n < 4; n++)
#pragma unroll
            for (int r = 0; r < 4; r++) mloc = fmaxf(mloc, sT[n][r]);
        mloc = fmaxf(mloc, __shfl_xor(mloc, 16, 64));
        mloc = fmaxf(mloc, __shfl_xor(mloc, 32, 64));
        if (!__all(mloc - mr <= 8.0f)) {
            float mn = fmaxf(mr, mloc);
            float al = exp2f(mr - mn);
            mr = mn;
            lr *= al;
#pragma unroll
            for (int d = 0; d < 8; d++) o[d] *= al;
        }
        float p[4][4];
        float ps = 0.f;
#pragma unroll
        for (int n = 0; n < 4; n++)
#pragma unroll
            for (int r = 0; r < 4; r++) {
                p[n][r] = exp2f(sT[n][r] - mr);
                ps += p[n][r];
            }
        ps += __shfl_xor(ps, 16, 64);
        ps += __shfl_xor(ps, 32, 64);
        lr += ps;
#pragma unroll
        for (int kk = 0; kk < 2; kk++) {
            union { uint_t u[4]; bf16x8 v; } bP;
            bP.u[0] = cvt_pk_bf16(p[2 * kk][0], p[2 * kk][1]);
            bP.u[1] = cvt_pk_bf16(p[2 * kk][2], p[2 * kk][3]);
            bP.u[2] = cvt_pk_bf16(p[2 * kk + 1][0], p[2 * kk + 1][1]);
            bP.u[3] = cvt_pk_bf16(p[2 * kk + 1][2], p[2 * kk + 1][3]);
#pragma unroll
            for (int dt = 0; dt < 8; dt++) {
                bf16x8 aV = *(const bf16x8*)(sm + DB + 16384 + (vbase[dt] ^ (kk << 6)));
                o[dt] = __builtin_amdgcn_mfma_f32_16x16x32_bf16(aV, bP.v, o[dt], 0, 0, 0);
            }
        }
    };

    STAGE(0, 0);
    __syncthreads();
#pragma unroll 1
    for (int t = 0; t < 16; t += 2) {
        STAGE(32768, t + 1);
        TILE(0);
        __syncthreads();
        if (t < 14) STAGE(0, t + 2);
        TILE(32768);
        __syncthreads();
    }

    float inv = 1.0f / lr;
    ushort_t* lO = (ushort_t*)sm;
#pragma unroll
    for (int dt = 0; dt < 8; dt++) {
        uint2 wv;
        wv.x = (uint_t)f2b(o[dt][0] * inv) | ((uint_t)f2b(o[dt][1] * inv) << 16);
        wv.y = (uint_t)f2b(o[dt][2] * inv) | ((uint_t)f2b(o[dt][3] * inv) << 16);
        *(uint2*)(lO + (w * 16 + c) * 136 + dt * 16 + g * 4) = wv;
    }
    __syncthreads();
    int row = tid >> 2, c8 = tid & 3;
    const ushort_t* src = lO + row * 136 + c8 * 32;
    ushort_t* dst = O + (size_t)(b * 2048 + qt * 128 + row) * DIM + h * HD + c8 * 32;
#pragma unroll
    for (int k = 0; k < 4; k++) *(uint4*)(dst + k * 8) = *(const uint4*)(src + k * 8);
}

extern "C" void kernel_launch(void* const* d_in, const int* in_sizes, int n_in,
                              void* d_out, int out_size, void* d_ws, size_t ws_size,
                              hipStream_t stream) {
    const float* x   = (const float*)d_in[0];
    const float* cam = (const float*)d_in[1];
    const float* ren = (const float*)d_in[2];
    const float* fx  = (const float*)d_in[3];
    const float* fc  = (const float*)d_in[4];
    const float* fr  = (const float*)d_in[5];
    const float* wq  = (const float*)d_in[6];
    const float* bq  = (const float*)d_in[7];
    const float* wk  = (const float*)d_in[8];
    const float* bk  = (const float*)d_in[9];
    const float* wv  = (const float*)d_in[10];
    const float* bv  = (const float*)d_in[11];
    const float* wkr = (const float*)d_in[12];
    const float* bkr = (const float*)d_in[13];
    const float* wvr = (const float*)d_in[14];
    const float* bvr = (const float*)d_in[15];
    const float* wo  = (const float*)d_in[16];
    const float* bo  = (const float*)d_in[17];
    const float* gq  = (const float*)d_in[18];
    const float* gk  = (const float*)d_in[19];

    char* ws = (char*)d_ws;
    ushort_t* wq_b     = (ushort_t*)(ws + 0);
    ushort_t* wk_b     = (ushort_t*)(ws + 8388608);   // wk||wv contiguous (N=4096)
    ushort_t* wkr_b    = (ushort_t*)(ws + 25165824);  // wkr||wvr contiguous (N=4096)
    ushort_t* wo_b     = (ushort_t*)(ws + 41943040);
    ushort_t* xb       = (ushort_t*)(ws + 50331648);  // 16.8MB; reused by attn_bf later
    ushort_t* camb     = (ushort_t*)(ws + 67108864);
    ushort_t* renb     = (ushort_t*)(ws + 71303168);
    float*    kcam_lin = (float*)(ws + 75497472);     // 8.4MB; region reused by vt later
    float*    kren_lin = (float*)(ws + 83886080);
    ushort_t* q_bf     = (ushort_t*)(ws + 92274688);
    ushort_t* kcam_bf  = (ushort_t*)(ws + 109051904);
    ushort_t* kren_bf  = (ushort_t*)(ws + 113246208);
    ushort_t* vcam_bf  = (ushort_t*)(ws + 117440512);
    ushort_t* vren_bf  = (ushort_t*)(ws + 121634816);
    ushort_t* vt       = (ushort_t*)(ws + 75497472);  // overlays dead kcam_lin/kren_lin
    ushort_t* attn_bf  = (ushort_t*)(ws + 50331648);  // overlays dead xb
    float*    q_lin    = (float*)d_out;               // d_out doubles as Q-proj scratch

    // fp32 -> bf16 converts
    CvtWArgs cw{{wq, wk, wv, wkr, wvr, wo}};
    k_cvtw<<<dim3(2048, 6), 256, 0, stream>>>(cw, wq_b);
    Cvt3Args c3{{x, cam, ren}, {xb, camb, renb}, {8388608, 2097152, 2097152}};
    k_cvt3<<<dim3(4096, 3), 256, 0, stream>>>(c3);

    // merged Q + K/V projections: 1024 blocks (2/CU x 2 passes)
    G8 qa{xb, wq_b, bq, nullptr, (void*)q_lin, nullptr};
    G8 kva0{camb, wk_b, bk, bv, (void*)kcam_lin, (void*)vcam_bf};
    G8 kva1{renb, wkr_b, bkr, bvr, (void*)kren_lin, (void*)vren_bf};
    k_gemm4<1><<<dim3(1024, 1, 1), 512, 0, stream>>>(qa, kva0, kva1);

    // RMSNorm+RoPE (Q folds (1/sqrt(HD))*log2(e) for exp2 softmax)
    k_rms_rope<<<4096, 256, 0, stream>>>(q_lin, gq, fx, q_bf, 2048,
                                         0.08838834764831845f * 1.4426950408889634f);
    k_rms_rope<<<1024, 256, 0, stream>>>(kcam_lin, gk, fc, kcam_bf, 512, 1.0f);
    k_rms_rope<<<1024, 256, 0, stream>>>(kren_lin, gk, fr, kren_bf, 512, 1.0f);
    k_vt<<<dim3(16, 16, 2), 256, 0, stream>>>(vcam_bf, vren_bf, vt);

    // flash attention (flat grid 512, XCD-pinned decode in-kernel, 128 q-rows/block)
    k_attn<<<dim3(512, 1, 1), 512, 0, stream>>>(q_bf, kcam_bf, kren_bf, vt, attn_bf);

    // output projection -> d_out (fp32), 512 blocks (2/CU, one pass)
    G8 oa{attn_bf, wo_b, bo, nullptr, d_out, nullptr};
    k_gemm4<0><<<dim3(512, 1, 1), 512, 0, stream>>>(oa, oa, oa);
}

// Round 7
// 229.465 us; speedup vs baseline: 1.7571x; 1.1042x over previous
//
#include <hip/hip_runtime.h>

typedef short bf16x8 __attribute__((ext_vector_type(8)));
typedef float f32x4 __attribute__((ext_vector_type(4)));
typedef unsigned short ushort_t;
typedef unsigned int uint_t;

#define DIM 2048
#define NH 16
#define HD 128

__device__ __forceinline__ ushort_t f2b(float f) {
    union { float f; uint_t u; } a; a.f = f;
    uint_t u = a.u;
    return (ushort_t)((u + 0x7fffu + ((u >> 16) & 1u)) >> 16);
}

__device__ __forceinline__ uint_t cvt_pk_bf16(float lo, float hi) {
    uint_t r;
    asm("v_cvt_pk_bf16_f32 %0, %1, %2" : "=v"(r) : "v"(lo), "v"(hi));
    return r;
}

__device__ __forceinline__ void gload_lds16(const void* g, void* l) {
    void* gg = const_cast<void*>(g);
    __builtin_amdgcn_global_load_lds(
        (__attribute__((address_space(1))) uint_t*)gg,
        (__attribute__((address_space(3))) uint_t*)l, 16, 0, 0);
}

// ---------------- batched weight convert: 6 x (2048*2048) into contiguous dst ----------------
struct CvtWArgs { const float* s[6]; };
__global__ __launch_bounds__(256) void k_cvtw(CvtWArgs a, ushort_t* __restrict__ dst) {
    int y = blockIdx.y;
    const float* in = a.s[y];
    ushort_t* out = dst + (size_t)y * 4194304;
    int idx = (blockIdx.x * 256 + threadIdx.x) * 8;
    float4 p = *(const float4*)(in + idx);
    float4 q = *(const float4*)(in + idx + 4);
    uint4 o;
    o.x = (uint_t)f2b(p.x) | ((uint_t)f2b(p.y) << 16);
    o.y = (uint_t)f2b(p.z) | ((uint_t)f2b(p.w) << 16);
    o.z = (uint_t)f2b(q.x) | ((uint_t)f2b(q.y) << 16);
    o.w = (uint_t)f2b(q.z) | ((uint_t)f2b(q.w) << 16);
    *(uint4*)(out + idx) = o;
}

// ---------------- activation converts: x / cam / ren in one dispatch ----------------
struct Cvt3Args { const float* s[3]; ushort_t* d[3]; int n[3]; };
__global__ __launch_bounds__(256) void k_cvt3(Cvt3Args a) {
    int y = blockIdx.y;
    int idx = (blockIdx.x * 256 + threadIdx.x) * 8;
    if (idx >= a.n[y]) return;
    const float* in = a.s[y];
    ushort_t* out = a.d[y];
    float4 p = *(const float4*)(in + idx);
    float4 q = *(const float4*)(in + idx + 4);
    uint4 o;
    o.x = (uint_t)f2b(p.x) | ((uint_t)f2b(p.y) << 16);
    o.y = (uint_t)f2b(p.z) | ((uint_t)f2b(p.w) << 16);
    o.z = (uint_t)f2b(q.x) | ((uint_t)f2b(q.y) << 16);
    o.w = (uint_t)f2b(q.z) | ((uint_t)f2b(q.w) << 16);
    *(uint4*)(out + idx) = o;
}

struct G8 {
    const ushort_t* A;
    const ushort_t* B;
    const float* bias0;
    const float* bias1;
    void* out0;
    void* out1;
};

// ======== 8-phase 256x256x(BK=64) bf16 NT GEMM, 512 thr, 128KB dynamic LDS ========
// MODE 1: merged QKV (256 blocks): re<128 -> Q (16x8, fp32 out0); else cam/ren KV
//         (4x16 each): bn<8 -> fp32 out0 (K), bn>=8 -> bf16 out1 (V, col-2048).
// LDS per dbuf (65536): A quadrant-subs [s4:2][64 rows][128B] per half (2 halves,
// 16KB each) at 0; B at 32768, halves by nh: [sub:4][32 rows][128B].
template<int MODE>
__global__ __launch_bounds__(512, 2) void k_g256(G8 p0, G8 p1, G8 p2) {
    extern __shared__ __align__(16) char sm[];
    int tid = threadIdx.x, lane = tid & 63, w = tid >> 6;
    int c = lane & 15, g = lane >> 4;
    int wr = w >> 2, wc = w & 3;

    int flat = blockIdx.x;
    G8 ar;
    int bm, bn, vOut = 0;
    if (MODE == 1) {
        int re = (flat & 7) * 32 + (flat >> 3);
        if (re < 128) { ar = p0; bm = re & 15; bn = re >> 4; }
        else {
            int r2 = re - 128;
            int z = r2 >> 6; r2 &= 63;
            ar = z ? p2 : p1;
            bm = r2 & 3; bn = r2 >> 2;
            vOut = (bn >= 8);
        }
    } else {
        int re = (flat & 7) * 16 + (flat >> 3);
        ar = p0; bm = re >> 3; bn = re & 7;
    }

    // ---- staging source/dest (pre-swizzled global source; linear LDS dest) ----
    int wj0 = 2 * w, wj1 = 2 * w + 1;
    int l3 = lane >> 3;
    int swz = ((lane & 7) ^ l3) << 4;
    int RA0 = (wj0 >> 3) * 128 + (wj0 & 7) * 8 + l3;
    int RA1 = (wj1 >> 3) * 128 + (wj1 & 7) * 8 + l3;
    int RB0 = (wj0 >> 2) * 64 + (wj0 & 3) * 8 + l3;
    int RB1 = (wj1 >> 2) * 64 + (wj1 & 3) * 8 + l3;
    const char* sA0 = (const char*)ar.A + (size_t)(bm * 256 + RA0) * 4096 + swz;
    const char* sA1 = (const char*)ar.A + (size_t)(bm * 256 + RA1) * 4096 + swz;
    const char* sB0 = (const char*)ar.B + (size_t)(bn * 256 + RB0) * 4096 + swz;
    const char* sB1 = (const char*)ar.B + (size_t)(bn * 256 + RB1) * 4096 + swz;
    char* dA0 = sm + wj0 * 1024;
    char* dA1 = sm + wj1 * 1024;
    char* dB0 = sm + 32768 + wj0 * 1024;
    char* dB1 = sm + 32768 + wj1 * 1024;

    auto SA = [&](int buf, int half, int t) {
        gload_lds16(sA0 + (size_t)half * 262144 + t * 128, dA0 + buf + half * 16384);
        gload_lds16(sA1 + (size_t)half * 262144 + t * 128, dA1 + buf + half * 16384);
    };
    auto SB = [&](int buf, int half, int t) {
        gload_lds16(sB0 + (size_t)half * 131072 + t * 128, dB0 + buf + half * 16384);
        gload_lds16(sB1 + (size_t)half * 131072 + t * 128, dB1 + buf + half * 16384);
    };

    // ---- read offsets (swizzled) ----
    int bKS0 = (g << 4) ^ ((c & 7) << 4);
    int bKS1 = (64 | (g << 4)) ^ ((c & 7) << 4);
    int aoffL = wr * 8192 + c * 128;           // + mh*16384 + m'*2048 + bKS
    int boffL = 32768 + wc * 4096 + c * 128;   // + nh*16384 + n'*2048 + bKS

    f32x4 acc[8][4];
#pragma unroll
    for (int m = 0; m < 8; m++)
#pragma unroll
        for (int n = 0; n < 4; n++) acc[m][n] = (f32x4){0.f, 0.f, 0.f, 0.f};

    bf16x8 aF[4][2], bF0[2][2], bF1[2][2];

    auto RA = [&](int buf, int mh) {
#pragma unroll
        for (int m = 0; m < 4; m++) {
            aF[m][0] = *(const bf16x8*)(sm + buf + mh * 16384 + aoffL + m * 2048 + bKS0);
            aF[m][1] = *(const bf16x8*)(sm + buf + mh * 16384 + aoffL + m * 2048 + bKS1);
        }
    };
    auto RB = [&](int buf, int nh, bf16x8 (&bF)[2][2]) {
#pragma unroll
        for (int n = 0; n < 2; n++) {
            bF[n][0] = *(const bf16x8*)(sm + buf + boffL + nh * 16384 + n * 2048 + bKS0);
            bF[n][1] = *(const bf16x8*)(sm + buf + boffL + nh * 16384 + n * 2048 + bKS1);
        }
    };
    auto MF = [&](int mh, int nh, bf16x8 (&bF)[2][2]) {
        __builtin_amdgcn_s_setprio(1);
#pragma unroll
        for (int m = 0; m < 4; m++)
#pragma unroll
            for (int n = 0; n < 2; n++)
#pragma unroll
                for (int ks = 0; ks < 2; ks++)
                    acc[mh * 4 + m][nh * 2 + n] = __builtin_amdgcn_mfma_f32_16x16x32_bf16(
                        aF[m][ks], bF[n][ks], acc[mh * 4 + m][nh * 2 + n], 0, 0, 0);
        __builtin_amdgcn_s_setprio(0);
    };

    // ---- prologue: T0 all 4 halves, T1 Ah0+Bh0 (12 loads) ----
    SA(0, 0, 0); SB(0, 0, 0); SA(0, 1, 0); SB(0, 1, 0);
    SA(65536, 0, 1); SB(65536, 0, 1);
    asm volatile("s_waitcnt vmcnt(8)" ::: "memory");
    __builtin_amdgcn_s_barrier();

#pragma unroll 1
    for (int i = 0; i < 16; ++i) {
        int Tb  = 2 * i + 1;
        int Ta2 = (2 * i + 2 > 31) ? 31 : 2 * i + 2;
        int Tb2 = (2 * i + 3 > 31) ? 31 : 2 * i + 3;
        // p1
        RA(0, 0); RB(0, 0, bF0);
        SA(65536, 1, Tb);
        __builtin_amdgcn_s_barrier();
        MF(0, 0, bF0);
        asm volatile("s_waitcnt vmcnt(6)" ::: "memory");
        __builtin_amdgcn_s_barrier();
        // p2
        RB(0, 1, bF1);
        SB(65536, 1, Tb);
        __builtin_amdgcn_s_barrier();
        MF(0, 1, bF1);
        __builtin_amdgcn_s_barrier();
        // p3
        RA(0, 1);
        SA(0, 0, Ta2);
        __builtin_amdgcn_s_barrier();
        MF(1, 0, bF0);
        __builtin_amdgcn_s_barrier();
        // p4
        SB(0, 0, Ta2);
        __builtin_amdgcn_s_barrier();
        MF(1, 1, bF1);
        asm volatile("s_waitcnt vmcnt(8)" ::: "memory");
        __builtin_amdgcn_s_barrier();
        // p5
        RA(65536, 0); RB(65536, 0, bF0);
        SA(0, 1, Ta2);
        __builtin_amdgcn_s_barrier();
        MF(0, 0, bF0);
        asm volatile("s_waitcnt vmcnt(6)" ::: "memory");
        __builtin_amdgcn_s_barrier();
        // p6
        RB(65536, 1, bF1);
        SB(0, 1, Ta2);
        __builtin_amdgcn_s_barrier();
        MF(0, 1, bF1);
        __builtin_amdgcn_s_barrier();
        // p7
        RA(65536, 1);
        SA(65536, 0, Tb2);
        __builtin_amdgcn_s_barrier();
        MF(1, 0, bF0);
        __builtin_amdgcn_s_barrier();
        // p8
        SB(65536, 0, Tb2);
        __builtin_amdgcn_s_barrier();
        MF(1, 1, bF1);
        asm volatile("s_waitcnt vmcnt(8)" ::: "memory");
        __builtin_amdgcn_s_barrier();
    }

    // ---- epilogue ----
    int orow0 = bm * 256 + wr * 128 + g * 4;
    int ocol0 = bn * 256 + wc * 64 + c;
    if (MODE == 0 || !vOut) {
        float* o0 = (float*)ar.out0;
#pragma unroll
        for (int n = 0; n < 4; n++) {
            int col = ocol0 + n * 16;
            float bv = ar.bias0[col];
#pragma unroll
            for (int m = 0; m < 8; m++)
#pragma unroll
                for (int q = 0; q < 4; q++)
                    o0[(size_t)(orow0 + m * 16 + q) * 2048 + col] = acc[m][n][q] + bv;
        }
    } else {
        ushort_t* o1 = (ushort_t*)ar.out1;
#pragma unroll
        for (int n = 0; n < 4; n++) {
            int col = ocol0 + n * 16 - 2048;
            float bv = ar.bias1[col];
#pragma unroll
            for (int m = 0; m < 8; m++)
#pragma unroll
                for (int q = 0; q < 4; q++)
                    o1[(size_t)(orow0 + m * 16 + q) * 2048 + col] = f2b(acc[m][n][q] + bv);
        }
    }
}

// ---------------- 2-phase 128x128 GEMM (kept for out-proj: 512 blocks, 2/CU) ----------------
template<int MERGED>
__global__ __launch_bounds__(512, 2) void k_gemm4(G8 p0, G8 p1, G8 p2) {
    __shared__ __align__(16) char sm[32768];
    int tid = threadIdx.x, lane = tid & 63, w = tid >> 6;
    int c = lane & 15, g = lane >> 4;
    int wr = w >> 2, wc = w & 3;

    int flat = blockIdx.x;
    G8 ar;
    int bm, bn;
    {
        int re = (flat & 7) * 64 + (flat >> 3);
        bm = re & 31; bn = re >> 5;
        ar = p0;
    }

    int chunk = ((tid & 3) ^ ((tid >> 3) & 3)) << 4;
    int r = tid >> 2;
    const char* gA = (const char*)ar.A + (size_t)(bm * 128 + r) * 4096 + chunk;
    const char* gB = (const char*)ar.B + (size_t)(bn * 128 + r) * 4096 + chunk;
    char* wA = sm + w * 1024;
    char* wB = sm + 8192 + w * 1024;

    f32x4 acc[4][2];
#pragma unroll
    for (int m = 0; m < 4; m++)
#pragma unroll
        for (int n = 0; n < 2; n++) acc[m][n] = (f32x4){0.f, 0.f, 0.f, 0.f};

    gload_lds16(gA, wA);
    gload_lds16(gB, wB);
    gload_lds16(gA + 64, wA + 16384);
    gload_lds16(gB + 64, wB + 16384);
    asm volatile("s_waitcnt vmcnt(2)" ::: "memory");
    __builtin_amdgcn_s_barrier();

    int arow = wr * 64 + c;
    int aoff = arow * 64 + ((g ^ ((arow >> 1) & 3)) << 4);
    int brow = wc * 32 + c;
    int boff = 8192 + brow * 64 + ((g ^ ((brow >> 1) & 3)) << 4);

    for (int kt = 0; kt < 64; ++kt) {
        int dboff = (kt & 1) * 16384;
        bf16x8 aF[4], bF[2];
#pragma unroll
        for (int m = 0; m < 4; m++) aF[m] = *(const bf16x8*)(sm + dboff + aoff + m * 1024);
#pragma unroll
        for (int n = 0; n < 2; n++) bF[n] = *(const bf16x8*)(sm + dboff + boff + n * 1024);
        asm volatile("s_waitcnt lgkmcnt(0)" ::: "memory");
        __builtin_amdgcn_sched_barrier(0);
        __builtin_amdgcn_s_barrier();
        int nt = kt + 2; if (nt > 63) nt = 63;
        size_t koff = (size_t)nt * 64;
        __builtin_amdgcn_s_setprio(1);
#pragma unroll
        for (int m = 0; m < 4; m++)
            acc[m][0] = __builtin_amdgcn_mfma_f32_16x16x32_bf16(aF[m], bF[0], acc[m][0], 0, 0, 0);
        gload_lds16(gA + koff, wA + dboff);
#pragma unroll
        for (int m = 0; m < 4; m++)
            acc[m][1] = __builtin_amdgcn_mfma_f32_16x16x32_bf16(aF[m], bF[1], acc[m][1], 0, 0, 0);
        gload_lds16(gB + koff, wB + dboff);
        __builtin_amdgcn_s_setprio(0);
        asm volatile("s_waitcnt vmcnt(2)" ::: "memory");
        __builtin_amdgcn_s_barrier();
    }

    int orow = bm * 128 + wr * 64 + g * 4;
    int ocolb = bn * 128 + wc * 32 + c;
    float* o0 = (float*)ar.out0;
#pragma unroll
    for (int n = 0; n < 2; n++) {
        int ocol = ocolb + n * 16;
        float bv = ar.bias0[ocol];
#pragma unroll
        for (int m = 0; m < 4; m++)
#pragma unroll
            for (int q = 0; q < 4; q++)
                o0[(size_t)(orow + m * 16 + q) * 2048 + ocol] = acc[m][n][q] + bv;
    }
}

// ---------------- fused RMSNorm + RoPE, fp32 in, bf16 out ----------------
__global__ __launch_bounds__(256) void k_rms_rope(const float* __restrict__ in,
                                                  const float* __restrict__ gain,
                                                  const float* __restrict__ freqs,
                                                  ushort_t* __restrict__ out,
                                                  int S, float oscale) {
    int row = blockIdx.x;
    int s = row % S;
    int tid = threadIdx.x;
    const float* p = in + (size_t)row * DIM + tid * 8;
    float4 a = *(const float4*)p;
    float4 b = *(const float4*)(p + 4);
    float y[8] = {a.x, a.y, a.z, a.w, b.x, b.y, b.z, b.w};
    float ss = 0.f;
#pragma unroll
    for (int j = 0; j < 8; j++) ss += y[j] * y[j];
#pragma unroll
    for (int off = 32; off > 0; off >>= 1) ss += __shfl_xor(ss, off, 64);
    __shared__ float red[4];
    int lane = tid & 63, wid = tid >> 6;
    if (lane == 0) red[wid] = ss;
    __syncthreads();
    float tot = red[0] + red[1] + red[2] + red[3];
    float inv = rsqrtf(tot * (1.0f / DIM) + 1e-6f);
    const float* g = gain + tid * 8;
    float4 g0 = *(const float4*)g;
    float4 g1 = *(const float4*)(g + 4);
    float gg[8] = {g0.x, g0.y, g0.z, g0.w, g1.x, g1.y, g1.z, g1.w};
    int p0 = (tid * 8 & 127) >> 1;
    const float* fq = freqs + ((size_t)s * 64 + p0) * 2;
    uint_t ow[4];
#pragma unroll
    for (int j = 0; j < 4; j++) {
        float fr = fq[j * 2 + 0], fi = fq[j * 2 + 1];
        float xr = y[2 * j] * inv * gg[2 * j];
        float xi = y[2 * j + 1] * inv * gg[2 * j + 1];
        float o0 = (xr * fr - xi * fi) * oscale;
        float o1 = (xr * fi + xi * fr) * oscale;
        ow[j] = (uint_t)f2b(o0) | ((uint_t)f2b(o1) << 16);
    }
    *(uint4*)(out + (size_t)row * DIM + tid * 8) = make_uint4(ow[0], ow[1], ow[2], ow[3]);
}

// ---------------- V transpose: vcam/vren (rows, DIM) -> vt[b,h,d=128,kv=1024] ----------------
__global__ __launch_bounds__(256) void k_vt(const ushort_t* __restrict__ vcam,
                                            const ushort_t* __restrict__ vren,
                                            ushort_t* __restrict__ vt) {
    __shared__ ushort_t t[64 * 136];
    int kt = blockIdx.x, h = blockIdx.y, b = blockIdx.z;
    int kv0 = kt * 64;
    const ushort_t* src = (kv0 < 512)
        ? vcam + ((size_t)(b * 512 + kv0)) * DIM + h * HD
        : vren + ((size_t)(b * 512 + kv0 - 512)) * DIM + h * HD;
    int tid = threadIdx.x;
#pragma unroll
    for (int i = 0; i < 4; i++) {
        int idx = i * 256 + tid;
        int kv = idx >> 4, c8 = idx & 15;
        uint4 v = *(const uint4*)(src + (size_t)kv * DIM + c8 * 8);
        *(uint4*)(t + kv * 136 + c8 * 8) = v;
    }
    __syncthreads();
    ushort_t* dst = vt + ((size_t)((b * NH + h) * HD)) * 1024 + kv0;
#pragma unroll
    for (int i = 0; i < 4; i++) {
        int idx = i * 256 + tid;
        int d = idx >> 3, c8 = idx & 7;
        ushort_t tmp[8];
#pragma unroll
        for (int j = 0; j < 8; j++) tmp[j] = t[(c8 * 8 + j) * 136 + d];
        uint4 o;
        o.x = (uint_t)tmp[0] | ((uint_t)tmp[1] << 16);
        o.y = (uint_t)tmp[2] | ((uint_t)tmp[3] << 16);
        o.z = (uint_t)tmp[4] | ((uint_t)tmp[5] << 16);
        o.w = (uint_t)tmp[6] | ((uint_t)tmp[7] << 16);
        *(uint4*)(dst + (size_t)d * 1024 + c8 * 8) = o;
    }
}

// ---------------- flash attention: 8 waves, 128 q-rows/block, double-buffered K/V ----------------
__global__ __launch_bounds__(512, 4) void k_attn(const ushort_t* __restrict__ Q,
                                                 const ushort_t* __restrict__ Kc,
                                                 const ushort_t* __restrict__ Kr,
                                                 const ushort_t* __restrict__ Vt,
                                                 ushort_t* __restrict__ O) {
    __shared__ __align__(16) char sm[65536];
    int tid = threadIdx.x, lane = tid & 63, w = tid >> 6;
    int c = lane & 15, g = lane >> 4;

    int bid = blockIdx.x;
    int xcd = bid & 7, idx = bid >> 3;
    int combo = idx & 3, qt = idx >> 2;
    int b = combo >> 1, h = xcd * 2 + (combo & 1);

    const ushort_t* qg = Q + ((size_t)(b * 2048 + qt * 128 + w * 16 + c)) * DIM + h * HD + g * 8;
    bf16x8 aQ[4];
#pragma unroll
    for (int ks = 0; ks < 4; ks++) aQ[ks] = *(const bf16x8*)(qg + ks * 32);

    int kbase[4], vbase[8];
#pragma unroll
    for (int n = 0; n < 4; n++) {
        int row = ((n >> 1) << 5) + ((c >> 2) << 3) + ((n & 1) << 2) + (c & 3);
        int sw = (row & 3) | (((row >> 3) & 3) << 2);
        kbase[n] = row * 256 + ((g ^ sw) << 4);
    }
#pragma unroll
    for (int dt = 0; dt < 8; dt++) {
        int vrow = dt * 16 + c;
        vbase[dt] = vrow * 128 + ((g ^ (vrow & 7)) << 4);
    }

    int swk = (lane >> 4) | ((w & 3) << 2);
    size_t klo = (size_t)(8 * w + (lane >> 4)) * 4096 + (size_t)(((lane & 15) ^ swk) << 4);
    size_t vlo = (size_t)(16 * w + (lane >> 3)) * 2048 + (size_t)(((lane & 7) ^ (lane >> 3)) << 4);
    int dst0 = w * 2048;

    const char* kc0 = (const char*)Kc + ((size_t)(b * 512) * DIM + h * HD) * 2;
    const char* kr0 = (const char*)Kr + ((size_t)(b * 512) * DIM + h * HD) * 2;
    const char* vtb = (const char*)Vt + ((size_t)((b * NH + h) * HD)) * 2048;

    float mr = -1e30f, lr = 0.f;
    f32x4 o[8];
#pragma unroll
    for (int d = 0; d < 8; d++) o[d] = (f32x4){0, 0, 0, 0};

    auto STAGE = [&](int DB, int t) {
        const char* kg = (t < 8) ? kc0 + (size_t)t * 262144 : kr0 + (size_t)(t - 8) * 262144;
        const char* vg = vtb + (size_t)t * 128;
        gload_lds16(kg + klo, sm + DB + dst0);
        gload_lds16(kg + klo + 16384, sm + DB + dst0 + 1024);
        gload_lds16(vg + vlo, sm + DB + 16384 + dst0);
        gload_lds16(vg + vlo + 16384, sm + DB + 16384 + dst0 + 1024);
    };

    auto TILE = [&](int DB) {
        f32x4 sT[4];
#pragma unroll
        for (int n = 0; n < 4; n++) sT[n] = (f32x4){0, 0, 0, 0};
#pragma unroll
        for (int n = 0; n < 4; n++)
#pragma unroll
            for (int ks = 0; ks < 4; ks++) {
                bf16x8 aK = *(const bf16x8*)(sm + DB + (kbase[n] ^ (ks << 6)));
                sT[n] = __builtin_amdgcn_mfma_f32_16x16x32_bf16(aK, aQ[ks], sT[n], 0, 0, 0);
            }
        float mloc = sT[0][0];
#pragma unroll
        for (int n = 0; n < 4; n++)
#pragma unroll
            for (int r = 0; r < 4; r++) mloc = fmaxf(mloc, sT[n][r]);
        mloc = fmaxf(mloc, __shfl_xor(mloc, 16, 64));
        mloc = fmaxf(mloc, __shfl_xor(mloc, 32, 64));
        if (!__all(mloc - mr <= 8.0f)) {
            float mn = fmaxf(mr, mloc);
            float al = exp2f(mr - mn);
            mr = mn;
            lr *= al;
#pragma unroll
            for (int d = 0; d < 8; d++) o[d] *= al;
        }
        float p[4][4];
        float ps = 0.f;
#pragma unroll
        for (int n = 0; n < 4; n++)
#pragma unroll
            for (int r = 0; r < 4; r++) {
                p[n][r] = exp2f(sT[n][r] - mr);
                ps += p[n][r];
            }
        ps += __shfl_xor(ps, 16, 64);
        ps += __shfl_xor(ps, 32, 64);
        lr += ps;
#pragma unroll
        for (int kk = 0; kk < 2; kk++) {
            union { uint_t u[4]; bf16x8 v; } bP;
            bP.u[0] = cvt_pk_bf16(p[2 * kk][0], p[2 * kk][1]);
            bP.u[1] = cvt_pk_bf16(p[2 * kk][2], p[2 * kk][3]);
            bP.u[2] = cvt_pk_bf16(p[2 * kk + 1][0], p[2 * kk + 1][1]);
            bP.u[3] = cvt_pk_bf16(p[2 * kk + 1][2], p[2 * kk + 1][3]);
#pragma unroll
            for (int dt = 0; dt < 8; dt++) {
                bf16x8 aV = *(const bf16x8*)(sm + DB + 16384 + (vbase[dt] ^ (kk << 6)));
                o[dt] = __builtin_amdgcn_mfma_f32_16x16x32_bf16(aV, bP.v, o[dt], 0, 0, 0);
            }
        }
    };

    STAGE(0, 0);
    __syncthreads();
#pragma unroll 1
    for (int t = 0; t < 16; t += 2) {
        STAGE(32768, t + 1);
        TILE(0);
        __syncthreads();
        if (t < 14) STAGE(0, t + 2);
        TILE(32768);
        __syncthreads();
    }

    float inv = 1.0f / lr;
    ushort_t* lO = (ushort_t*)sm;
#pragma unroll
    for (int dt = 0; dt < 8; dt++) {
        uint2 wv;
        wv.x = (uint_t)f2b(o[dt][0] * inv) | ((uint_t)f2b(o[dt][1] * inv) << 16);
        wv.y = (uint_t)f2b(o[dt][2] * inv) | ((uint_t)f2b(o[dt][3] * inv) << 16);
        *(uint2*)(lO + (w * 16 + c) * 136 + dt * 16 + g * 4) = wv;
    }
    __syncthreads();
    int row = tid >> 2, c8 = tid & 3;
    const ushort_t* src = lO + row * 136 + c8 * 32;
    ushort_t* dst = O + (size_t)(b * 2048 + qt * 128 + row) * DIM + h * HD + c8 * 32;
#pragma unroll
    for (int k = 0; k < 4; k++) *(uint4*)(dst + k * 8) = *(const uint4*)(src + k * 8);
}

extern "C" void kernel_launch(void* const* d_in, const int* in_sizes, int n_in,
                              void* d_out, int out_size, void* d_ws, size_t ws_size,
                              hipStream_t stream) {
    const float* x   = (const float*)d_in[0];
    const float* cam = (const float*)d_in[1];
    const float* ren = (const float*)d_in[2];
    const float* fx  = (const float*)d_in[3];
    const float* fc  = (const float*)d_in[4];
    const float* fr  = (const float*)d_in[5];
    const float* wq  = (const float*)d_in[6];
    const float* bq  = (const float*)d_in[7];
    const float* wk  = (const float*)d_in[8];
    const float* bk  = (const float*)d_in[9];
    const float* wv  = (const float*)d_in[10];
    const float* bv  = (const float*)d_in[11];
    const float* wkr = (const float*)d_in[12];
    const float* bkr = (const float*)d_in[13];
    const float* wvr = (const float*)d_in[14];
    const float* bvr = (const float*)d_in[15];
    const float* wo  = (const float*)d_in[16];
    const float* bo  = (const float*)d_in[17];
    const float* gq  = (const float*)d_in[18];
    const float* gk  = (const float*)d_in[19];

    char* ws = (char*)d_ws;
    ushort_t* wq_b     = (ushort_t*)(ws + 0);
    ushort_t* wk_b     = (ushort_t*)(ws + 8388608);   // wk||wv contiguous (N=4096)
    ushort_t* wkr_b    = (ushort_t*)(ws + 25165824);  // wkr||wvr contiguous (N=4096)
    ushort_t* wo_b     = (ushort_t*)(ws + 41943040);
    ushort_t* xb       = (ushort_t*)(ws + 50331648);  // 16.8MB; reused by attn_bf later
    ushort_t* camb     = (ushort_t*)(ws + 67108864);
    ushort_t* renb     = (ushort_t*)(ws + 71303168);
    float*    kcam_lin = (float*)(ws + 75497472);     // 8.4MB; region reused by vt later
    float*    kren_lin = (float*)(ws + 83886080);
    ushort_t* q_bf     = (ushort_t*)(ws + 92274688);
    ushort_t* kcam_bf  = (ushort_t*)(ws + 109051904);
    ushort_t* kren_bf  = (ushort_t*)(ws + 113246208);
    ushort_t* vcam_bf  = (ushort_t*)(ws + 117440512);
    ushort_t* vren_bf  = (ushort_t*)(ws + 121634816);
    ushort_t* vt       = (ushort_t*)(ws + 75497472);  // overlays dead kcam_lin/kren_lin
    ushort_t* attn_bf  = (ushort_t*)(ws + 50331648);  // overlays dead xb
    float*    q_lin    = (float*)d_out;               // d_out doubles as Q-proj scratch

    // allow 128KB dynamic LDS for the 8-phase GEMM (host-side attr, not captured)
    hipFuncSetAttribute(reinterpret_cast<const void*>(&k_g256<1>),
                        hipFuncAttributeMaxDynamicSharedMemorySize, 131072);

    // fp32 -> bf16 converts
    CvtWArgs cw{{wq, wk, wv, wkr, wvr, wo}};
    k_cvtw<<<dim3(2048, 6), 256, 0, stream>>>(cw, wq_b);
    Cvt3Args c3{{x, cam, ren}, {xb, camb, renb}, {8388608, 2097152, 2097152}};
    k_cvt3<<<dim3(4096, 3), 256, 0, stream>>>(c3);

    // merged Q + K/V projections: 8-phase 256^2 kernel, 256 blocks (1/CU exact)
    G8 qa{xb, wq_b, bq, nullptr, (void*)q_lin, nullptr};
    G8 kva0{camb, wk_b, bk, bv, (void*)kcam_lin, (void*)vcam_bf};
    G8 kva1{renb, wkr_b, bkr, bvr, (void*)kren_lin, (void*)vren_bf};
    k_g256<1><<<dim3(256, 1, 1), 512, 131072, stream>>>(qa, kva0, kva1);

    // RMSNorm+RoPE (Q folds (1/sqrt(HD))*log2(e) for exp2 softmax)
    k_rms_rope<<<4096, 256, 0, stream>>>(q_lin, gq, fx, q_bf, 2048,
                                         0.08838834764831845f * 1.4426950408889634f);
    k_rms_rope<<<1024, 256, 0, stream>>>(kcam_lin, gk, fc, kcam_bf, 512, 1.0f);
    k_rms_rope<<<1024, 256, 0, stream>>>(kren_lin, gk, fr, kren_bf, 512, 1.0f);
    k_vt<<<dim3(16, 16, 2), 256, 0, stream>>>(vcam_bf, vren_bf, vt);

    // flash attention (flat grid 512, XCD-pinned decode in-kernel, 128 q-rows/block)
    k_attn<<<dim3(512, 1, 1), 512, 0, stream>>>(q_bf, kcam_bf, kren_bf, vt, attn_bf);

    // output projection -> d_out (fp32), 2-phase kernel, 512 blocks (2/CU)
    G8 oa{attn_bf, wo_b, bo, nullptr, d_out, nullptr};
    k_gemm4<0><<<dim3(512, 1, 1), 512, 0, stream>>>(oa, oa, oa);
}

// Round 9
// 212.377 us; speedup vs baseline: 1.8985x; 1.0805x over previous
//
#include <hip/hip_runtime.h>

typedef short bf16x8 __attribute__((ext_vector_type(8)));
typedef float f32x4 __attribute__((ext_vector_type(4)));
typedef unsigned short ushort_t;
typedef unsigned int uint_t;

#define DIM 2048
#define NH 16
#define HD 128

__device__ __forceinline__ ushort_t f2b(float f) {
    union { float f; uint_t u; } a; a.f = f;
    uint_t u = a.u;
    return (ushort_t)((u + 0x7fffu + ((u >> 16) & 1u)) >> 16);
}

__device__ __forceinline__ float b2f(ushort_t s) {
    union { uint_t u; float f; } a; a.u = ((uint_t)s) << 16;
    return a.f;
}

__device__ __forceinline__ uint_t cvt_pk_bf16(float lo, float hi) {
    uint_t r;
    asm("v_cvt_pk_bf16_f32 %0, %1, %2" : "=v"(r) : "v"(lo), "v"(hi));
    return r;
}

__device__ __forceinline__ void gload_lds16(const void* g, void* l) {
    void* gg = const_cast<void*>(g);
    __builtin_amdgcn_global_load_lds(
        (__attribute__((address_space(1))) uint_t*)gg,
        (__attribute__((address_space(3))) uint_t*)l, 16, 0, 0);
}

// ---------------- batched weight convert: 6 x (2048*2048) into contiguous dst ----------------
struct CvtWArgs { const float* s[6]; };
__global__ __launch_bounds__(256) void k_cvtw(CvtWArgs a, ushort_t* __restrict__ dst) {
    int y = blockIdx.y;
    const float* in = a.s[y];
    ushort_t* out = dst + (size_t)y * 4194304;
    int idx = (blockIdx.x * 256 + threadIdx.x) * 8;
    float4 p = *(const float4*)(in + idx);
    float4 q = *(const float4*)(in + idx + 4);
    uint4 o;
    o.x = (uint_t)f2b(p.x) | ((uint_t)f2b(p.y) << 16);
    o.y = (uint_t)f2b(p.z) | ((uint_t)f2b(p.w) << 16);
    o.z = (uint_t)f2b(q.x) | ((uint_t)f2b(q.y) << 16);
    o.w = (uint_t)f2b(q.z) | ((uint_t)f2b(q.w) << 16);
    *(uint4*)(out + idx) = o;
}

// ---------------- activation converts: x / cam / ren in one dispatch ----------------
struct Cvt3Args { const float* s[3]; ushort_t* d[3]; int n[3]; };
__global__ __launch_bounds__(256) void k_cvt3(Cvt3Args a) {
    int y = blockIdx.y;
    int idx = (blockIdx.x * 256 + threadIdx.x) * 8;
    if (idx >= a.n[y]) return;
    const float* in = a.s[y];
    ushort_t* out = a.d[y];
    float4 p = *(const float4*)(in + idx);
    float4 q = *(const float4*)(in + idx + 4);
    uint4 o;
    o.x = (uint_t)f2b(p.x) | ((uint_t)f2b(p.y) << 16);
    o.y = (uint_t)f2b(p.z) | ((uint_t)f2b(p.w) << 16);
    o.z = (uint_t)f2b(q.x) | ((uint_t)f2b(q.y) << 16);
    o.w = (uint_t)f2b(q.z) | ((uint_t)f2b(q.w) << 16);
    *(uint4*)(out + idx) = o;
}

struct G8 {
    const ushort_t* A;
    const ushort_t* B;
    const float* bias0;
    const float* bias1;
    void* out0;
    void* out1;
};

// ======== 8-phase 256x256x(BK=64) bf16 NT GEMM (merged QKV), 512 thr, 128KB LDS ========
// Q blocks: bf16 row-major out0. KV blocks: cols<2048 -> K bf16 row-major out0;
// cols>=2048 -> V directly into vt tile-major [b,h,t(16)][d=128][kv=64] (out1).
__global__ __launch_bounds__(512, 2) void k_g256(G8 p0, G8 p1, G8 p2) {
    extern __shared__ __align__(16) char sm[];
    int tid = threadIdx.x, lane = tid & 63, w = tid >> 6;
    int c = lane & 15, g = lane >> 4;
    int wr = w >> 2, wc = w & 3;

    int flat = blockIdx.x;
    G8 ar;
    int bm, bn, isKV = 0, kvoff = 0;
    {
        int re = (flat & 7) * 32 + (flat >> 3);
        if (re < 128) { ar = p0; bm = re & 15; bn = re >> 4; }
        else {
            int r2 = re - 128;
            int z = r2 >> 6; r2 &= 63;
            ar = z ? p2 : p1;
            bm = r2 & 3; bn = r2 >> 2;
            isKV = 1; kvoff = z ? 512 : 0;
        }
    }

    int wj0 = 2 * w, wj1 = 2 * w + 1;
    int l3 = lane >> 3;
    int swz = ((lane & 7) ^ l3) << 4;
    int RA0 = (wj0 >> 3) * 128 + (wj0 & 7) * 8 + l3;
    int RA1 = (wj1 >> 3) * 128 + (wj1 & 7) * 8 + l3;
    int RB0 = (wj0 >> 2) * 64 + (wj0 & 3) * 8 + l3;
    int RB1 = (wj1 >> 2) * 64 + (wj1 & 3) * 8 + l3;
    const char* sA0 = (const char*)ar.A + (size_t)(bm * 256 + RA0) * 4096 + swz;
    const char* sA1 = (const char*)ar.A + (size_t)(bm * 256 + RA1) * 4096 + swz;
    const char* sB0 = (const char*)ar.B + (size_t)(bn * 256 + RB0) * 4096 + swz;
    const char* sB1 = (const char*)ar.B + (size_t)(bn * 256 + RB1) * 4096 + swz;
    char* dA0 = sm + wj0 * 1024;
    char* dA1 = sm + wj1 * 1024;
    char* dB0 = sm + 32768 + wj0 * 1024;
    char* dB1 = sm + 32768 + wj1 * 1024;

    auto SA = [&](int buf, int half, int t) {
        gload_lds16(sA0 + (size_t)half * 262144 + t * 128, dA0 + buf + half * 16384);
        gload_lds16(sA1 + (size_t)half * 262144 + t * 128, dA1 + buf + half * 16384);
    };
    auto SB = [&](int buf, int half, int t) {
        gload_lds16(sB0 + (size_t)half * 131072 + t * 128, dB0 + buf + half * 16384);
        gload_lds16(sB1 + (size_t)half * 131072 + t * 128, dB1 + buf + half * 16384);
    };

    int bKS0 = (g << 4) ^ ((c & 7) << 4);
    int bKS1 = (64 | (g << 4)) ^ ((c & 7) << 4);
    int aoffL = wr * 8192 + c * 128;
    int boffL = 32768 + wc * 4096 + c * 128;

    f32x4 acc[8][4];
#pragma unroll
    for (int m = 0; m < 8; m++)
#pragma unroll
        for (int n = 0; n < 4; n++) acc[m][n] = (f32x4){0.f, 0.f, 0.f, 0.f};

    bf16x8 aF[4][2], bF0[2][2], bF1[2][2];

    auto RA = [&](int buf, int mh) {
#pragma unroll
        for (int m = 0; m < 4; m++) {
            aF[m][0] = *(const bf16x8*)(sm + buf + mh * 16384 + aoffL + m * 2048 + bKS0);
            aF[m][1] = *(const bf16x8*)(sm + buf + mh * 16384 + aoffL + m * 2048 + bKS1);
        }
    };
    auto RB = [&](int buf, int nh, bf16x8 (&bF)[2][2]) {
#pragma unroll
        for (int n = 0; n < 2; n++) {
            bF[n][0] = *(const bf16x8*)(sm + buf + boffL + nh * 16384 + n * 2048 + bKS0);
            bF[n][1] = *(const bf16x8*)(sm + buf + boffL + nh * 16384 + n * 2048 + bKS1);
        }
    };
    auto MF = [&](int mh, int nh, bf16x8 (&bF)[2][2]) {
        __builtin_amdgcn_s_setprio(1);
#pragma unroll
        for (int m = 0; m < 4; m++)
#pragma unroll
            for (int n = 0; n < 2; n++)
#pragma unroll
                for (int ks = 0; ks < 2; ks++)
                    acc[mh * 4 + m][nh * 2 + n] = __builtin_amdgcn_mfma_f32_16x16x32_bf16(
                        aF[m][ks], bF[n][ks], acc[mh * 4 + m][nh * 2 + n], 0, 0, 0);
        __builtin_amdgcn_s_setprio(0);
    };

    SA(0, 0, 0); SB(0, 0, 0); SA(0, 1, 0); SB(0, 1, 0);
    SA(65536, 0, 1); SB(65536, 0, 1);
    asm volatile("s_waitcnt vmcnt(8)" ::: "memory");
    __builtin_amdgcn_s_barrier();

#pragma unroll 1
    for (int i = 0; i < 16; ++i) {
        int Tb  = 2 * i + 1;
        int Ta2 = (2 * i + 2 > 31) ? 31 : 2 * i + 2;
        int Tb2 = (2 * i + 3 > 31) ? 31 : 2 * i + 3;
        // p1
        RA(0, 0); RB(0, 0, bF0);
        SA(65536, 1, Tb);
        __builtin_amdgcn_s_barrier();
        MF(0, 0, bF0);
        asm volatile("s_waitcnt vmcnt(6)" ::: "memory");
        __builtin_amdgcn_s_barrier();
        // p2
        RB(0, 1, bF1);
        SB(65536, 1, Tb);
        __builtin_amdgcn_s_barrier();
        MF(0, 1, bF1);
        __builtin_amdgcn_s_barrier();
        // p3
        RA(0, 1);
        SA(0, 0, Ta2);
        __builtin_amdgcn_s_barrier();
        MF(1, 0, bF0);
        __builtin_amdgcn_s_barrier();
        // p4
        SB(0, 0, Ta2);
        __builtin_amdgcn_s_barrier();
        MF(1, 1, bF1);
        asm volatile("s_waitcnt vmcnt(8)" ::: "memory");
        __builtin_amdgcn_s_barrier();
        // p5
        RA(65536, 0); RB(65536, 0, bF0);
        SA(0, 1, Ta2);
        __builtin_amdgcn_s_barrier();
        MF(0, 0, bF0);
        asm volatile("s_waitcnt vmcnt(6)" ::: "memory");
        __builtin_amdgcn_s_barrier();
        // p6
        RB(65536, 1, bF1);
        SB(0, 1, Ta2);
        __builtin_amdgcn_s_barrier();
        MF(0, 1, bF1);
        __builtin_amdgcn_s_barrier();
        // p7
        RA(65536, 1);
        SA(65536, 0, Tb2);
        __builtin_amdgcn_s_barrier();
        MF(1, 0, bF0);
        __builtin_amdgcn_s_barrier();
        // p8
        SB(65536, 0, Tb2);
        __builtin_amdgcn_s_barrier();
        MF(1, 1, bF1);
        asm volatile("s_waitcnt vmcnt(8)" ::: "memory");
        __builtin_amdgcn_s_barrier();
    }

    int orow0 = bm * 256 + wr * 128 + g * 4;
    int ocol0 = bn * 256 + wc * 64 + c;
    if (!isKV || ocol0 < 2048) {
        // Q or K: bf16 row-major, ld 2048
        ushort_t* o0 = (ushort_t*)ar.out0;
#pragma unroll
        for (int n = 0; n < 4; n++) {
            int col = ocol0 + n * 16;
            float bv = ar.bias0[col];
#pragma unroll
            for (int m = 0; m < 8; m++)
#pragma unroll
                for (int q = 0; q < 4; q++)
                    o0[(size_t)(orow0 + m * 16 + q) * 2048 + col] = f2b(acc[m][n][q] + bv);
        }
    } else {
        // V -> vt tile-major [b,h,t][d=128][kv=64] (row stride 64 ushorts!)
        ushort_t* o1 = (ushort_t*)ar.out1;
#pragma unroll
        for (int n = 0; n < 4; n++) {
            int col2 = ocol0 + n * 16 - 2048;
            int h = col2 >> 7, d = col2 & 127;
            float bv = ar.bias1[col2];
#pragma unroll
            for (int m = 0; m < 8; m++) {
                int r = orow0 + m * 16;
                int bb = r >> 9;
                int kvg = kvoff + (r & 511);
                int t = kvg >> 6, ki = kvg & 63;
                uint2 wv;
                wv.x = cvt_pk_bf16(acc[m][n][0] + bv, acc[m][n][1] + bv);
                wv.y = cvt_pk_bf16(acc[m][n][2] + bv, acc[m][n][3] + bv);
                *(uint2*)(o1 + (size_t)(((bb * 16 + h) * 16 + t)) * 8192 + d * 64 + ki) = wv;
            }
        }
    }
}

// ======== 8-phase 128x256x(BK=64) bf16 NT GEMM (out-proj), 512 thr, 96KB LDS, fp32 out ========
__global__ __launch_bounds__(512, 2) void k_g128(G8 p0) {
    extern __shared__ __align__(16) char sm[];
    int tid = threadIdx.x, lane = tid & 63, w = tid >> 6;
    int c = lane & 15, g = lane >> 4;
    int wr = w >> 2, wc = w & 3;

    int flat = blockIdx.x;
    int re = (flat & 7) * 32 + (flat >> 3);
    int bm = re & 31, bn = re >> 5;   // XCD owns one B panel (1MB), streams A
    G8 ar = p0;

    int l3 = lane >> 3;
    int swz = ((lane & 7) ^ l3) << 4;
    int wj0 = 2 * w, wj1 = 2 * w + 1;
    int RB0 = (wj0 >> 2) * 64 + (wj0 & 3) * 8 + l3;
    int RB1 = (wj1 >> 2) * 64 + (wj1 & 3) * 8 + l3;
    const char* sA  = (const char*)ar.A + (size_t)(bm * 128 + w * 8 + l3) * 4096 + swz;
    const char* sB0 = (const char*)ar.B + (size_t)(bn * 256 + RB0) * 4096 + swz;
    const char* sB1 = (const char*)ar.B + (size_t)(bn * 256 + RB1) * 4096 + swz;
    char* dA  = sm + w * 1024;
    char* dB0 = sm + 16384 + wj0 * 1024;
    char* dB1 = sm + 16384 + wj1 * 1024;

    auto SA = [&](int buf, int half, int t) {
        gload_lds16(sA + (size_t)half * 262144 + t * 128, dA + buf + half * 8192);
    };
    auto SB = [&](int buf, int half, int t) {
        gload_lds16(sB0 + (size_t)half * 131072 + t * 128, dB0 + buf + half * 16384);
        gload_lds16(sB1 + (size_t)half * 131072 + t * 128, dB1 + buf + half * 16384);
    };

    int bKS0 = (g << 4) ^ ((c & 7) << 4);
    int bKS1 = (64 | (g << 4)) ^ ((c & 7) << 4);
    int aoffL = wr * 8192 + c * 128;
    int boffL = 16384 + wc * 4096 + c * 128;

    f32x4 acc[4][4];
#pragma unroll
    for (int m = 0; m < 4; m++)
#pragma unroll
        for (int n = 0; n < 4; n++) acc[m][n] = (f32x4){0.f, 0.f, 0.f, 0.f};

    bf16x8 aF[2][2], bF0[2][2], bF1[2][2];

    auto RA = [&](int buf, int mhp) {
#pragma unroll
        for (int m = 0; m < 2; m++) {
            aF[m][0] = *(const bf16x8*)(sm + buf + aoffL + (mhp * 2 + m) * 2048 + bKS0);
            aF[m][1] = *(const bf16x8*)(sm + buf + aoffL + (mhp * 2 + m) * 2048 + bKS1);
        }
    };
    auto RB = [&](int buf, int nh, bf16x8 (&bF)[2][2]) {
#pragma unroll
        for (int n = 0; n < 2; n++) {
            bF[n][0] = *(const bf16x8*)(sm + buf + boffL + nh * 16384 + n * 2048 + bKS0);
            bF[n][1] = *(const bf16x8*)(sm + buf + boffL + nh * 16384 + n * 2048 + bKS1);
        }
    };
    auto MF = [&](int mhp, int nh, bf16x8 (&bF)[2][2]) {
        __builtin_amdgcn_s_setprio(1);
#pragma unroll
        for (int m = 0; m < 2; m++)
#pragma unroll
            for (int n = 0; n < 2; n++)
#pragma unroll
                for (int ks = 0; ks < 2; ks++)
                    acc[mhp * 2 + m][nh * 2 + n] = __builtin_amdgcn_mfma_f32_16x16x32_bf16(
                        aF[m][ks], bF[n][ks], acc[mhp * 2 + m][nh * 2 + n], 0, 0, 0);
        __builtin_amdgcn_s_setprio(0);
    };

    const int B1 = 49152;
    SA(0, 0, 0); SA(0, 1, 0); SB(0, 0, 0); SB(0, 1, 0);
    SA(B1, 0, 1);
    asm volatile("s_waitcnt vmcnt(1)" ::: "memory");
    __builtin_amdgcn_s_barrier();

#pragma unroll 1
    for (int i = 0; i < 16; ++i) {
        int Tb  = 2 * i + 1;
        int Ta2 = (2 * i + 2 > 31) ? 31 : 2 * i + 2;
        int Tb2 = (2 * i + 3 > 31) ? 31 : 2 * i + 3;
        // p1
        RA(0, 0); RB(0, 0, bF0);
        SA(B1, 1, Tb);
        __builtin_amdgcn_s_barrier();
        MF(0, 0, bF0);
        __builtin_amdgcn_s_barrier();
        // p2
        RB(0, 1, bF1);
        SB(B1, 0, Tb);
        __builtin_amdgcn_s_barrier();
        MF(0, 1, bF1);
        __builtin_amdgcn_s_barrier();
        // p3
        RA(0, 1);
        SB(B1, 1, Tb);
        __builtin_amdgcn_s_barrier();
        MF(1, 0, bF0);
        __builtin_amdgcn_s_barrier();
        // p4
        SA(0, 0, Ta2);
        __builtin_amdgcn_s_barrier();
        MF(1, 1, bF1);
        asm volatile("s_waitcnt vmcnt(3)" ::: "memory");
        __builtin_amdgcn_s_barrier();
        // p5
        RA(B1, 0); RB(B1, 0, bF0);
        SA(0, 1, Ta2);
        __builtin_amdgcn_s_barrier();
        MF(0, 0, bF0);
        asm volatile("s_waitcnt vmcnt(2)" ::: "memory");
        __builtin_amdgcn_s_barrier();
        // p6
        RB(B1, 1, bF1);
        SB(0, 0, Ta2);
        __builtin_amdgcn_s_barrier();
        MF(0, 1, bF1);
        __builtin_amdgcn_s_barrier();
        // p7
        RA(B1, 1);
        SB(0, 1, Ta2);
        __builtin_amdgcn_s_barrier();
        MF(1, 0, bF0);
        __builtin_amdgcn_s_barrier();
        // p8
        SA(B1, 0, Tb2);
        __builtin_amdgcn_s_barrier();
        MF(1, 1, bF1);
        asm volatile("s_waitcnt vmcnt(1)" ::: "memory");
        __builtin_amdgcn_s_barrier();
    }

    int orow0 = bm * 128 + wr * 64 + g * 4;
    int ocol0 = bn * 256 + wc * 64 + c;
    float* o0 = (float*)ar.out0;
#pragma unroll
    for (int n = 0; n < 4; n++) {
        int col = ocol0 + n * 16;
        float bv = ar.bias0[col];
#pragma unroll
        for (int m = 0; m < 4; m++)
#pragma unroll
            for (int q = 0; q < 4; q++)
                o0[(size_t)(orow0 + m * 16 + q) * 2048 + col] = acc[m][n][q] + bv;
    }
}

// ---------------- merged RMSNorm + RoPE: bf16 row-major in -> packed [b,h,s,128] bf16 out ----------------
struct RR { const ushort_t* in; const float* gain; const float* freqs; ushort_t* out; int lgS; float scale; };
__global__ __launch_bounds__(256) void k_rr(RR a0, RR a1, RR a2) {
    int bid = blockIdx.x;
    RR a; int row;
    if (bid < 4096) { a = a0; row = bid; }
    else if (bid < 5120) { a = a1; row = bid - 4096; }
    else { a = a2; row = bid - 5120; }
    int S = 1 << a.lgS;
    int s = row & (S - 1);
    int b = row >> a.lgS;
    int tid = threadIdx.x;
    uint4 v = *(const uint4*)(a.in + (size_t)row * 2048 + tid * 8);
    ushort_t us[8];
    us[0] = (ushort_t)(v.x & 0xffff); us[1] = (ushort_t)(v.x >> 16);
    us[2] = (ushort_t)(v.y & 0xffff); us[3] = (ushort_t)(v.y >> 16);
    us[4] = (ushort_t)(v.z & 0xffff); us[5] = (ushort_t)(v.z >> 16);
    us[6] = (ushort_t)(v.w & 0xffff); us[7] = (ushort_t)(v.w >> 16);
    float y[8];
#pragma unroll
    for (int j = 0; j < 8; j++) y[j] = b2f(us[j]);
    float ss = 0.f;
#pragma unroll
    for (int j = 0; j < 8; j++) ss += y[j] * y[j];
#pragma unroll
    for (int off = 32; off > 0; off >>= 1) ss += __shfl_xor(ss, off, 64);
    __shared__ float red[4];
    int lane = tid & 63, wid = tid >> 6;
    if (lane == 0) red[wid] = ss;
    __syncthreads();
    float tot = red[0] + red[1] + red[2] + red[3];
    float inv = rsqrtf(tot * (1.0f / DIM) + 1e-6f);
    const float* gp = a.gain + tid * 8;
    float4 g0 = *(const float4*)gp;
    float4 g1 = *(const float4*)(gp + 4);
    float gg[8] = {g0.x, g0.y, g0.z, g0.w, g1.x, g1.y, g1.z, g1.w};
    int p0 = (tid * 8 & 127) >> 1;
    const float* fq = a.freqs + ((size_t)s * 64 + p0) * 2;
    uint_t ow[4];
#pragma unroll
    for (int j = 0; j < 4; j++) {
        float fr = fq[j * 2 + 0], fi = fq[j * 2 + 1];
        float xr = y[2 * j] * inv * gg[2 * j];
        float xi = y[2 * j + 1] * inv * gg[2 * j + 1];
        float o0 = (xr * fr - xi * fi) * a.scale;
        float o1 = (xr * fi + xi * fr) * a.scale;
        ow[j] = (uint_t)f2b(o0) | ((uint_t)f2b(o1) << 16);
    }
    int h = tid >> 4;
    ushort_t* dst = a.out + ((size_t)((b * 16 + h) * S + s)) * 128 + (tid & 15) * 8;
    *(uint4*)dst = make_uint4(ow[0], ow[1], ow[2], ow[3]);
}

// ---------------- flash attention: 8 waves, 128 q/block, dbuf K/V, packed inputs ----------------
// Q packed [b,h,2048,128]; K packed [b,h,512,128] (cam/ren); V tile-major [b,h,t][128][64].
__global__ __launch_bounds__(512, 4) void k_attn(const ushort_t* __restrict__ Q,
                                                 const ushort_t* __restrict__ Kc,
                                                 const ushort_t* __restrict__ Kr,
                                                 const ushort_t* __restrict__ Vt,
                                                 ushort_t* __restrict__ O) {
    __shared__ __align__(16) char sm[65536];
    int tid = threadIdx.x, lane = tid & 63, w = tid >> 6;
    int c = lane & 15, g = lane >> 4;

    int bid = blockIdx.x;
    int xcd = bid & 7, idx = bid >> 3;
    int combo = idx & 3, qt = idx >> 2;
    int b = combo >> 1, h = xcd * 2 + (combo & 1);
    int bh = b * 16 + h;

    const ushort_t* qg = Q + ((size_t)(bh * 2048 + qt * 128 + w * 16 + c)) * 128 + g * 8;
    bf16x8 aQ[4];
#pragma unroll
    for (int ks = 0; ks < 4; ks++) aQ[ks] = *(const bf16x8*)(qg + ks * 32);

    int kbase[4], vbase[8];
#pragma unroll
    for (int n = 0; n < 4; n++) {
        int row = ((n >> 1) << 5) + ((c >> 2) << 3) + ((n & 1) << 2) + (c & 3);
        int sw = (row & 3) | (((row >> 3) & 3) << 2);
        kbase[n] = row * 256 + ((g ^ sw) << 4);
    }
#pragma unroll
    for (int dt = 0; dt < 8; dt++) {
        int vrow = dt * 16 + c;
        vbase[dt] = vrow * 128 + ((g ^ (vrow & 7)) << 4);
    }

    int swk = (lane >> 4) | ((w & 3) << 2);
    int klo = (8 * w + (lane >> 4)) * 256 + (((lane & 15) ^ swk) << 4);
    int vlo = (16 * w + (lane >> 3)) * 128 + (((lane & 7) ^ (lane >> 3)) << 4);
    int dst0 = w * 2048;

    const char* kcb = (const char*)Kc + (size_t)bh * 131072;
    const char* krb = (const char*)Kr + (size_t)bh * 131072;
    const char* vtb = (const char*)Vt + (size_t)bh * 262144;

    float mr = -1e30f, lr = 0.f;
    f32x4 o[8];
#pragma unroll
    for (int d = 0; d < 8; d++) o[d] = (f32x4){0, 0, 0, 0};

    auto STAGE = [&](int DB, int t) {
        const char* kg = (t < 8) ? kcb + t * 16384 : krb + (t - 8) * 16384;
        const char* vg = vtb + t * 16384;
        gload_lds16(kg + klo, sm + DB + dst0);
        gload_lds16(kg + klo + 1024, sm + DB + dst0 + 1024);
        gload_lds16(vg + vlo, sm + DB + 16384 + dst0);
        gload_lds16(vg + vlo + 1024, sm + DB + 16384 + dst0 + 1024);
    };

    auto TILE = [&](int DB) {
        f32x4 sT[4];
#pragma unroll
        for (int n = 0; n < 4; n++) sT[n] = (f32x4){0, 0, 0, 0};
#pragma unroll
        for (int n = 0; n < 4; n++)
#pragma unroll
            for (int ks = 0; ks < 4; ks++) {
                bf16x8 aK = *(const bf16x8*)(sm + DB + (kbase[n] ^ (ks << 6)));
                sT[n] = __builtin_amdgcn_mfma_f32_16x16x32_bf16(aK, aQ[ks], sT[n], 0, 0, 0);
            }
        float mloc = sT[0][0];
#pragma unroll
        for (int n = 0; n < 4; n++)
#pragma unroll
            for (int r = 0; r < 4; r++) mloc = fmaxf(mloc, sT[n][r]);
        if (!__all(mloc - mr <= 8.0f)) {
            float mx = fmaxf(mloc, __shfl_xor(mloc, 16, 64));
            mx = fmaxf(mx, __shfl_xor(mx, 32, 64));
            float mn = fmaxf(mr, mx);
            float al = exp2f(mr - mn);
            mr = mn;
            lr *= al;
#pragma unroll
            for (int d = 0; d < 8; d++) o[d] *= al;
        }
        float p[4][4];
        float ps = 0.f;
#pragma unroll
        for (int n = 0; n < 4; n++)
#pragma unroll
            for (int r = 0; r < 4; r++) {
                p[n][r] = exp2f(sT[n][r] - mr);
                ps += p[n][r];
            }
        lr += ps;   // per-lane partial; reduced across groups at the end
#pragma unroll
        for (int kk = 0; kk < 2; kk++) {
            union { uint_t u[4]; bf16x8 v; } bP;
            bP.u[0] = cvt_pk_bf16(p[2 * kk][0], p[2 * kk][1]);
            bP.u[1] = cvt_pk_bf16(p[2 * kk][2], p[2 * kk][3]);
            bP.u[2] = cvt_pk_bf16(p[2 * kk + 1][0], p[2 * kk + 1][1]);
            bP.u[3] = cvt_pk_bf16(p[2 * kk + 1][2], p[2 * kk + 1][3]);
#pragma unroll
            for (int dt = 0; dt < 8; dt++) {
                bf16x8 aV = *(const bf16x8*)(sm + DB + 16384 + (vbase[dt] ^ (kk << 6)));
                o[dt] = __builtin_amdgcn_mfma_f32_16x16x32_bf16(aV, bP.v, o[dt], 0, 0, 0);
            }
        }
    };

    STAGE(0, 0);
    __syncthreads();
#pragma unroll 1
    for (int t = 0; t < 16; t += 2) {
        STAGE(32768, t + 1);
        TILE(0);
        __syncthreads();
        if (t < 14) STAGE(0, t + 2);
        TILE(32768);
        __syncthreads();
    }

    lr += __shfl_xor(lr, 16, 64);
    lr += __shfl_xor(lr, 32, 64);
    float inv = 1.0f / lr;
    ushort_t* lO = (ushort_t*)sm;
#pragma unroll
    for (int dt = 0; dt < 8; dt++) {
        uint2 wv;
        wv.x = (uint_t)f2b(o[dt][0] * inv) | ((uint_t)f2b(o[dt][1] * inv) << 16);
        wv.y = (uint_t)f2b(o[dt][2] * inv) | ((uint_t)f2b(o[dt][3] * inv) << 16);
        *(uint2*)(lO + (w * 16 + c) * 136 + dt * 16 + g * 4) = wv;
    }
    __syncthreads();
    int row = tid >> 2, c8 = tid & 3;
    const ushort_t* src = lO + row * 136 + c8 * 32;
    ushort_t* dst = O + (size_t)(b * 2048 + qt * 128 + row) * 2048 + h * 128 + c8 * 32;
#pragma unroll
    for (int k = 0; k < 4; k++) *(uint4*)(dst + k * 8) = *(const uint4*)(src + k * 8);
}

extern "C" void kernel_launch(void* const* d_in, const int* in_sizes, int n_in,
                              void* d_out, int out_size, void* d_ws, size_t ws_size,
                              hipStream_t stream) {
    const float* x   = (const float*)d_in[0];
    const float* cam = (const float*)d_in[1];
    const float* ren = (const float*)d_in[2];
    const float* fx  = (const float*)d_in[3];
    const float* fc  = (const float*)d_in[4];
    const float* fr  = (const float*)d_in[5];
    const float* wq  = (const float*)d_in[6];
    const float* bq  = (const float*)d_in[7];
    const float* wk  = (const float*)d_in[8];
    const float* bk  = (const float*)d_in[9];
    const float* wv  = (const float*)d_in[10];
    const float* bv  = (const float*)d_in[11];
    const float* wkr = (const float*)d_in[12];
    const float* bkr = (const float*)d_in[13];
    const float* wvr = (const float*)d_in[14];
    const float* bvr = (const float*)d_in[15];
    const float* wo  = (const float*)d_in[16];
    const float* bo  = (const float*)d_in[17];
    const float* gq  = (const float*)d_in[18];
    const float* gk  = (const float*)d_in[19];

    char* ws = (char*)d_ws;
    ushort_t* wq_b     = (ushort_t*)(ws + 0);
    ushort_t* wk_b     = (ushort_t*)(ws + 8388608);    // wk||wv contiguous (N=4096)
    ushort_t* wkr_b    = (ushort_t*)(ws + 25165824);   // wkr||wvr contiguous
    ushort_t* wo_b     = (ushort_t*)(ws + 41943040);
    ushort_t* xb       = (ushort_t*)(ws + 50331648);   // reused by attn_bf later
    ushort_t* camb     = (ushort_t*)(ws + 67108864);
    ushort_t* renb     = (ushort_t*)(ws + 71303168);
    ushort_t* kcam_lin = (ushort_t*)(ws + 75497472);   // bf16 [1024][2048]
    ushort_t* kren_lin = (ushort_t*)(ws + 79691776);
    ushort_t* vt       = (ushort_t*)(ws + 83886080);   // tile-major V, 8MB
    ushort_t* q_bf     = (ushort_t*)(ws + 92274688);   // packed [b,h,2048,128]
    ushort_t* kcam_bf  = (ushort_t*)(ws + 109051904);  // packed [b,h,512,128]
    ushort_t* kren_bf  = (ushort_t*)(ws + 113246208);
    ushort_t* attn_bf  = (ushort_t*)(ws + 50331648);   // overlays dead xb
    ushort_t* q_lin    = (ushort_t*)d_out;             // d_out doubles as bf16 Q-proj scratch

    hipFuncSetAttribute(reinterpret_cast<const void*>(&k_g256),
                        hipFuncAttributeMaxDynamicSharedMemorySize, 131072);
    hipFuncSetAttribute(reinterpret_cast<const void*>(&k_g128),
                        hipFuncAttributeMaxDynamicSharedMemorySize, 98304);

    // fp32 -> bf16 converts
    CvtWArgs cw{{wq, wk, wv, wkr, wvr, wo}};
    k_cvtw<<<dim3(2048, 6), 256, 0, stream>>>(cw, wq_b);
    Cvt3Args c3{{x, cam, ren}, {xb, camb, renb}, {8388608, 2097152, 2097152}};
    k_cvt3<<<dim3(4096, 3), 256, 0, stream>>>(c3);

    // merged Q + K/V projections (8-phase 256^2, 256 blocks); V lands in vt directly
    G8 qa{xb, wq_b, bq, nullptr, (void*)q_lin, nullptr};
    G8 kva0{camb, wk_b, bk, bv, (void*)kcam_lin, (void*)vt};
    G8 kva1{renb, wkr_b, bkr, bvr, (void*)kren_lin, (void*)vt};
    k_g256<<<dim3(256, 1, 1), 512, 131072, stream>>>(qa, kva0, kva1);

    // merged RMSNorm+RoPE (Q folds (1/sqrt(HD))*log2(e)); outputs packed per-head
    RR r0{q_lin, gq, fx, q_bf, 11, 0.08838834764831845f * 1.4426950408889634f};
    RR r1{kcam_lin, gk, fc, kcam_bf, 9, 1.0f};
    RR r2{kren_lin, gk, fr, kren_bf, 9, 1.0f};
    k_rr<<<dim3(6144, 1, 1), 256, 0, stream>>>(r0, r1, r2);

    // flash attention (flat 512, XCD-pinned, contiguous staging)
    k_attn<<<dim3(512, 1, 1), 512, 0, stream>>>(q_bf, kcam_bf, kren_bf, vt, attn_bf);

    // output projection -> d_out (fp32), 8-phase 128x256, 256 blocks
    G8 oa{attn_bf, wo_b, bo, nullptr, d_out, nullptr};
    k_g128<<<dim3(256, 1, 1), 512, 98304, stream>>>(oa);
}

// Round 10
// 207.938 us; speedup vs baseline: 1.9390x; 1.0213x over previous
//
#include <hip/hip_runtime.h>

typedef short bf16x8 __attribute__((ext_vector_type(8)));
typedef float f32x4 __attribute__((ext_vector_type(4)));
typedef unsigned short ushort_t;
typedef unsigned int uint_t;

#define DIM 2048
#define NH 16
#define HD 128

__device__ __forceinline__ ushort_t f2b(float f) {
    union { float f; uint_t u; } a; a.f = f;
    uint_t u = a.u;
    return (ushort_t)((u + 0x7fffu + ((u >> 16) & 1u)) >> 16);
}

__device__ __forceinline__ float b2f(ushort_t s) {
    union { uint_t u; float f; } a; a.u = ((uint_t)s) << 16;
    return a.f;
}

__device__ __forceinline__ uint_t cvt_pk_bf16(float lo, float hi) {
    uint_t r;
    asm("v_cvt_pk_bf16_f32 %0, %1, %2" : "=v"(r) : "v"(lo), "v"(hi));
    return r;
}

__device__ __forceinline__ void gload_lds16(const void* g, void* l) {
    void* gg = const_cast<void*>(g);
    __builtin_amdgcn_global_load_lds(
        (__attribute__((address_space(1))) uint_t*)gg,
        (__attribute__((address_space(3))) uint_t*)l, 16, 0, 0);
}

// ---------------- batched weight convert: 6 x (2048*2048) into contiguous dst ----------------
struct CvtWArgs { const float* s[6]; };
__global__ __launch_bounds__(256) void k_cvtw(CvtWArgs a, ushort_t* __restrict__ dst) {
    int y = blockIdx.y;
    const float* in = a.s[y];
    ushort_t* out = dst + (size_t)y * 4194304;
    int idx = (blockIdx.x * 256 + threadIdx.x) * 8;
    float4 p = *(const float4*)(in + idx);
    float4 q = *(const float4*)(in + idx + 4);
    uint4 o;
    o.x = (uint_t)f2b(p.x) | ((uint_t)f2b(p.y) << 16);
    o.y = (uint_t)f2b(p.z) | ((uint_t)f2b(p.w) << 16);
    o.z = (uint_t)f2b(q.x) | ((uint_t)f2b(q.y) << 16);
    o.w = (uint_t)f2b(q.z) | ((uint_t)f2b(q.w) << 16);
    *(uint4*)(out + idx) = o;
}

// ---------------- activation converts: x / cam / ren in one dispatch ----------------
struct Cvt3Args { const float* s[3]; ushort_t* d[3]; int n[3]; };
__global__ __launch_bounds__(256) void k_cvt3(Cvt3Args a) {
    int y = blockIdx.y;
    int idx = (blockIdx.x * 256 + threadIdx.x) * 8;
    if (idx >= a.n[y]) return;
    const float* in = a.s[y];
    ushort_t* out = a.d[y];
    float4 p = *(const float4*)(in + idx);
    float4 q = *(const float4*)(in + idx + 4);
    uint4 o;
    o.x = (uint_t)f2b(p.x) | ((uint_t)f2b(p.y) << 16);
    o.y = (uint_t)f2b(p.z) | ((uint_t)f2b(p.w) << 16);
    o.z = (uint_t)f2b(q.x) | ((uint_t)f2b(q.y) << 16);
    o.w = (uint_t)f2b(q.z) | ((uint_t)f2b(q.w) << 16);
    *(uint4*)(out + idx) = o;
}

struct G8 {
    const ushort_t* A;
    const ushort_t* B;
    const float* bias0;
    const float* bias1;
    void* out0;
    void* out1;
};

// ======== 8-phase 256x256x(BK=64) bf16 NT GEMM (merged QKV), 512 thr, 128KB LDS ========
// B rows staged with within-32 permutation rho(j)=(j&15)*2+(j>>4) so lane c owns
// output cols {c*2, c*2+1} per (wc,nh) window -> packed uint stores.
__global__ __launch_bounds__(512, 2) void k_g256(G8 p0, G8 p1, G8 p2) {
    extern __shared__ __align__(16) char sm[];
    int tid = threadIdx.x, lane = tid & 63, w = tid >> 6;
    int c = lane & 15, g = lane >> 4;
    int wr = w >> 2, wc = w & 3;

    int flat = blockIdx.x;
    G8 ar;
    int bm, bn, isKV = 0, kvoff = 0;
    {
        int re = (flat & 7) * 32 + (flat >> 3);
        if (re < 128) { ar = p0; bm = re & 15; bn = re >> 4; }
        else {
            int r2 = re - 128;
            int z = r2 >> 6; r2 &= 63;
            ar = z ? p2 : p1;
            bm = r2 & 3; bn = r2 >> 2;
            isKV = 1; kvoff = z ? 512 : 0;
        }
    }

    int wj0 = 2 * w, wj1 = 2 * w + 1;
    int l3 = lane >> 3;
    int swz = ((lane & 7) ^ l3) << 4;
    int RA0 = (wj0 >> 3) * 128 + (wj0 & 7) * 8 + l3;
    int RA1 = (wj1 >> 3) * 128 + (wj1 & 7) * 8 + l3;
    // B source rows: rho-permuted within each 32-row window (packed-epilogue map)
    int LB0 = wj0 * 8 + l3;
    int LB1 = wj1 * 8 + l3;
    int RB0 = (LB0 >> 5) * 64 + (LB0 & 15) * 2 + ((LB0 >> 4) & 1);
    int RB1 = (LB1 >> 5) * 64 + (LB1 & 15) * 2 + ((LB1 >> 4) & 1);
    const char* sA0 = (const char*)ar.A + (size_t)(bm * 256 + RA0) * 4096 + swz;
    const char* sA1 = (const char*)ar.A + (size_t)(bm * 256 + RA1) * 4096 + swz;
    const char* sB0 = (const char*)ar.B + (size_t)(bn * 256 + RB0) * 4096 + swz;
    const char* sB1 = (const char*)ar.B + (size_t)(bn * 256 + RB1) * 4096 + swz;
    char* dA0 = sm + wj0 * 1024;
    char* dA1 = sm + wj1 * 1024;
    char* dB0 = sm + 32768 + wj0 * 1024;
    char* dB1 = sm + 32768 + wj1 * 1024;

    auto SA = [&](int buf, int half, int t) {
        gload_lds16(sA0 + (size_t)half * 262144 + t * 128, dA0 + buf + half * 16384);
        gload_lds16(sA1 + (size_t)half * 262144 + t * 128, dA1 + buf + half * 16384);
    };
    auto SB = [&](int buf, int half, int t) {
        gload_lds16(sB0 + (size_t)half * 131072 + t * 128, dB0 + buf + half * 16384);
        gload_lds16(sB1 + (size_t)half * 131072 + t * 128, dB1 + buf + half * 16384);
    };

    int bKS0 = (g << 4) ^ ((c & 7) << 4);
    int bKS1 = (64 | (g << 4)) ^ ((c & 7) << 4);
    int aoffL = wr * 8192 + c * 128;
    int boffL = 32768 + wc * 4096 + c * 128;

    f32x4 acc[8][4];
#pragma unroll
    for (int m = 0; m < 8; m++)
#pragma unroll
        for (int n = 0; n < 4; n++) acc[m][n] = (f32x4){0.f, 0.f, 0.f, 0.f};

    bf16x8 aF[4][2], bF0[2][2], bF1[2][2];

    auto RA = [&](int buf, int mh) {
#pragma unroll
        for (int m = 0; m < 4; m++) {
            aF[m][0] = *(const bf16x8*)(sm + buf + mh * 16384 + aoffL + m * 2048 + bKS0);
            aF[m][1] = *(const bf16x8*)(sm + buf + mh * 16384 + aoffL + m * 2048 + bKS1);
        }
    };
    auto RB = [&](int buf, int nh, bf16x8 (&bF)[2][2]) {
#pragma unroll
        for (int n = 0; n < 2; n++) {
            bF[n][0] = *(const bf16x8*)(sm + buf + boffL + nh * 16384 + n * 2048 + bKS0);
            bF[n][1] = *(const bf16x8*)(sm + buf + boffL + nh * 16384 + n * 2048 + bKS1);
        }
    };
    auto MF = [&](int mh, int nh, bf16x8 (&bF)[2][2]) {
        __builtin_amdgcn_s_setprio(1);
#pragma unroll
        for (int m = 0; m < 4; m++)
#pragma unroll
            for (int n = 0; n < 2; n++)
#pragma unroll
                for (int ks = 0; ks < 2; ks++)
                    acc[mh * 4 + m][nh * 2 + n] = __builtin_amdgcn_mfma_f32_16x16x32_bf16(
                        aF[m][ks], bF[n][ks], acc[mh * 4 + m][nh * 2 + n], 0, 0, 0);
        __builtin_amdgcn_s_setprio(0);
    };

    SA(0, 0, 0); SB(0, 0, 0); SA(0, 1, 0); SB(0, 1, 0);
    SA(65536, 0, 1); SB(65536, 0, 1);
    asm volatile("s_waitcnt vmcnt(8)" ::: "memory");
    __builtin_amdgcn_s_barrier();

#pragma unroll 1
    for (int i = 0; i < 16; ++i) {
        int Tb  = 2 * i + 1;
        int Ta2 = (2 * i + 2 > 31) ? 31 : 2 * i + 2;
        int Tb2 = (2 * i + 3 > 31) ? 31 : 2 * i + 3;
        // p1
        RA(0, 0); RB(0, 0, bF0);
        SA(65536, 1, Tb);
        __builtin_amdgcn_s_barrier();
        MF(0, 0, bF0);
        asm volatile("s_waitcnt vmcnt(6)" ::: "memory");
        __builtin_amdgcn_s_barrier();
        // p2
        RB(0, 1, bF1);
        SB(65536, 1, Tb);
        __builtin_amdgcn_s_barrier();
        MF(0, 1, bF1);
        __builtin_amdgcn_s_barrier();
        // p3
        RA(0, 1);
        SA(0, 0, Ta2);
        __builtin_amdgcn_s_barrier();
        MF(1, 0, bF0);
        __builtin_amdgcn_s_barrier();
        // p4
        SB(0, 0, Ta2);
        __builtin_amdgcn_s_barrier();
        MF(1, 1, bF1);
        asm volatile("s_waitcnt vmcnt(8)" ::: "memory");
        __builtin_amdgcn_s_barrier();
        // p5
        RA(65536, 0); RB(65536, 0, bF0);
        SA(0, 1, Ta2);
        __builtin_amdgcn_s_barrier();
        MF(0, 0, bF0);
        asm volatile("s_waitcnt vmcnt(6)" ::: "memory");
        __builtin_amdgcn_s_barrier();
        // p6
        RB(65536, 1, bF1);
        SB(0, 1, Ta2);
        __builtin_amdgcn_s_barrier();
        MF(0, 1, bF1);
        __builtin_amdgcn_s_barrier();
        // p7
        RA(65536, 1);
        SA(65536, 0, Tb2);
        __builtin_amdgcn_s_barrier();
        MF(1, 0, bF0);
        __builtin_amdgcn_s_barrier();
        // p8
        SB(65536, 0, Tb2);
        __builtin_amdgcn_s_barrier();
        MF(1, 1, bF1);
        asm volatile("s_waitcnt vmcnt(8)" ::: "memory");
        __builtin_amdgcn_s_barrier();
    }

    // epilogue: lane owns cols colb0+nh*32+{0,1}; rows orow0+m*16+q
    int orow0 = bm * 256 + wr * 128 + g * 4;
    int colb0 = bn * 256 + wc * 64 + c * 2;
    if (!isKV || bn < 8) {
        // Q or K: bf16 row-major ld 2048; packed uint stores (64B/16-lane group)
        ushort_t* o0 = (ushort_t*)ar.out0;
#pragma unroll
        for (int nh = 0; nh < 2; nh++) {
            int colb = colb0 + nh * 32;
            float2 bv = *(const float2*)(ar.bias0 + colb);
#pragma unroll
            for (int m = 0; m < 8; m++)
#pragma unroll
                for (int q = 0; q < 4; q++) {
                    uint_t pk = cvt_pk_bf16(acc[m][nh * 2][q] + bv.x,
                                            acc[m][nh * 2 + 1][q] + bv.y);
                    *(uint_t*)(o0 + (size_t)(orow0 + m * 16 + q) * 2048 + colb) = pk;
                }
        }
    } else {
        // V -> vt tile-major [b,h,t][d=128][kv=64] (row stride 64 ushorts)
        ushort_t* o1 = (ushort_t*)ar.out1;
#pragma unroll
        for (int nh = 0; nh < 2; nh++)
#pragma unroll
            for (int np = 0; np < 2; np++) {
                int col2 = colb0 + nh * 32 + np - 2048;
                int h = col2 >> 7, d = col2 & 127;
                float bvs = ar.bias1[col2];
#pragma unroll
                for (int m = 0; m < 8; m++) {
                    int r = orow0 + m * 16;
                    int bb = r >> 9;
                    int kvg = kvoff + (r & 511);
                    int t = kvg >> 6, ki = kvg & 63;
                    uint2 wv;
                    wv.x = cvt_pk_bf16(acc[m][nh * 2 + np][0] + bvs, acc[m][nh * 2 + np][1] + bvs);
                    wv.y = cvt_pk_bf16(acc[m][nh * 2 + np][2] + bvs, acc[m][nh * 2 + np][3] + bvs);
                    *(uint2*)(o1 + (size_t)((bb * 16 + h) * 16 + t) * 8192 + d * 64 + ki) = wv;
                }
            }
    }
}

// ======== 8-phase 128x256x(BK=64) bf16 NT GEMM (out-proj), 512 thr, 96KB LDS, fp32 out ========
__global__ __launch_bounds__(512, 2) void k_g128(G8 p0) {
    extern __shared__ __align__(16) char sm[];
    int tid = threadIdx.x, lane = tid & 63, w = tid >> 6;
    int c = lane & 15, g = lane >> 4;
    int wr = w >> 2, wc = w & 3;

    int flat = blockIdx.x;
    int re = (flat & 7) * 32 + (flat >> 3);
    int bm = re & 31, bn = re >> 5;   // XCD owns one B panel (1MB), streams A
    G8 ar = p0;

    int l3 = lane >> 3;
    int swz = ((lane & 7) ^ l3) << 4;
    int wj0 = 2 * w, wj1 = 2 * w + 1;
    int LB0 = wj0 * 8 + l3;
    int LB1 = wj1 * 8 + l3;
    int RB0 = (LB0 >> 5) * 64 + (LB0 & 15) * 2 + ((LB0 >> 4) & 1);
    int RB1 = (LB1 >> 5) * 64 + (LB1 & 15) * 2 + ((LB1 >> 4) & 1);
    const char* sA  = (const char*)ar.A + (size_t)(bm * 128 + w * 8 + l3) * 4096 + swz;
    const char* sB0 = (const char*)ar.B + (size_t)(bn * 256 + RB0) * 4096 + swz;
    const char* sB1 = (const char*)ar.B + (size_t)(bn * 256 + RB1) * 4096 + swz;
    char* dA  = sm + w * 1024;
    char* dB0 = sm + 16384 + wj0 * 1024;
    char* dB1 = sm + 16384 + wj1 * 1024;

    auto SA = [&](int buf, int half, int t) {
        gload_lds16(sA + (size_t)half * 262144 + t * 128, dA + buf + half * 8192);
    };
    auto SB = [&](int buf, int half, int t) {
        gload_lds16(sB0 + (size_t)half * 131072 + t * 128, dB0 + buf + half * 16384);
        gload_lds16(sB1 + (size_t)half * 131072 + t * 128, dB1 + buf + half * 16384);
    };

    int bKS0 = (g << 4) ^ ((c & 7) << 4);
    int bKS1 = (64 | (g << 4)) ^ ((c & 7) << 4);
    int aoffL = wr * 8192 + c * 128;
    int boffL = 16384 + wc * 4096 + c * 128;

    f32x4 acc[4][4];
#pragma unroll
    for (int m = 0; m < 4; m++)
#pragma unroll
        for (int n = 0; n < 4; n++) acc[m][n] = (f32x4){0.f, 0.f, 0.f, 0.f};

    bf16x8 aF[2][2], bF0[2][2], bF1[2][2];

    auto RA = [&](int buf, int mhp) {
#pragma unroll
        for (int m = 0; m < 2; m++) {
            aF[m][0] = *(const bf16x8*)(sm + buf + aoffL + (mhp * 2 + m) * 2048 + bKS0);
            aF[m][1] = *(const bf16x8*)(sm + buf + aoffL + (mhp * 2 + m) * 2048 + bKS1);
        }
    };
    auto RB = [&](int buf, int nh, bf16x8 (&bF)[2][2]) {
#pragma unroll
        for (int n = 0; n < 2; n++) {
            bF[n][0] = *(const bf16x8*)(sm + buf + boffL + nh * 16384 + n * 2048 + bKS0);
            bF[n][1] = *(const bf16x8*)(sm + buf + boffL + nh * 16384 + n * 2048 + bKS1);
        }
    };
    auto MF = [&](int mhp, int nh, bf16x8 (&bF)[2][2]) {
        __builtin_amdgcn_s_setprio(1);
#pragma unroll
        for (int m = 0; m < 2; m++)
#pragma unroll
            for (int n = 0; n < 2; n++)
#pragma unroll
                for (int ks = 0; ks < 2; ks++)
                    acc[mhp * 2 + m][nh * 2 + n] = __builtin_amdgcn_mfma_f32_16x16x32_bf16(
                        aF[m][ks], bF[n][ks], acc[mhp * 2 + m][nh * 2 + n], 0, 0, 0);
        __builtin_amdgcn_s_setprio(0);
    };

    const int B1 = 49152;
    SA(0, 0, 0); SA(0, 1, 0); SB(0, 0, 0); SB(0, 1, 0);
    SA(B1, 0, 1);
    asm volatile("s_waitcnt vmcnt(1)" ::: "memory");
    __builtin_amdgcn_s_barrier();

#pragma unroll 1
    for (int i = 0; i < 16; ++i) {
        int Tb  = 2 * i + 1;
        int Ta2 = (2 * i + 2 > 31) ? 31 : 2 * i + 2;
        int Tb2 = (2 * i + 3 > 31) ? 31 : 2 * i + 3;
        // p1
        RA(0, 0); RB(0, 0, bF0);
        SA(B1, 1, Tb);
        __builtin_amdgcn_s_barrier();
        MF(0, 0, bF0);
        __builtin_amdgcn_s_barrier();
        // p2
        RB(0, 1, bF1);
        SB(B1, 0, Tb);
        __builtin_amdgcn_s_barrier();
        MF(0, 1, bF1);
        __builtin_amdgcn_s_barrier();
        // p3
        RA(0, 1);
        SB(B1, 1, Tb);
        __builtin_amdgcn_s_barrier();
        MF(1, 0, bF0);
        __builtin_amdgcn_s_barrier();
        // p4
        SA(0, 0, Ta2);
        __builtin_amdgcn_s_barrier();
        MF(1, 1, bF1);
        asm volatile("s_waitcnt vmcnt(3)" ::: "memory");
        __builtin_amdgcn_s_barrier();
        // p5
        RA(B1, 0); RB(B1, 0, bF0);
        SA(0, 1, Ta2);
        __builtin_amdgcn_s_barrier();
        MF(0, 0, bF0);
        asm volatile("s_waitcnt vmcnt(2)" ::: "memory");
        __builtin_amdgcn_s_barrier();
        // p6
        RB(B1, 1, bF1);
        SB(0, 0, Ta2);
        __builtin_amdgcn_s_barrier();
        MF(0, 1, bF1);
        __builtin_amdgcn_s_barrier();
        // p7
        RA(B1, 1);
        SB(0, 1, Ta2);
        __builtin_amdgcn_s_barrier();
        MF(1, 0, bF0);
        __builtin_amdgcn_s_barrier();
        // p8
        SA(B1, 0, Tb2);
        __builtin_amdgcn_s_barrier();
        MF(1, 1, bF1);
        asm volatile("s_waitcnt vmcnt(1)" ::: "memory");
        __builtin_amdgcn_s_barrier();
    }

    // epilogue: float2 stores -> 128B full lines per 16-lane group
    int orow0 = bm * 128 + wr * 64 + g * 4;
    int colb0 = bn * 256 + wc * 64 + c * 2;
    float* o0 = (float*)ar.out0;
#pragma unroll
    for (int nh = 0; nh < 2; nh++) {
        int colb = colb0 + nh * 32;
        float2 bv = *(const float2*)(ar.bias0 + colb);
#pragma unroll
        for (int m = 0; m < 4; m++)
#pragma unroll
            for (int q = 0; q < 4; q++) {
                float2 st = {acc[m][nh * 2][q] + bv.x, acc[m][nh * 2 + 1][q] + bv.y};
                *(float2*)(o0 + (size_t)(orow0 + m * 16 + q) * 2048 + colb) = st;
            }
    }
}

// ---------------- merged RMSNorm + RoPE: bf16 row-major in -> packed [b,h,s,128] bf16 out ----------------
struct RR { const ushort_t* in; const float* gain; const float* freqs; ushort_t* out; int lgS; float scale; };
__global__ __launch_bounds__(256) void k_rr(RR a0, RR a1, RR a2) {
    int bid = blockIdx.x;
    RR a; int row;
    if (bid < 4096) { a = a0; row = bid; }
    else if (bid < 5120) { a = a1; row = bid - 4096; }
    else { a = a2; row = bid - 5120; }
    int S = 1 << a.lgS;
    int s = row & (S - 1);
    int b = row >> a.lgS;
    int tid = threadIdx.x;
    uint4 v = *(const uint4*)(a.in + (size_t)row * 2048 + tid * 8);
    ushort_t us[8];
    us[0] = (ushort_t)(v.x & 0xffff); us[1] = (ushort_t)(v.x >> 16);
    us[2] = (ushort_t)(v.y & 0xffff); us[3] = (ushort_t)(v.y >> 16);
    us[4] = (ushort_t)(v.z & 0xffff); us[5] = (ushort_t)(v.z >> 16);
    us[6] = (ushort_t)(v.w & 0xffff); us[7] = (ushort_t)(v.w >> 16);
    float y[8];
#pragma unroll
    for (int j = 0; j < 8; j++) y[j] = b2f(us[j]);
    float ss = 0.f;
#pragma unroll
    for (int j = 0; j < 8; j++) ss += y[j] * y[j];
#pragma unroll
    for (int off = 32; off > 0; off >>= 1) ss += __shfl_xor(ss, off, 64);
    __shared__ float red[4];
    int lane = tid & 63, wid = tid >> 6;
    if (lane == 0) red[wid] = ss;
    __syncthreads();
    float tot = red[0] + red[1] + red[2] + red[3];
    float inv = rsqrtf(tot * (1.0f / DIM) + 1e-6f);
    const float* gp = a.gain + tid * 8;
    float4 g0 = *(const float4*)gp;
    float4 g1 = *(const float4*)(gp + 4);
    float gg[8] = {g0.x, g0.y, g0.z, g0.w, g1.x, g1.y, g1.z, g1.w};
    int p0 = (tid * 8 & 127) >> 1;
    const float* fq = a.freqs + ((size_t)s * 64 + p0) * 2;
    uint_t ow[4];
#pragma unroll
    for (int j = 0; j < 4; j++) {
        float fr = fq[j * 2 + 0], fi = fq[j * 2 + 1];
        float xr = y[2 * j] * inv * gg[2 * j];
        float xi = y[2 * j + 1] * inv * gg[2 * j + 1];
        float o0 = (xr * fr - xi * fi) * a.scale;
        float o1 = (xr * fi + xi * fr) * a.scale;
        ow[j] = (uint_t)f2b(o0) | ((uint_t)f2b(o1) << 16);
    }
    int h = tid >> 4;
    ushort_t* dst = a.out + ((size_t)((b * 16 + h) * S + s)) * 128 + (tid & 15) * 8;
    *(uint4*)dst = make_uint4(ow[0], ow[1], ow[2], ow[3]);
}

// ---------------- flash attention: 8 waves, 128 q/block, dbuf K/V, packed inputs ----------------
__global__ __launch_bounds__(512, 4) void k_attn(const ushort_t* __restrict__ Q,
                                                 const ushort_t* __restrict__ Kc,
                                                 const ushort_t* __restrict__ Kr,
                                                 const ushort_t* __restrict__ Vt,
                                                 ushort_t* __restrict__ O) {
    __shared__ __align__(16) char sm[65536];
    int tid = threadIdx.x, lane = tid & 63, w = tid >> 6;
    int c = lane & 15, g = lane >> 4;

    int bid = blockIdx.x;
    int xcd = bid & 7, idx = bid >> 3;
    int combo = idx & 3, qt = idx >> 2;
    int b = combo >> 1, h = xcd * 2 + (combo & 1);
    int bh = b * 16 + h;

    const ushort_t* qg = Q + ((size_t)(bh * 2048 + qt * 128 + w * 16 + c)) * 128 + g * 8;
    bf16x8 aQ[4];
#pragma unroll
    for (int ks = 0; ks < 4; ks++) aQ[ks] = *(const bf16x8*)(qg + ks * 32);

    int kbase[4], vbase[8];
#pragma unroll
    for (int n = 0; n < 4; n++) {
        int row = ((n >> 1) << 5) + ((c >> 2) << 3) + ((n & 1) << 2) + (c & 3);
        int sw = (row & 3) | (((row >> 3) & 3) << 2);
        kbase[n] = row * 256 + ((g ^ sw) << 4);
    }
#pragma unroll
    for (int dt = 0; dt < 8; dt++) {
        int vrow = dt * 16 + c;
        vbase[dt] = vrow * 128 + ((g ^ (vrow & 7)) << 4);
    }

    int swk = (lane >> 4) | ((w & 3) << 2);
    int klo = (8 * w + (lane >> 4)) * 256 + (((lane & 15) ^ swk) << 4);
    int vlo = (16 * w + (lane >> 3)) * 128 + (((lane & 7) ^ (lane >> 3)) << 4);
    int dst0 = w * 2048;

    const char* kcb = (const char*)Kc + (size_t)bh * 131072;
    const char* krb = (const char*)Kr + (size_t)bh * 131072;
    const char* vtb = (const char*)Vt + (size_t)bh * 262144;

    float mr = -1e30f, lr = 0.f;
    f32x4 o[8];
#pragma unroll
    for (int d = 0; d < 8; d++) o[d] = (f32x4){0, 0, 0, 0};

    auto STAGE = [&](int DB, int t) {
        const char* kg = (t < 8) ? kcb + t * 16384 : krb + (t - 8) * 16384;
        const char* vg = vtb + t * 16384;
        gload_lds16(kg + klo, sm + DB + dst0);
        gload_lds16(kg + klo + 1024, sm + DB + dst0 + 1024);
        gload_lds16(vg + vlo, sm + DB + 16384 + dst0);
        gload_lds16(vg + vlo + 1024, sm + DB + 16384 + dst0 + 1024);
    };

    auto TILE = [&](int DB) {
        f32x4 sT[4];
#pragma unroll
        for (int n = 0; n < 4; n++) sT[n] = (f32x4){0, 0, 0, 0};
#pragma unroll
        for (int n = 0; n < 4; n++)
#pragma unroll
            for (int ks = 0; ks < 4; ks++) {
                bf16x8 aK = *(const bf16x8*)(sm + DB + (kbase[n] ^ (ks << 6)));
                sT[n] = __builtin_amdgcn_mfma_f32_16x16x32_bf16(aK, aQ[ks], sT[n], 0, 0, 0);
            }
        float mloc = sT[0][0];
#pragma unroll
        for (int n = 0; n < 4; n++)
#pragma unroll
            for (int r = 0; r < 4; r++) mloc = fmaxf(mloc, sT[n][r]);
        if (!__all(mloc - mr <= 8.0f)) {
            float mx = fmaxf(mloc, __shfl_xor(mloc, 16, 64));
            mx = fmaxf(mx, __shfl_xor(mx, 32, 64));
            float mn = fmaxf(mr, mx);
            float al = exp2f(mr - mn);
            mr = mn;
            lr *= al;
#pragma unroll
            for (int d = 0; d < 8; d++) o[d] *= al;
        }
        float p[4][4];
        float ps = 0.f;
#pragma unroll
        for (int n = 0; n < 4; n++)
#pragma unroll
            for (int r = 0; r < 4; r++) {
                p[n][r] = exp2f(sT[n][r] - mr);
                ps += p[n][r];
            }
        lr += ps;
#pragma unroll
        for (int kk = 0; kk < 2; kk++) {
            union { uint_t u[4]; bf16x8 v; } bP;
            bP.u[0] = cvt_pk_bf16(p[2 * kk][0], p[2 * kk][1]);
            bP.u[1] = cvt_pk_bf16(p[2 * kk][2], p[2 * kk][3]);
            bP.u[2] = cvt_pk_bf16(p[2 * kk + 1][0], p[2 * kk + 1][1]);
            bP.u[3] = cvt_pk_bf16(p[2 * kk + 1][2], p[2 * kk + 1][3]);
#pragma unroll
            for (int dt = 0; dt < 8; dt++) {
                bf16x8 aV = *(const bf16x8*)(sm + DB + 16384 + (vbase[dt] ^ (kk << 6)));
                o[dt] = __builtin_amdgcn_mfma_f32_16x16x32_bf16(aV, bP.v, o[dt], 0, 0, 0);
            }
        }
    };

    STAGE(0, 0);
    __syncthreads();
#pragma unroll 1
    for (int t = 0; t < 16; t += 2) {
        STAGE(32768, t + 1);
        TILE(0);
        __syncthreads();
        if (t < 14) STAGE(0, t + 2);
        TILE(32768);
        __syncthreads();
    }

    lr += __shfl_xor(lr, 16, 64);
    lr += __shfl_xor(lr, 32, 64);
    float inv = 1.0f / lr;
    ushort_t* lO = (ushort_t*)sm;
#pragma unroll
    for (int dt = 0; dt < 8; dt++) {
        uint2 wv;
        wv.x = (uint_t)f2b(o[dt][0] * inv) | ((uint_t)f2b(o[dt][1] * inv) << 16);
        wv.y = (uint_t)f2b(o[dt][2] * inv) | ((uint_t)f2b(o[dt][3] * inv) << 16);
        *(uint2*)(lO + (w * 16 + c) * 136 + dt * 16 + g * 4) = wv;
    }
    __syncthreads();
    int row = tid >> 2, c8 = tid & 3;
    const ushort_t* src = lO + row * 136 + c8 * 32;
    ushort_t* dst = O + (size_t)(b * 2048 + qt * 128 + row) * 2048 + h * 128 + c8 * 32;
#pragma unroll
    for (int k = 0; k < 4; k++) *(uint4*)(dst + k * 8) = *(const uint4*)(src + k * 8);
}

extern "C" void kernel_launch(void* const* d_in, const int* in_sizes, int n_in,
                              void* d_out, int out_size, void* d_ws, size_t ws_size,
                              hipStream_t stream) {
    const float* x   = (const float*)d_in[0];
    const float* cam = (const float*)d_in[1];
    const float* ren = (const float*)d_in[2];
    const float* fx  = (const float*)d_in[3];
    const float* fc  = (const float*)d_in[4];
    const float* fr  = (const float*)d_in[5];
    const float* wq  = (const float*)d_in[6];
    const float* bq  = (const float*)d_in[7];
    const float* wk  = (const float*)d_in[8];
    const float* bk  = (const float*)d_in[9];
    const float* wv  = (const float*)d_in[10];
    const float* bv  = (const float*)d_in[11];
    const float* wkr = (const float*)d_in[12];
    const float* bkr = (const float*)d_in[13];
    const float* wvr = (const float*)d_in[14];
    const float* bvr = (const float*)d_in[15];
    const float* wo  = (const float*)d_in[16];
    const float* bo  = (const float*)d_in[17];
    const float* gq  = (const float*)d_in[18];
    const float* gk  = (const float*)d_in[19];

    char* ws = (char*)d_ws;
    ushort_t* wq_b     = (ushort_t*)(ws + 0);
    ushort_t* wk_b     = (ushort_t*)(ws + 8388608);    // wk||wv contiguous (N=4096)
    ushort_t* wkr_b    = (ushort_t*)(ws + 25165824);   // wkr||wvr contiguous
    ushort_t* wo_b     = (ushort_t*)(ws + 41943040);
    ushort_t* xb       = (ushort_t*)(ws + 50331648);   // reused by attn_bf later
    ushort_t* camb     = (ushort_t*)(ws + 67108864);
    ushort_t* renb     = (ushort_t*)(ws + 71303168);
    ushort_t* kcam_lin = (ushort_t*)(ws + 75497472);   // bf16 [1024][2048]
    ushort_t* kren_lin = (ushort_t*)(ws + 79691776);
    ushort_t* vt       = (ushort_t*)(ws + 83886080);   // tile-major V, 8MB
    ushort_t* q_bf     = (ushort_t*)(ws + 92274688);   // packed [b,h,2048,128]
    ushort_t* kcam_bf  = (ushort_t*)(ws + 109051904);  // packed [b,h,512,128]
    ushort_t* kren_bf  = (ushort_t*)(ws + 113246208);
    ushort_t* attn_bf  = (ushort_t*)(ws + 50331648);   // overlays dead xb
    ushort_t* q_lin    = (ushort_t*)d_out;             // d_out doubles as bf16 Q-proj scratch

    hipFuncSetAttribute(reinterpret_cast<const void*>(&k_g256),
                        hipFuncAttributeMaxDynamicSharedMemorySize, 131072);
    hipFuncSetAttribute(reinterpret_cast<const void*>(&k_g128),
                        hipFuncAttributeMaxDynamicSharedMemorySize, 98304);

    // fp32 -> bf16 converts
    CvtWArgs cw{{wq, wk, wv, wkr, wvr, wo}};
    k_cvtw<<<dim3(2048, 6), 256, 0, stream>>>(cw, wq_b);
    Cvt3Args c3{{x, cam, ren}, {xb, camb, renb}, {8388608, 2097152, 2097152}};
    k_cvt3<<<dim3(4096, 3), 256, 0, stream>>>(c3);

    // merged Q + K/V projections (8-phase 256^2, 256 blocks); V lands in vt directly
    G8 qa{xb, wq_b, bq, nullptr, (void*)q_lin, nullptr};
    G8 kva0{camb, wk_b, bk, bv, (void*)kcam_lin, (void*)vt};
    G8 kva1{renb, wkr_b, bkr, bvr, (void*)kren_lin, (void*)vt};
    k_g256<<<dim3(256, 1, 1), 512, 131072, stream>>>(qa, kva0, kva1);

    // merged RMSNorm+RoPE (Q folds (1/sqrt(HD))*log2(e)); outputs packed per-head
    RR r0{q_lin, gq, fx, q_bf, 11, 0.08838834764831845f * 1.4426950408889634f};
    RR r1{kcam_lin, gk, fc, kcam_bf, 9, 1.0f};
    RR r2{kren_lin, gk, fr, kren_bf, 9, 1.0f};
    k_rr<<<dim3(6144, 1, 1), 256, 0, stream>>>(r0, r1, r2);

    // flash attention (flat 512, XCD-pinned, contiguous staging)
    k_attn<<<dim3(512, 1, 1), 512, 0, stream>>>(q_bf, kcam_bf, kren_bf, vt, attn_bf);

    // output projection -> d_out (fp32), 8-phase 128x256, 256 blocks
    G8 oa{attn_bf, wo_b, bo, nullptr, d_out, nullptr};
    k_g128<<<dim3(256, 1, 1), 512, 98304, stream>>>(oa);
}